// Round 1
// baseline (6755.442 us; speedup 1.0000x reference)
//
#include <hip/hip_runtime.h>

#define DM 192      // D_MODEL
#define DI 384      // D_INNER
#define DSt 16      // D_STATE
#define DTR 12      // DT_RANK
#define DC 4        // D_CONV
#define NL 24       // DEPTH
#define HP 14
#define NH 3
#define NB 4        // BATCH
#define SL 197      // seq len (tokens + cls)
#define NT 196      // spatial tokens
#define XZW 768     // 2*D_INNER
#define DBLW 44     // DT_RANK + 2*D_STATE

static __device__ __forceinline__ float siluf(float x) { return x / (1.f + expf(-x)); }
static __device__ __forceinline__ float softplusf(float x) { return (x > 20.f) ? x : log1pf(expf(x)); }

// ---- block reduce helpers (sum over first NWAVES waves) ----
static __device__ __forceinline__ float blk_sum3(float v, float* wsum) {
  for (int off = 32; off; off >>= 1) v += __shfl_xor(v, off, 64);
  int wid = threadIdx.x >> 6;
  if ((threadIdx.x & 63) == 0) wsum[wid] = v;
  __syncthreads();
  return wsum[0] + wsum[1] + wsum[2];
}
static __device__ __forceinline__ float blk_sum4(float v, float* wsum) {
  for (int off = 32; off; off >>= 1) v += __shfl_xor(v, off, 64);
  int wid = threadIdx.x >> 6;
  if ((threadIdx.x & 63) == 0) wsum[wid] = v;
  __syncthreads();
  return wsum[0] + wsum[1] + wsum[2] + wsum[3];
}

// ---- rope tables: cos/sin (196,192) ----
__global__ void k_rope_init(float* __restrict__ cosT, float* __restrict__ sinT) {
  int gid = blockIdx.x * blockDim.x + threadIdx.x;
  if (gid >= NT * DM) return;
  int c = gid % DM, tk = gid / DM;
  int py = tk / HP, px = tk % HP;
  int pos = (c < 96) ? py : px;
  int i = (c < 96) ? (c >> 1) : ((c - 96) >> 1);
  double fb = pow(10000.0, -((double)(2 * i)) / 96.0);
  double ang = (double)pos * fb;
  cosT[gid] = (float)cos(ang);
  sinT[gid] = (float)sin(ang);
}

// ---- patch embed + cls + pos; also zero res ----
__global__ __launch_bounds__(DM) void k_patch(
    const float* __restrict__ x1, const float* __restrict__ x2,
    const float* __restrict__ pw, const float* __restrict__ pb,
    const float* __restrict__ cls, const float* __restrict__ pos,
    float* __restrict__ h, float* __restrict__ res) {
  int bx = blockIdx.x;
  int t = bx % SL; int b = (bx / SL) % NB; int e = bx / (SL * NB);
  int o = threadIdx.x;
  const float* img = e ? x2 : x1;
  size_t hoff = ((size_t)(e * NB + b) * SL + t) * DM + o;
  res[hoff] = 0.f;
  __shared__ float patch[768];
  float v;
  if (t == 0) {
    v = cls[e * DM + o];
  } else {
    int tk = t - 1, py = tk / HP, px = tk % HP;
    for (int i = o; i < 768; i += DM) {
      int c = i >> 8, r = (i >> 4) & 15, xx = i & 15;
      patch[i] = img[((size_t)(b * 3 + c) * 224 + (py * 16 + r)) * 224 + (px * 16 + xx)];
    }
    __syncthreads();
    const float* w = pw + ((size_t)e * DM + o) * 768;
    float acc = 0.f;
    for (int i = 0; i < 768; ++i) acc += patch[i] * w[i];
    v = acc + pb[e * DM + o];
  }
  h[hoff] = v + pos[((size_t)e * SL + t) * DM + o];
}

// ---- per layer: rope(h); res += ; hs = rmsnorm(res)*nw ----
__global__ __launch_bounds__(DM) void k_rope_res_norm(
    const float* __restrict__ h, float* __restrict__ res, float* __restrict__ hs,
    const float* __restrict__ nw, const float* __restrict__ cosT,
    const float* __restrict__ sinT, int l) {
  int bx = blockIdx.x;
  int t = bx % SL; int b = (bx / SL) % NB; int e = bx / (SL * NB);
  int c = threadIdx.x;
  __shared__ float sh[DM];
  __shared__ float wsum[3];
  size_t base = ((size_t)(e * NB + b) * SL + t) * DM;
  sh[c] = h[base + c];
  __syncthreads();
  float v = sh[c];
  if (t > 0) {
    int tk = t - 1;
    float co = cosT[tk * DM + c], si = sinT[tk * DM + c];
    float partner = sh[c ^ 1];
    float rot = (c & 1) ? partner : -partner;
    v = v * co + rot * si;
  }
  float r = res[base + c] + v;
  res[base + c] = r;
  float tot = blk_sum3(r * r, wsum);
  float scale = rsqrtf(tot / (float)DM + 1e-5f);
  hs[base + c] = r * scale * nw[(size_t)(e * NL + l) * DM + c];
}

// ---- generic tiled C = alpha*(A0[+A1]) @ B^T, batched over z via struct ----
struct MM4 {
  const float* A0[4];
  const float* A1[4];
  const float* B[4];
  float* C[4];
};
__global__ __launch_bounds__(256) void k_mm_nt(MM4 p, int M, int N, int K, float alpha) {
  const float* __restrict__ A0 = p.A0[blockIdx.z];
  const float* __restrict__ A1 = p.A1[blockIdx.z];
  const float* __restrict__ Bw = p.B[blockIdx.z];
  float* __restrict__ C = p.C[blockIdx.z];
  __shared__ float As[32][33];
  __shared__ float Bs[32][33];
  int m0 = blockIdx.y * 32, n0 = blockIdx.x * 32;
  int tx = threadIdx.x & 31, ty = threadIdx.x >> 5;
  float acc0 = 0, acc1 = 0, acc2 = 0, acc3 = 0;
  for (int k0 = 0; k0 < K; k0 += 32) {
#pragma unroll
    for (int it = 0; it < 4; ++it) {
      int i = threadIdx.x + it * 256;
      int r = i >> 5, cc = i & 31;
      int gm = m0 + r, gk = k0 + cc;
      float va = 0.f;
      if (gm < M && gk < K) {
        va = A0[(size_t)gm * K + gk];
        if (A1) va += A1[(size_t)gm * K + gk];
      }
      As[r][cc] = va;
      int gn = n0 + r;
      float vb = 0.f;
      if (gn < N && gk < K) vb = Bw[(size_t)gn * K + gk];
      Bs[r][cc] = vb;
    }
    __syncthreads();
#pragma unroll
    for (int kk = 0; kk < 32; ++kk) {
      float bv = Bs[tx][kk];
      acc0 += As[ty][kk] * bv;
      acc1 += As[ty + 8][kk] * bv;
      acc2 += As[ty + 16][kk] * bv;
      acc3 += As[ty + 24][kk] * bv;
    }
    __syncthreads();
  }
  int gn = n0 + tx;
  if (gn < N) {
    int gm = m0 + ty;
    if (gm < M) C[(size_t)gm * N + gn] = alpha * acc0;
    gm += 8; if (gm < M) C[(size_t)gm * N + gn] = alpha * acc1;
    gm += 8; if (gm < M) C[(size_t)gm * N + gn] = alpha * acc2;
    gm += 8; if (gm < M) C[(size_t)gm * N + gn] = alpha * acc3;
  }
}

// ---- causal depthwise conv (k=4) + silu; handles direction reversal ----
__global__ void k_conv_silu(const float* __restrict__ xz, const float* __restrict__ cw,
                            const float* __restrict__ cb, float* __restrict__ xs, int l) {
  int gid = blockIdx.x * blockDim.x + threadIdx.x;
  if (gid >= 2 * 2 * NB * SL * DI) return;
  int d = gid % DI;
  int t = (gid / DI) % SL;
  int b = (gid / (DI * SL)) % NB;
  int dir = (gid / (DI * SL * NB)) % 2;
  int e = gid / (DI * SL * NB * 2);
  size_t pidx = (size_t)(e * NL + l) * 2 + dir;
  const float* cwp = cw + (pidx * DI + d) * DC;
  float acc = cb[pidx * DI + d];
#pragma unroll
  for (int k = 0; k < DC; ++k) {
    int ts = t - (DC - 1) + k;
    if (ts >= 0) {
      int torig = dir ? (SL - 1 - ts) : ts;
      acc += cwp[k] * xz[((size_t)(e * NB + b) * SL + torig) * XZW + d];
    }
  }
  xs[gid] = siluf(acc);
}

// ---- delta = softplus(dt @ dw^T + db) ----
__global__ void k_delta(const float* __restrict__ dbl, const float* __restrict__ dtw,
                        const float* __restrict__ dtb, float* __restrict__ delta, int l) {
  int gid = blockIdx.x * blockDim.x + threadIdx.x;
  if (gid >= 2 * 2 * NB * SL * DI) return;
  int d = gid % DI;
  int t = (gid / DI) % SL;
  int b = (gid / (DI * SL)) % NB;
  int dir = (gid / (DI * SL * NB)) % 2;
  int e = gid / (DI * SL * NB * 2);
  int z = e * 2 + dir;
  size_t pidx = (size_t)(e * NL + l) * 2 + dir;
  const float* row = dbl + ((size_t)(z * NB + b) * SL + t) * DBLW;
  const float* w = dtw + (pidx * DI + d) * DTR;
  float acc = dtb[pidx * DI + d];
#pragma unroll
  for (int r = 0; r < DTR; ++r) acc += row[r] * w[r];
  delta[gid] = softplusf(acc);
}

// ---- selective scan: 16 lanes per channel (n-dim), sequential over t ----
__global__ __launch_bounds__(256) void k_scan(
    const float* __restrict__ xs, const float* __restrict__ delta,
    const float* __restrict__ dbl, const float* __restrict__ xz,
    const float* __restrict__ alog, const float* __restrict__ dpw,
    float* __restrict__ y0, float* __restrict__ y1, int l) {
  int bx = blockIdx.x;
  int dg = bx % (DI / 16);
  int b = (bx / (DI / 16)) % NB;
  int dir = (bx / (DI / 16 * NB)) % 2;
  int e = bx / (DI / 16 * NB * 2);
  int n = threadIdx.x & 15;
  int dl = threadIdx.x >> 4;
  int d = dg * 16 + dl;
  size_t pidx = (size_t)(e * NL + l) * 2 + dir;
  float A = -expf(alog[(pidx * DI + d) * DSt + n]);
  float dpv = dpw[pidx * DI + d];
  int z = e * 2 + dir;
  size_t xsbase = ((size_t)(z * NB + b) * SL) * DI + d;
  size_t dblbase = ((size_t)(z * NB + b) * SL) * DBLW;
  size_t zbase = ((size_t)(e * NB + b) * SL) * XZW + DI + d;
  float* yout = dir ? y1 : y0;
  size_t ybase = ((size_t)(e * NB + b) * SL) * DI + d;
  float hst = 0.f;
  // 1-deep prefetch
  float dv = delta[xsbase];
  float xv = xs[xsbase];
  float bm = dbl[dblbase + DTR + n];
  float cv = dbl[dblbase + DTR + DSt + n];
  for (int t = 0; t < SL; ++t) {
    float dv_n = 0, xv_n = 0, bm_n = 0, cv_n = 0;
    if (t + 1 < SL) {
      size_t xo = xsbase + (size_t)(t + 1) * DI;
      dv_n = delta[xo];
      xv_n = xs[xo];
      const float* dn = dbl + dblbase + (size_t)(t + 1) * DBLW;
      bm_n = dn[DTR + n];
      cv_n = dn[DTR + DSt + n];
    }
    hst = expf(dv * A) * hst + (dv * xv) * bm;
    float p = hst * cv;
    p += __shfl_xor(p, 1, 64);
    p += __shfl_xor(p, 2, 64);
    p += __shfl_xor(p, 4, 64);
    p += __shfl_xor(p, 8, 64);
    if (n == 0) {
      int torig = dir ? (SL - 1 - t) : t;
      float zv = xz[zbase + (size_t)torig * XZW];
      float y = p + xv * dpv;
      yout[ybase + (size_t)torig * DI] = y * siluf(zv);
    }
    dv = dv_n; xv = xv_n; bm = bm_n; cv = cv_n;
  }
}

// ---- final: rmsnorm(h+res)*nfw, drop cls, token-major fT (e,b,196,192) ----
__global__ __launch_bounds__(DM) void k_final_norm(
    const float* __restrict__ h, const float* __restrict__ res,
    const float* __restrict__ nfw, float* __restrict__ fT) {
  int bx = blockIdx.x;
  int tk = bx % NT; int b = (bx / NT) % NB; int e = bx / (NT * NB);
  int c = threadIdx.x;
  __shared__ float wsum[3];
  size_t base = ((size_t)(e * NB + b) * SL + (tk + 1)) * DM;
  float r = h[base + c] + res[base + c];
  float tot = blk_sum3(r * r, wsum);
  float scale = rsqrtf(tot / (float)DM + 1e-5f);
  fT[((size_t)(e * NB + b) * NT + tk) * DM + c] = r * scale * nfw[e * DM + c];
}

// ---- depthwise 3x3 SAME over 14x14; in token-major, out channel-major ----
__global__ void k_dwconv(const float* __restrict__ qkvl, const float* __restrict__ qdw,
                         const float* __restrict__ kdw, const float* __restrict__ vdw,
                         float* __restrict__ qkvd) {
  int gid = blockIdx.x * blockDim.x + threadIdx.x;
  if (gid >= 3 * NB * DM * NT) return;
  int nn = gid % NT;
  int o = (gid / NT) % DM;
  int b = (gid / (NT * DM)) % NB;
  int zz = gid / (NT * DM * NB);
  const float* wsel = (zz == 0 ? qdw : (zz == 1 ? kdw : vdw)) + o * 9;
  int y = nn / HP, x = nn % HP;
  const float* in = qkvl + ((size_t)zz * NB + b) * NT * DM;
  float acc = 0.f;
#pragma unroll
  for (int ky = 0; ky < 3; ++ky) {
    int yy = y + ky - 1;
    if (yy < 0 || yy >= HP) continue;
#pragma unroll
    for (int kx = 0; kx < 3; ++kx) {
      int xx = x + kx - 1;
      if (xx < 0 || xx >= HP) continue;
      acc += in[(size_t)(yy * HP + xx) * DM + o] * wsel[ky * 3 + kx];
    }
  }
  qkvd[gid] = acc;
}

// ---- L2-normalize q,k rows over n=196 (in place) ----
__global__ __launch_bounds__(256) void k_l2norm(float* __restrict__ qkvd) {
  int bx = blockIdx.x;
  int C = bx % DM; int b = (bx / DM) % NB; int zz = bx / (DM * NB);
  int i = threadIdx.x;
  __shared__ float wsum[4];
  float* row = qkvd + ((size_t)zz * NB + b) * DM * NT + (size_t)C * NT;
  float v = (i < NT) ? row[i] : 0.f;
  float tot = blk_sum4(v * v, wsum);
  float sc = 1.f / fmaxf(sqrtf(tot), 1e-12f);
  if (i < NT) row[i] = v * sc;
}

// ---- S = temp*qn.kn^T, softmax over j (block=(b,h,i), 64 threads=j) ----
__global__ __launch_bounds__(64) void k_attn_sm(const float* __restrict__ qkvd,
                                                const float* __restrict__ temp,
                                                float* __restrict__ P) {
  int bx = blockIdx.x;
  int i = bx % 64; int hh = (bx / 64) % NH; int b = bx / (64 * NH);
  int j = threadIdx.x;
  __shared__ float qs[NT];
  const float* qrow = qkvd + ((size_t)0 * NB + b) * DM * NT + (size_t)(hh * 64 + i) * NT;
  for (int k = j; k < NT; k += 64) qs[k] = qrow[k];
  __syncthreads();
  const float* krow = qkvd + ((size_t)1 * NB + b) * DM * NT + (size_t)(hh * 64 + j) * NT;
  float acc = 0.f;
  for (int k = 0; k < NT; ++k) acc += qs[k] * krow[k];
  acc *= temp[hh];
  float m = acc;
  for (int off = 32; off; off >>= 1) m = fmaxf(m, __shfl_xor(m, off, 64));
  float ex = expf(acc - m);
  float s = ex;
  for (int off = 32; off; off >>= 1) s += __shfl_xor(s, off, 64);
  P[((size_t)(b * NH + hh) * 64 + i) * 64 + j] = ex / s;
}

// ---- out = P @ vh ----
__global__ __launch_bounds__(256) void k_av(const float* __restrict__ P,
                                            const float* __restrict__ qkvd,
                                            float* __restrict__ att) {
  int bx = blockIdx.x;
  int i = bx % 64; int hh = (bx / 64) % NH; int b = bx / (64 * NH);
  int nn = threadIdx.x;
  __shared__ float ps[64];
  if (nn < 64) ps[nn] = P[((size_t)(b * NH + hh) * 64 + i) * 64 + nn];
  __syncthreads();
  if (nn >= NT) return;
  const float* vbase = qkvd + ((size_t)2 * NB + b) * DM * NT + (size_t)(hh * 64) * NT + nn;
  float acc = 0.f;
  for (int j = 0; j < 64; ++j) acc += ps[j] * vbase[(size_t)j * NT];
  att[((size_t)b * DM + hh * 64 + i) * NT + nn] = acc;
}

// ---- final pointwise projection to d_out ----
__global__ __launch_bounds__(256) void k_out(const float* __restrict__ att,
                                             const float* __restrict__ pw,
                                             float* __restrict__ out) {
  int bx = blockIdx.x;
  int o = bx % DM; int b = bx / DM;
  int nn = threadIdx.x;
  if (nn >= NT) return;
  const float* abase = att + (size_t)b * DM * NT + nn;
  const float* w = pw + (size_t)o * DM;
  float acc = 0.f;
  for (int c = 0; c < DM; ++c) acc += abase[(size_t)c * NT] * w[c];
  out[((size_t)b * DM + o) * NT + nn] = acc;
}

extern "C" void kernel_launch(void* const* d_in, const int* in_sizes, int n_in,
                              void* d_out, int out_size, void* d_ws, size_t ws_size,
                              hipStream_t stream) {
  const float* x1      = (const float*)d_in[0];
  const float* x2      = (const float*)d_in[1];
  const float* patch_w = (const float*)d_in[2];
  const float* patch_b = (const float*)d_in[3];
  const float* cls_tok = (const float*)d_in[4];
  const float* pos_emb = (const float*)d_in[5];
  const float* norm_w  = (const float*)d_in[6];
  const float* in_w    = (const float*)d_in[7];
  const float* conv_w  = (const float*)d_in[8];
  const float* conv_b  = (const float*)d_in[9];
  const float* xp_w    = (const float*)d_in[10];
  const float* dt_w    = (const float*)d_in[11];
  const float* dt_b    = (const float*)d_in[12];
  const float* A_log   = (const float*)d_in[13];
  const float* Dp      = (const float*)d_in[14];
  const float* out_w   = (const float*)d_in[15];
  const float* normf_w = (const float*)d_in[16];
  const float* qw      = (const float*)d_in[17];
  const float* qdw     = (const float*)d_in[18];
  const float* kw      = (const float*)d_in[19];
  const float* kdw     = (const float*)d_in[20];
  const float* vw      = (const float*)d_in[21];
  const float* vdw     = (const float*)d_in[22];
  const float* pww     = (const float*)d_in[23];
  const float* temp    = (const float*)d_in[24];

  float* ws = (float*)d_ws;
  size_t o = 0;
  float* cosT = ws + o; o += (size_t)NT * DM;
  float* sinT = ws + o; o += (size_t)NT * DM;
  float* hB   = ws + o; o += 2ull * NB * SL * DM;
  float* resB = ws + o; o += 2ull * NB * SL * DM;
  float* hsB  = ws + o; o += 2ull * NB * SL * DM;
  float* xzB  = ws + o; o += 2ull * NB * SL * XZW;
  float* xsB  = ws + o; o += 4ull * NB * SL * DI;
  float* dblB = ws + o; o += 4ull * NB * SL * DBLW;
  float* delB = ws + o; o += 4ull * NB * SL * DI;
  float* y0B  = ws + o; o += 2ull * NB * SL * DI;
  float* y1B  = ws + o; o += 2ull * NB * SL * DI;
  float* fTB  = ws + o; o += 2ull * NB * NT * DM;
  float* qkvL = ws + o; o += 3ull * NB * NT * DM;
  float* qkvD = ws + o; o += 3ull * NB * DM * NT;
  float* Pb   = ws + o; o += (size_t)NB * NH * 64 * 64;
  float* attB = ws + o; o += (size_t)NB * DM * NT;
  (void)ws_size; (void)in_sizes; (void)n_in; (void)out_size;

  const int M = NB * SL;  // 788 rows per encoder

  k_rope_init<<<(NT * DM + 255) / 256, 256, 0, stream>>>(cosT, sinT);
  k_patch<<<2 * NB * SL, DM, 0, stream>>>(x1, x2, patch_w, patch_b, cls_tok, pos_emb, hB, resB);

  for (int l = 0; l < NL; ++l) {
    k_rope_res_norm<<<2 * NB * SL, DM, 0, stream>>>(hB, resB, hsB, norm_w, cosT, sinT, l);

    // xz = hs @ in_w^T  (per encoder)
    {
      MM4 p{};
      for (int e = 0; e < 2; ++e) {
        p.A0[e] = hsB + (size_t)e * M * DM;
        p.A1[e] = nullptr;
        p.B[e]  = in_w + (size_t)(e * NL + l) * XZW * DM;
        p.C[e]  = xzB + (size_t)e * M * XZW;
      }
      dim3 g((XZW + 31) / 32, (M + 31) / 32, 2);
      k_mm_nt<<<g, 256, 0, stream>>>(p, M, XZW, DM, 1.f);
    }

    k_conv_silu<<<(2 * 2 * NB * SL * DI + 255) / 256, 256, 0, stream>>>(xzB, conv_w, conv_b, xsB, l);

    // dbl = xs @ xp_w^T (per e,dir)
    {
      MM4 p{};
      for (int z = 0; z < 4; ++z) {
        int e = z / 2, dir = z % 2;
        p.A0[z] = xsB + (size_t)z * M * DI;
        p.A1[z] = nullptr;
        p.B[z]  = xp_w + ((size_t)(e * NL + l) * 2 + dir) * DBLW * DI;
        p.C[z]  = dblB + (size_t)z * M * DBLW;
      }
      dim3 g((DBLW + 31) / 32, (M + 31) / 32, 4);
      k_mm_nt<<<g, 256, 0, stream>>>(p, M, DBLW, DI, 1.f);
    }

    k_delta<<<(2 * 2 * NB * SL * DI + 255) / 256, 256, 0, stream>>>(dblB, dt_w, dt_b, delB, l);

    k_scan<<<2 * 2 * NB * (DI / 16), 256, 0, stream>>>(xsB, delB, dblB, xzB, A_log, Dp, y0B, y1B, l);

    // h = 0.5*(y0+y1) @ out_w^T (per encoder)
    {
      MM4 p{};
      for (int e = 0; e < 2; ++e) {
        p.A0[e] = y0B + (size_t)e * M * DI;
        p.A1[e] = y1B + (size_t)e * M * DI;
        p.B[e]  = out_w + (size_t)(e * NL + l) * DM * DI;
        p.C[e]  = hB + (size_t)e * M * DM;
      }
      dim3 g((DM + 31) / 32, (M + 31) / 32, 2);
      k_mm_nt<<<g, 256, 0, stream>>>(p, M, DM, DI, 0.5f);
    }
  }

  k_final_norm<<<2 * NB * NT, DM, 0, stream>>>(hB, resB, normf_w, fTB);

  // q/k/v linear: q from f1 (e=0), k,v from f2 (e=1)
  {
    MM4 p{};
    const int Mq = NB * NT;  // 784
    p.A0[0] = fTB;                                p.A1[0] = nullptr; p.B[0] = qw; p.C[0] = qkvL;
    p.A0[1] = fTB + (size_t)NB * NT * DM;         p.A1[1] = nullptr; p.B[1] = kw; p.C[1] = qkvL + (size_t)Mq * DM;
    p.A0[2] = fTB + (size_t)NB * NT * DM;         p.A1[2] = nullptr; p.B[2] = vw; p.C[2] = qkvL + 2ull * Mq * DM;
    dim3 g((DM + 31) / 32, (Mq + 31) / 32, 3);
    k_mm_nt<<<g, 256, 0, stream>>>(p, Mq, DM, DM, 1.f);
  }

  k_dwconv<<<(3 * NB * DM * NT + 255) / 256, 256, 0, stream>>>(qkvL, qdw, kdw, vdw, qkvD);
  k_l2norm<<<2 * NB * DM, 256, 0, stream>>>(qkvD);
  k_attn_sm<<<NB * NH * 64, 64, 0, stream>>>(qkvD, temp, Pb);
  k_av<<<NB * NH * 64, 256, 0, stream>>>(Pb, qkvD, attB);
  k_out<<<NB * DM, 256, 0, stream>>>(attB, pww, (float*)d_out);
}

// Round 3
// 5406.003 us; speedup vs baseline: 1.2496x; 1.2496x over previous
//
#include <hip/hip_runtime.h>

#define DM 192      // D_MODEL
#define DI 384      // D_INNER
#define DSt 16      // D_STATE
#define DTR 12      // DT_RANK
#define DC 4        // D_CONV
#define NL 24       // DEPTH
#define HP 14
#define NH 3
#define NB 4        // BATCH
#define SL 197      // seq len (tokens + cls)
#define NT 196      // spatial tokens
#define XZW 768     // 2*D_INNER
#define DBLW 44     // DT_RANK + 2*D_STATE
#define CH 16       // scan chunk depth (register prefetch)

static __device__ __forceinline__ float siluf(float x) { return x / (1.f + expf(-x)); }
static __device__ __forceinline__ float softplusf(float x) { return (x > 20.f) ? x : log1pf(expf(x)); }

// ---- block reduce helpers (sum over first NWAVES waves) ----
static __device__ __forceinline__ float blk_sum3(float v, float* wsum) {
  for (int off = 32; off; off >>= 1) v += __shfl_xor(v, off, 64);
  int wid = threadIdx.x >> 6;
  if ((threadIdx.x & 63) == 0) wsum[wid] = v;
  __syncthreads();
  return wsum[0] + wsum[1] + wsum[2];
}
static __device__ __forceinline__ float blk_sum4(float v, float* wsum) {
  for (int off = 32; off; off >>= 1) v += __shfl_xor(v, off, 64);
  int wid = threadIdx.x >> 6;
  if ((threadIdx.x & 63) == 0) wsum[wid] = v;
  __syncthreads();
  return wsum[0] + wsum[1] + wsum[2] + wsum[3];
}

// ---- rope tables: cos/sin (196,192) ----
__global__ void k_rope_init(float* __restrict__ cosT, float* __restrict__ sinT) {
  int gid = blockIdx.x * blockDim.x + threadIdx.x;
  if (gid >= NT * DM) return;
  int c = gid % DM, tk = gid / DM;
  int py = tk / HP, px = tk % HP;
  int pos = (c < 96) ? py : px;
  int i = (c < 96) ? (c >> 1) : ((c - 96) >> 1);
  double fb = pow(10000.0, -((double)(2 * i)) / 96.0);
  double ang = (double)pos * fb;
  cosT[gid] = (float)cos(ang);
  sinT[gid] = (float)sin(ang);
}

// ---- patch embed + cls + pos; also zero res ----
__global__ __launch_bounds__(DM) void k_patch(
    const float* __restrict__ x1, const float* __restrict__ x2,
    const float* __restrict__ pw, const float* __restrict__ pb,
    const float* __restrict__ cls, const float* __restrict__ pos,
    float* __restrict__ h, float* __restrict__ res) {
  int bx = blockIdx.x;
  int t = bx % SL; int b = (bx / SL) % NB; int e = bx / (SL * NB);
  int o = threadIdx.x;
  const float* img = e ? x2 : x1;
  size_t hoff = ((size_t)(e * NB + b) * SL + t) * DM + o;
  res[hoff] = 0.f;
  __shared__ float patch[768];
  float v;
  if (t == 0) {
    v = cls[e * DM + o];
  } else {
    int tk = t - 1, py = tk / HP, px = tk % HP;
    for (int i = o; i < 768; i += DM) {
      int c = i >> 8, r = (i >> 4) & 15, xx = i & 15;
      patch[i] = img[((size_t)(b * 3 + c) * 224 + (py * 16 + r)) * 224 + (px * 16 + xx)];
    }
    __syncthreads();
    const float* w = pw + ((size_t)e * DM + o) * 768;
    float acc = 0.f;
    for (int i = 0; i < 768; ++i) acc += patch[i] * w[i];
    v = acc + pb[e * DM + o];
  }
  h[hoff] = v + pos[((size_t)e * SL + t) * DM + o];
}

// ---- per layer: rope(h); res += ; hs = rmsnorm(res)*nw ----
__global__ __launch_bounds__(DM) void k_rope_res_norm(
    const float* __restrict__ h, float* __restrict__ res, float* __restrict__ hs,
    const float* __restrict__ nw, const float* __restrict__ cosT,
    const float* __restrict__ sinT, int l) {
  int bx = blockIdx.x;
  int t = bx % SL; int b = (bx / SL) % NB; int e = bx / (SL * NB);
  int c = threadIdx.x;
  __shared__ float sh[DM];
  __shared__ float wsum[3];
  size_t base = ((size_t)(e * NB + b) * SL + t) * DM;
  sh[c] = h[base + c];
  __syncthreads();
  float v = sh[c];
  if (t > 0) {
    int tk = t - 1;
    float co = cosT[tk * DM + c], si = sinT[tk * DM + c];
    float partner = sh[c ^ 1];
    float rot = (c & 1) ? partner : -partner;
    v = v * co + rot * si;
  }
  float r = res[base + c] + v;
  res[base + c] = r;
  float tot = blk_sum3(r * r, wsum);
  float scale = rsqrtf(tot / (float)DM + 1e-5f);
  hs[base + c] = r * scale * nw[(size_t)(e * NL + l) * DM + c];
}

// ---- generic tiled C = alpha*(A0[+A1]) @ B^T, batched over z via struct ----
struct MM4 {
  const float* A0[4];
  const float* A1[4];
  const float* B[4];
  float* C[4];
};
__global__ __launch_bounds__(256) void k_mm_nt(MM4 p, int M, int N, int K, float alpha) {
  const float* __restrict__ A0 = p.A0[blockIdx.z];
  const float* __restrict__ A1 = p.A1[blockIdx.z];
  const float* __restrict__ Bw = p.B[blockIdx.z];
  float* __restrict__ C = p.C[blockIdx.z];
  __shared__ float As[32][33];
  __shared__ float Bs[32][33];
  int m0 = blockIdx.y * 32, n0 = blockIdx.x * 32;
  int tx = threadIdx.x & 31, ty = threadIdx.x >> 5;
  float acc0 = 0, acc1 = 0, acc2 = 0, acc3 = 0;
  for (int k0 = 0; k0 < K; k0 += 32) {
#pragma unroll
    for (int it = 0; it < 4; ++it) {
      int i = threadIdx.x + it * 256;
      int r = i >> 5, cc = i & 31;
      int gm = m0 + r, gk = k0 + cc;
      float va = 0.f;
      if (gm < M && gk < K) {
        va = A0[(size_t)gm * K + gk];
        if (A1) va += A1[(size_t)gm * K + gk];
      }
      As[r][cc] = va;
      int gn = n0 + r;
      float vb = 0.f;
      if (gn < N && gk < K) vb = Bw[(size_t)gn * K + gk];
      Bs[r][cc] = vb;
    }
    __syncthreads();
#pragma unroll
    for (int kk = 0; kk < 32; ++kk) {
      float bv = Bs[tx][kk];
      acc0 += As[ty][kk] * bv;
      acc1 += As[ty + 8][kk] * bv;
      acc2 += As[ty + 16][kk] * bv;
      acc3 += As[ty + 24][kk] * bv;
    }
    __syncthreads();
  }
  int gn = n0 + tx;
  if (gn < N) {
    int gm = m0 + ty;
    if (gm < M) C[(size_t)gm * N + gn] = alpha * acc0;
    gm += 8; if (gm < M) C[(size_t)gm * N + gn] = alpha * acc1;
    gm += 8; if (gm < M) C[(size_t)gm * N + gn] = alpha * acc2;
    gm += 8; if (gm < M) C[(size_t)gm * N + gn] = alpha * acc3;
  }
}

// ---- causal depthwise conv (k=4) + silu; handles direction reversal ----
__global__ void k_conv_silu(const float* __restrict__ xz, const float* __restrict__ cw,
                            const float* __restrict__ cb, float* __restrict__ xs, int l) {
  int gid = blockIdx.x * blockDim.x + threadIdx.x;
  if (gid >= 2 * 2 * NB * SL * DI) return;
  int d = gid % DI;
  int t = (gid / DI) % SL;
  int b = (gid / (DI * SL)) % NB;
  int dir = (gid / (DI * SL * NB)) % 2;
  int e = gid / (DI * SL * NB * 2);
  size_t pidx = (size_t)(e * NL + l) * 2 + dir;
  const float* cwp = cw + (pidx * DI + d) * DC;
  float acc = cb[pidx * DI + d];
#pragma unroll
  for (int k = 0; k < DC; ++k) {
    int ts = t - (DC - 1) + k;
    if (ts >= 0) {
      int torig = dir ? (SL - 1 - ts) : ts;
      acc += cwp[k] * xz[((size_t)(e * NB + b) * SL + torig) * XZW + d];
    }
  }
  xs[gid] = siluf(acc);
}

// ---- delta = softplus(dt @ dw^T + db) ----
__global__ void k_delta(const float* __restrict__ dbl, const float* __restrict__ dtw,
                        const float* __restrict__ dtb, float* __restrict__ delta, int l) {
  int gid = blockIdx.x * blockDim.x + threadIdx.x;
  if (gid >= 2 * 2 * NB * SL * DI) return;
  int d = gid % DI;
  int t = (gid / DI) % SL;
  int b = (gid / (DI * SL)) % NB;
  int dir = (gid / (DI * SL * NB)) % 2;
  int e = gid / (DI * SL * NB * 2);
  int z = e * 2 + dir;
  size_t pidx = (size_t)(e * NL + l) * 2 + dir;
  const float* row = dbl + ((size_t)(z * NB + b) * SL + t) * DBLW;
  const float* w = dtw + (pidx * DI + d) * DTR;
  float acc = dtb[pidx * DI + d];
#pragma unroll
  for (int r = 0; r < DTR; ++r) acc += row[r] * w[r];
  delta[gid] = softplusf(acc);
}

// ---- selective scan: 16 lanes per channel (n-dim), sequential over t ----
// Chunked CH-deep register prefetch, ping-pong double buffered: loads for
// chunk c+1 are all issued before computing chunk c, so ~900cy memory
// latency hides under a full chunk of compute instead of one step.
__global__ __launch_bounds__(256) void k_scan(
    const float* __restrict__ xs, const float* __restrict__ delta,
    const float* __restrict__ dbl, const float* __restrict__ xz,
    const float* __restrict__ alog, const float* __restrict__ dpw,
    float* __restrict__ y0, float* __restrict__ y1, int l) {
  int bx = blockIdx.x;
  int dg = bx % (DI / 16);
  int b = (bx / (DI / 16)) % NB;
  int dir = (bx / (DI / 16 * NB)) % 2;
  int e = bx / (DI / 16 * NB * 2);
  int n = threadIdx.x & 15;
  int dl = threadIdx.x >> 4;
  int d = dg * 16 + dl;
  size_t pidx = (size_t)(e * NL + l) * 2 + dir;
  float A = -expf(alog[(pidx * DI + d) * DSt + n]);
  float dpv = dpw[pidx * DI + d];
  int z = e * 2 + dir;
  size_t xsbase = ((size_t)(z * NB + b) * SL) * DI + d;
  size_t dblbase = ((size_t)(z * NB + b) * SL) * DBLW;
  size_t zbase = ((size_t)(e * NB + b) * SL) * XZW + DI + d;
  float* yout = dir ? y1 : y0;
  size_t ybase = ((size_t)(e * NB + b) * SL) * DI + d;
  float hst = 0.f;

  float dvA[CH], xvA[CH], bmA[CH], cvA[CH], zvA[CH];
  float dvB[CH], xvB[CH], bmB[CH], cvB[CH], zvB[CH];

  auto LOAD = [&](int t0, float (&dv)[CH], float (&xv)[CH], float (&bm)[CH],
                  float (&cv)[CH], float (&zv)[CH]) {
#pragma unroll
    for (int i = 0; i < CH; ++i) {
      int t = t0 + i;
      bool ok = (t < SL);
      size_t xo = xsbase + (size_t)t * DI;
      dv[i] = ok ? delta[xo] : 0.f;
      xv[i] = ok ? xs[xo] : 0.f;
      const float* dn = dbl + dblbase + (size_t)t * DBLW + DTR + n;
      bm[i] = ok ? dn[0] : 0.f;
      cv[i] = ok ? dn[DSt] : 0.f;
      int torig = dir ? (SL - 1 - t) : t;
      zv[i] = (ok && n == 0) ? xz[zbase + (size_t)torig * XZW] : 0.f;
    }
  };

  auto COMP = [&](int t0, float (&dv)[CH], float (&xv)[CH], float (&bm)[CH],
                  float (&cv)[CH], float (&zv)[CH]) {
#pragma unroll
    for (int i = 0; i < CH; ++i) {
      hst = __expf(dv[i] * A) * hst + (dv[i] * xv[i]) * bm[i];
      float p = hst * cv[i];
      p += __shfl_xor(p, 1, 64);
      p += __shfl_xor(p, 2, 64);
      p += __shfl_xor(p, 4, 64);
      p += __shfl_xor(p, 8, 64);
      int t = t0 + i;
      if (n == 0 && t < SL) {
        int torig = dir ? (SL - 1 - t) : t;
        float yv = p + xv[i] * dpv;
        yout[ybase + (size_t)torig * DI] = yv * siluf(zv[i]);
      }
    }
  };

  LOAD(0, dvA, xvA, bmA, cvA, zvA);
#pragma unroll 1
  for (int c = 0; c < 14; c += 2) {
    LOAD((c + 1) * CH, dvB, xvB, bmB, cvB, zvB);
    COMP(c * CH, dvA, xvA, bmA, cvA, zvA);
    LOAD((c + 2) * CH, dvA, xvA, bmA, cvA, zvA);
    COMP((c + 1) * CH, dvB, xvB, bmB, cvB, zvB);
  }
}

// ---- final: rmsnorm(h+res)*nfw, drop cls, token-major fT (e,b,196,192) ----
__global__ __launch_bounds__(DM) void k_final_norm(
    const float* __restrict__ h, const float* __restrict__ res,
    const float* __restrict__ nfw, float* __restrict__ fT) {
  int bx = blockIdx.x;
  int tk = bx % NT; int b = (bx / NT) % NB; int e = bx / (NT * NB);
  int c = threadIdx.x;
  __shared__ float wsum[3];
  size_t base = ((size_t)(e * NB + b) * SL + (tk + 1)) * DM;
  float r = h[base + c] + res[base + c];
  float tot = blk_sum3(r * r, wsum);
  float scale = rsqrtf(tot / (float)DM + 1e-5f);
  fT[((size_t)(e * NB + b) * NT + tk) * DM + c] = r * scale * nfw[e * DM + c];
}

// ---- depthwise 3x3 SAME over 14x14; in token-major, out channel-major ----
__global__ void k_dwconv(const float* __restrict__ qkvl, const float* __restrict__ qdw,
                         const float* __restrict__ kdw, const float* __restrict__ vdw,
                         float* __restrict__ qkvd) {
  int gid = blockIdx.x * blockDim.x + threadIdx.x;
  if (gid >= 3 * NB * DM * NT) return;
  int nn = gid % NT;
  int o = (gid / NT) % DM;
  int b = (gid / (NT * DM)) % NB;
  int zz = gid / (NT * DM * NB);
  const float* wsel = (zz == 0 ? qdw : (zz == 1 ? kdw : vdw)) + o * 9;
  int y = nn / HP, x = nn % HP;
  const float* in = qkvl + ((size_t)zz * NB + b) * NT * DM;
  float acc = 0.f;
#pragma unroll
  for (int ky = 0; ky < 3; ++ky) {
    int yy = y + ky - 1;
    if (yy < 0 || yy >= HP) continue;
#pragma unroll
    for (int kx = 0; kx < 3; ++kx) {
      int xx = x + kx - 1;
      if (xx < 0 || xx >= HP) continue;
      acc += in[(size_t)(yy * HP + xx) * DM + o] * wsel[ky * 3 + kx];
    }
  }
  qkvd[gid] = acc;
}

// ---- L2-normalize q,k rows over n=196 (in place) ----
__global__ __launch_bounds__(256) void k_l2norm(float* __restrict__ qkvd) {
  int bx = blockIdx.x;
  int C = bx % DM; int b = (bx / DM) % NB; int zz = bx / (DM * NB);
  int i = threadIdx.x;
  __shared__ float wsum[4];
  float* row = qkvd + ((size_t)zz * NB + b) * DM * NT + (size_t)C * NT;
  float v = (i < NT) ? row[i] : 0.f;
  float tot = blk_sum4(v * v, wsum);
  float sc = 1.f / fmaxf(sqrtf(tot), 1e-12f);
  if (i < NT) row[i] = v * sc;
}

// ---- S = temp*qn.kn^T, softmax over j (block=(b,h,i), 64 threads=j) ----
__global__ __launch_bounds__(64) void k_attn_sm(const float* __restrict__ qkvd,
                                                const float* __restrict__ temp,
                                                float* __restrict__ P) {
  int bx = blockIdx.x;
  int i = bx % 64; int hh = (bx / 64) % NH; int b = bx / (64 * NH);
  int j = threadIdx.x;
  __shared__ float qs[NT];
  const float* qrow = qkvd + ((size_t)0 * NB + b) * DM * NT + (size_t)(hh * 64 + i) * NT;
  for (int k = j; k < NT; k += 64) qs[k] = qrow[k];
  __syncthreads();
  const float* krow = qkvd + ((size_t)1 * NB + b) * DM * NT + (size_t)(hh * 64 + j) * NT;
  float acc = 0.f;
  for (int k = 0; k < NT; ++k) acc += qs[k] * krow[k];
  acc *= temp[hh];
  float m = acc;
  for (int off = 32; off; off >>= 1) m = fmaxf(m, __shfl_xor(m, off, 64));
  float ex = expf(acc - m);
  float s = ex;
  for (int off = 32; off; off >>= 1) s += __shfl_xor(s, off, 64);
  P[((size_t)(b * NH + hh) * 64 + i) * 64 + j] = ex / s;
}

// ---- out = P @ vh ----
__global__ __launch_bounds__(256) void k_av(const float* __restrict__ P,
                                            const float* __restrict__ qkvd,
                                            float* __restrict__ att) {
  int bx = blockIdx.x;
  int i = bx % 64; int hh = (bx / 64) % NH; int b = bx / (64 * NH);
  int nn = threadIdx.x;
  __shared__ float ps[64];
  if (nn < 64) ps[nn] = P[((size_t)(b * NH + hh) * 64 + i) * 64 + nn];
  __syncthreads();
  if (nn >= NT) return;
  const float* vbase = qkvd + ((size_t)2 * NB + b) * DM * NT + (size_t)(hh * 64) * NT + nn;
  float acc = 0.f;
  for (int j = 0; j < 64; ++j) acc += ps[j] * vbase[(size_t)j * NT];
  att[((size_t)b * DM + hh * 64 + i) * NT + nn] = acc;
}

// ---- final pointwise projection to d_out ----
__global__ __launch_bounds__(256) void k_out(const float* __restrict__ att,
                                             const float* __restrict__ pw,
                                             float* __restrict__ out) {
  int bx = blockIdx.x;
  int o = bx % DM; int b = bx / DM;
  int nn = threadIdx.x;
  if (nn >= NT) return;
  const float* abase = att + (size_t)b * DM * NT + nn;
  const float* w = pw + (size_t)o * DM;
  float acc = 0.f;
  for (int c = 0; c < DM; ++c) acc += abase[(size_t)c * NT] * w[c];
  out[((size_t)b * DM + o) * NT + nn] = acc;
}

extern "C" void kernel_launch(void* const* d_in, const int* in_sizes, int n_in,
                              void* d_out, int out_size, void* d_ws, size_t ws_size,
                              hipStream_t stream) {
  const float* x1      = (const float*)d_in[0];
  const float* x2      = (const float*)d_in[1];
  const float* patch_w = (const float*)d_in[2];
  const float* patch_b = (const float*)d_in[3];
  const float* cls_tok = (const float*)d_in[4];
  const float* pos_emb = (const float*)d_in[5];
  const float* norm_w  = (const float*)d_in[6];
  const float* in_w    = (const float*)d_in[7];
  const float* conv_w  = (const float*)d_in[8];
  const float* conv_b  = (const float*)d_in[9];
  const float* xp_w    = (const float*)d_in[10];
  const float* dt_w    = (const float*)d_in[11];
  const float* dt_b    = (const float*)d_in[12];
  const float* A_log   = (const float*)d_in[13];
  const float* Dp      = (const float*)d_in[14];
  const float* out_w   = (const float*)d_in[15];
  const float* normf_w = (const float*)d_in[16];
  const float* qw      = (const float*)d_in[17];
  const float* qdw     = (const float*)d_in[18];
  const float* kw      = (const float*)d_in[19];
  const float* kdw     = (const float*)d_in[20];
  const float* vw      = (const float*)d_in[21];
  const float* vdw     = (const float*)d_in[22];
  const float* pww     = (const float*)d_in[23];
  const float* temp    = (const float*)d_in[24];

  float* ws = (float*)d_ws;
  size_t o = 0;
  float* cosT = ws + o; o += (size_t)NT * DM;
  float* sinT = ws + o; o += (size_t)NT * DM;
  float* hB   = ws + o; o += 2ull * NB * SL * DM;
  float* resB = ws + o; o += 2ull * NB * SL * DM;
  float* hsB  = ws + o; o += 2ull * NB * SL * DM;
  float* xzB  = ws + o; o += 2ull * NB * SL * XZW;
  float* xsB  = ws + o; o += 4ull * NB * SL * DI;
  float* dblB = ws + o; o += 4ull * NB * SL * DBLW;
  float* delB = ws + o; o += 4ull * NB * SL * DI;
  float* y0B  = ws + o; o += 2ull * NB * SL * DI;
  float* y1B  = ws + o; o += 2ull * NB * SL * DI;
  float* fTB  = ws + o; o += 2ull * NB * NT * DM;
  float* qkvL = ws + o; o += 3ull * NB * NT * DM;
  float* qkvD = ws + o; o += 3ull * NB * DM * NT;
  float* Pb   = ws + o; o += (size_t)NB * NH * 64 * 64;
  float* attB = ws + o; o += (size_t)NB * DM * NT;
  (void)ws_size; (void)in_sizes; (void)n_in; (void)out_size;

  const int M = NB * SL;  // 788 rows per encoder

  k_rope_init<<<(NT * DM + 255) / 256, 256, 0, stream>>>(cosT, sinT);
  k_patch<<<2 * NB * SL, DM, 0, stream>>>(x1, x2, patch_w, patch_b, cls_tok, pos_emb, hB, resB);

  for (int l = 0; l < NL; ++l) {
    k_rope_res_norm<<<2 * NB * SL, DM, 0, stream>>>(hB, resB, hsB, norm_w, cosT, sinT, l);

    // xz = hs @ in_w^T  (per encoder)
    {
      MM4 p{};
      for (int e = 0; e < 2; ++e) {
        p.A0[e] = hsB + (size_t)e * M * DM;
        p.A1[e] = nullptr;
        p.B[e]  = in_w + (size_t)(e * NL + l) * XZW * DM;
        p.C[e]  = xzB + (size_t)e * M * XZW;
      }
      dim3 g((XZW + 31) / 32, (M + 31) / 32, 2);
      k_mm_nt<<<g, 256, 0, stream>>>(p, M, XZW, DM, 1.f);
    }

    k_conv_silu<<<(2 * 2 * NB * SL * DI + 255) / 256, 256, 0, stream>>>(xzB, conv_w, conv_b, xsB, l);

    // dbl = xs @ xp_w^T (per e,dir)
    {
      MM4 p{};
      for (int z = 0; z < 4; ++z) {
        int e = z / 2, dir = z % 2;
        p.A0[z] = xsB + (size_t)z * M * DI;
        p.A1[z] = nullptr;
        p.B[z]  = xp_w + ((size_t)(e * NL + l) * 2 + dir) * DBLW * DI;
        p.C[z]  = dblB + (size_t)z * M * DBLW;
      }
      dim3 g((DBLW + 31) / 32, (M + 31) / 32, 4);
      k_mm_nt<<<g, 256, 0, stream>>>(p, M, DBLW, DI, 1.f);
    }

    k_delta<<<(2 * 2 * NB * SL * DI + 255) / 256, 256, 0, stream>>>(dblB, dt_w, dt_b, delB, l);

    k_scan<<<2 * 2 * NB * (DI / 16), 256, 0, stream>>>(xsB, delB, dblB, xzB, A_log, Dp, y0B, y1B, l);

    // h = 0.5*(y0+y1) @ out_w^T (per encoder)
    {
      MM4 p{};
      for (int e = 0; e < 2; ++e) {
        p.A0[e] = y0B + (size_t)e * M * DI;
        p.A1[e] = y1B + (size_t)e * M * DI;
        p.B[e]  = out_w + (size_t)(e * NL + l) * DM * DI;
        p.C[e]  = hB + (size_t)e * M * DM;
      }
      dim3 g((DM + 31) / 32, (M + 31) / 32, 2);
      k_mm_nt<<<g, 256, 0, stream>>>(p, M, DM, DI, 0.5f);
    }
  }

  k_final_norm<<<2 * NB * NT, DM, 0, stream>>>(hB, resB, normf_w, fTB);

  // q/k/v linear: q from f1 (e=0), k,v from f2 (e=1)
  {
    MM4 p{};
    const int Mq = NB * NT;  // 784
    p.A0[0] = fTB;                                p.A1[0] = nullptr; p.B[0] = qw; p.C[0] = qkvL;
    p.A0[1] = fTB + (size_t)NB * NT * DM;         p.A1[1] = nullptr; p.B[1] = kw; p.C[1] = qkvL + (size_t)Mq * DM;
    p.A0[2] = fTB + (size_t)NB * NT * DM;         p.A1[2] = nullptr; p.B[2] = vw; p.C[2] = qkvL + 2ull * Mq * DM;
    dim3 g((DM + 31) / 32, (Mq + 31) / 32, 3);
    k_mm_nt<<<g, 256, 0, stream>>>(p, Mq, DM, DM, 1.f);
  }

  k_dwconv<<<(3 * NB * DM * NT + 255) / 256, 256, 0, stream>>>(qkvL, qdw, kdw, vdw, qkvD);
  k_l2norm<<<2 * NB * DM, 256, 0, stream>>>(qkvD);
  k_attn_sm<<<NB * NH * 64, 64, 0, stream>>>(qkvD, temp, Pb);
  k_av<<<NB * NH * 64, 256, 0, stream>>>(Pb, qkvD, attB);
  k_out<<<NB * DM, 256, 0, stream>>>(attB, pww, (float*)d_out);
}

// Round 4
// 5227.636 us; speedup vs baseline: 1.2923x; 1.0341x over previous
//
#include <hip/hip_runtime.h>

#define DM 192      // D_MODEL
#define DI 384      // D_INNER
#define DSt 16      // D_STATE
#define DTR 12      // DT_RANK
#define DC 4        // D_CONV
#define NL 24       // DEPTH
#define HP 14
#define NH 3
#define NB 4        // BATCH
#define SL 197      // seq len (tokens + cls)
#define NT 196      // spatial tokens
#define XZW 768     // 2*D_INNER
#define DBLW 44     // DT_RANK + 2*D_STATE
#define TC 32       // scan chunk (steps staged in LDS)
#define NCHK 7      // ceil(197/32)

static __device__ __forceinline__ float siluf(float x) { return x / (1.f + expf(-x)); }
static __device__ __forceinline__ float softplusf(float x) { return (x > 20.f) ? x : log1pf(expf(x)); }

// ---- block reduce helpers ----
static __device__ __forceinline__ float blk_sum3(float v, float* wsum) {
  for (int off = 32; off; off >>= 1) v += __shfl_xor(v, off, 64);
  int wid = threadIdx.x >> 6;
  if ((threadIdx.x & 63) == 0) wsum[wid] = v;
  __syncthreads();
  return wsum[0] + wsum[1] + wsum[2];
}
static __device__ __forceinline__ float blk_sum4(float v, float* wsum) {
  for (int off = 32; off; off >>= 1) v += __shfl_xor(v, off, 64);
  int wid = threadIdx.x >> 6;
  if ((threadIdx.x & 63) == 0) wsum[wid] = v;
  __syncthreads();
  return wsum[0] + wsum[1] + wsum[2] + wsum[3];
}

// ---- rope tables: cos/sin (196,192) ----
__global__ void k_rope_init(float* __restrict__ cosT, float* __restrict__ sinT) {
  int gid = blockIdx.x * blockDim.x + threadIdx.x;
  if (gid >= NT * DM) return;
  int c = gid % DM, tk = gid / DM;
  int py = tk / HP, px = tk % HP;
  int pos = (c < 96) ? py : px;
  int i = (c < 96) ? (c >> 1) : ((c - 96) >> 1);
  double fb = pow(10000.0, -((double)(2 * i)) / 96.0);
  double ang = (double)pos * fb;
  cosT[gid] = (float)cos(ang);
  sinT[gid] = (float)sin(ang);
}

// ---- im2col: P (2, 784, 768) patch matrix ----
__global__ void k_im2col(const float* __restrict__ x1, const float* __restrict__ x2,
                         float* __restrict__ P) {
  int gid = blockIdx.x * blockDim.x + threadIdx.x;
  if (gid >= 2 * 784 * 768) return;
  int col = gid % 768;
  int row = (gid / 768) % 784;
  int e = gid / (768 * 784);
  int b = row / NT, tk = row % NT;
  int c = col >> 8, r = (col >> 4) & 15, xx = col & 15;
  int py = tk / HP, px = tk % HP;
  const float* img = e ? x2 : x1;
  P[gid] = img[((size_t)(b * 3 + c) * 224 + (py * 16 + r)) * 224 + (px * 16 + xx)];
}

// ---- patch epilogue: h = mm_out + pb + pos (cls row special); res = 0 ----
__global__ void k_patch_fin(const float* __restrict__ pm, const float* __restrict__ pb,
                            const float* __restrict__ cls, const float* __restrict__ pos,
                            float* __restrict__ h, float* __restrict__ res) {
  int gid = blockIdx.x * blockDim.x + threadIdx.x;
  if (gid >= 2 * NB * SL * DM) return;
  int c = gid % DM;
  int t = (gid / DM) % SL;
  int b = (gid / (DM * SL)) % NB;
  int e = gid / (DM * SL * NB);
  float v;
  if (t == 0) v = cls[e * DM + c];
  else v = pm[((size_t)e * 784 + b * NT + (t - 1)) * DM + c] + pb[e * DM + c];
  h[gid] = v + pos[((size_t)e * SL + t) * DM + c];
  res[gid] = 0.f;
}

// ---- per layer: rope(h); res += ; hs = rmsnorm(res)*nw ----
__global__ __launch_bounds__(DM) void k_rope_res_norm(
    const float* __restrict__ h, float* __restrict__ res, float* __restrict__ hs,
    const float* __restrict__ nw, const float* __restrict__ cosT,
    const float* __restrict__ sinT, int l) {
  int bx = blockIdx.x;
  int t = bx % SL; int b = (bx / SL) % NB; int e = bx / (SL * NB);
  int c = threadIdx.x;
  __shared__ float sh[DM];
  __shared__ float wsum[3];
  size_t base = ((size_t)(e * NB + b) * SL + t) * DM;
  sh[c] = h[base + c];
  __syncthreads();
  float v = sh[c];
  if (t > 0) {
    int tk = t - 1;
    float co = cosT[tk * DM + c], si = sinT[tk * DM + c];
    float partner = sh[c ^ 1];
    float rot = (c & 1) ? partner : -partner;
    v = v * co + rot * si;
  }
  float r = res[base + c] + v;
  res[base + c] = r;
  float tot = blk_sum3(r * r, wsum);
  float scale = rsqrtf(tot / (float)DM + 1e-5f);
  hs[base + c] = r * scale * nw[(size_t)(e * NL + l) * DM + c];
}

// ---- generic tiled C = alpha*(A0[+A1]) @ B^T, batched over z via struct ----
struct MM4 {
  const float* A0[4];
  const float* A1[4];
  const float* B[4];
  float* C[4];
};
__global__ __launch_bounds__(256) void k_mm_nt(MM4 p, int M, int N, int K, float alpha) {
  const float* __restrict__ A0 = p.A0[blockIdx.z];
  const float* __restrict__ A1 = p.A1[blockIdx.z];
  const float* __restrict__ Bw = p.B[blockIdx.z];
  float* __restrict__ C = p.C[blockIdx.z];
  __shared__ float As[32][33];
  __shared__ float Bs[32][33];
  int m0 = blockIdx.y * 32, n0 = blockIdx.x * 32;
  int tx = threadIdx.x & 31, ty = threadIdx.x >> 5;
  float acc0 = 0, acc1 = 0, acc2 = 0, acc3 = 0;
  for (int k0 = 0; k0 < K; k0 += 32) {
#pragma unroll
    for (int it = 0; it < 4; ++it) {
      int i = threadIdx.x + it * 256;
      int r = i >> 5, cc = i & 31;
      int gm = m0 + r, gk = k0 + cc;
      float va = 0.f;
      if (gm < M && gk < K) {
        va = A0[(size_t)gm * K + gk];
        if (A1) va += A1[(size_t)gm * K + gk];
      }
      As[r][cc] = va;
      int gn = n0 + r;
      float vb = 0.f;
      if (gn < N && gk < K) vb = Bw[(size_t)gn * K + gk];
      Bs[r][cc] = vb;
    }
    __syncthreads();
#pragma unroll
    for (int kk = 0; kk < 32; ++kk) {
      float bv = Bs[tx][kk];
      acc0 += As[ty][kk] * bv;
      acc1 += As[ty + 8][kk] * bv;
      acc2 += As[ty + 16][kk] * bv;
      acc3 += As[ty + 24][kk] * bv;
    }
    __syncthreads();
  }
  int gn = n0 + tx;
  if (gn < N) {
    int gm = m0 + ty;
    if (gm < M) C[(size_t)gm * N + gn] = alpha * acc0;
    gm += 8; if (gm < M) C[(size_t)gm * N + gn] = alpha * acc1;
    gm += 8; if (gm < M) C[(size_t)gm * N + gn] = alpha * acc2;
    gm += 8; if (gm < M) C[(size_t)gm * N + gn] = alpha * acc3;
  }
}

// ---- causal depthwise conv (k=4) + silu; handles direction reversal ----
__global__ void k_conv_silu(const float* __restrict__ xz, const float* __restrict__ cw,
                            const float* __restrict__ cb, float* __restrict__ xs, int l) {
  int gid = blockIdx.x * blockDim.x + threadIdx.x;
  if (gid >= 2 * 2 * NB * SL * DI) return;
  int d = gid % DI;
  int t = (gid / DI) % SL;
  int b = (gid / (DI * SL)) % NB;
  int dir = (gid / (DI * SL * NB)) % 2;
  int e = gid / (DI * SL * NB * 2);
  size_t pidx = (size_t)(e * NL + l) * 2 + dir;
  const float* cwp = cw + (pidx * DI + d) * DC;
  float acc = cb[pidx * DI + d];
#pragma unroll
  for (int k = 0; k < DC; ++k) {
    int ts = t - (DC - 1) + k;
    if (ts >= 0) {
      int torig = dir ? (SL - 1 - ts) : ts;
      acc += cwp[k] * xz[((size_t)(e * NB + b) * SL + torig) * XZW + d];
    }
  }
  xs[gid] = siluf(acc);
}

// ---- delta = softplus(dt @ dw^T + db) ----
__global__ void k_delta(const float* __restrict__ dbl, const float* __restrict__ dtw,
                        const float* __restrict__ dtb, float* __restrict__ delta, int l) {
  int gid = blockIdx.x * blockDim.x + threadIdx.x;
  if (gid >= 2 * 2 * NB * SL * DI) return;
  int d = gid % DI;
  int t = (gid / DI) % SL;
  int b = (gid / (DI * SL)) % NB;
  int dir = (gid / (DI * SL * NB)) % 2;
  int e = gid / (DI * SL * NB * 2);
  int z = e * 2 + dir;
  size_t pidx = (size_t)(e * NL + l) * 2 + dir;
  const float* row = dbl + ((size_t)(z * NB + b) * SL + t) * DBLW;
  const float* w = dtw + (pidx * DI + d) * DTR;
  float acc = dtb[pidx * DI + d];
#pragma unroll
  for (int r = 0; r < DTR; ++r) acc += row[r] * w[r];
  delta[gid] = softplusf(acc);
}

// ---- selective scan with explicit LDS double-buffered staging ----
// Block = (e,dir,b,dg): 16 channels x 16 states. Chunks of TC=32 steps.
// T14 split: issue global loads to regs early, COMP from LDS, then reg->LDS
// write + one barrier per chunk. Bm/C rows are shared by all 16 channels
// (staged once instead of fetched 16x).
__global__ __launch_bounds__(256) void k_scan(
    const float* __restrict__ xs, const float* __restrict__ delta,
    const float* __restrict__ dbl, const float* __restrict__ xz,
    const float* __restrict__ alog, const float* __restrict__ dpw,
    float* __restrict__ y0, float* __restrict__ y1, int l) {
  int bx = blockIdx.x;
  int dg = bx % (DI / 16);
  int b = (bx / (DI / 16)) % NB;
  int dir = (bx / (DI / 16 * NB)) % 2;
  int e = bx / (DI / 16 * NB * 2);
  int tid = threadIdx.x;
  int n = tid & 15;       // state index (compute role)
  int ch = tid >> 4;      // channel within group (compute role)
  int d = dg * 16 + ch;
  size_t pidx = (size_t)(e * NL + l) * 2 + dir;
  float A = -expf(alog[(pidx * DI + d) * DSt + n]);
  float dpv = dpw[pidx * DI + d];
  int z = e * 2 + dir;
  size_t dblbase = ((size_t)(z * NB + b) * SL) * DBLW;
  float* yout = dir ? y1 : y0;
  size_t ybase = ((size_t)(e * NB + b) * SL) * DI + d;

  // load-role bases
  int lch = tid & 15;       // channel for dv/xv/zv loads
  int ltt = tid >> 4;       // 0..15
  int lj = tid & 31;        // 0..31 (Bm|C)
  int ltt2 = tid >> 5;      // 0..7
  size_t gdbase = ((size_t)(z * NB + b) * SL) * DI + dg * 16 + lch;
  size_t gzbase = ((size_t)(e * NB + b) * SL) * XZW + DI + dg * 16 + lch;

  __shared__ float s_dv[2][TC][16];
  __shared__ float s_xv[2][TC][16];
  __shared__ float s_zv[2][TC][16];
  __shared__ float s_bc[2][TC][32];

  float r_dv[2], r_xv[2], r_zv[2], r_bc[4];

  auto LOADREG = [&](int c) {
    int t0 = c * TC;
#pragma unroll
    for (int k = 0; k < 2; ++k) {
      int t = t0 + ltt + 16 * k;
      int tm = t < SL ? t : SL - 1;
      r_dv[k] = delta[gdbase + (size_t)tm * DI];
      r_xv[k] = xs[gdbase + (size_t)tm * DI];
      int torig = dir ? (SL - 1 - tm) : tm;
      r_zv[k] = xz[gzbase + (size_t)torig * XZW];
    }
#pragma unroll
    for (int k = 0; k < 4; ++k) {
      int t = t0 + ltt2 + 8 * k;
      int tm = t < SL ? t : SL - 1;
      r_bc[k] = dbl[dblbase + (size_t)tm * DBLW + DTR + lj];
    }
  };
  auto STORE = [&](int pb) {
#pragma unroll
    for (int k = 0; k < 2; ++k) {
      s_dv[pb][ltt + 16 * k][lch] = r_dv[k];
      s_xv[pb][ltt + 16 * k][lch] = r_xv[k];
      s_zv[pb][ltt + 16 * k][lch] = r_zv[k];
    }
#pragma unroll
    for (int k = 0; k < 4; ++k) s_bc[pb][ltt2 + 8 * k][lj] = r_bc[k];
  };

  float hst = 0.f;
  auto COMP = [&](int pb, int c) {
    int t0 = c * TC;
#pragma unroll
    for (int i = 0; i < TC; ++i) {
      float dv = s_dv[pb][i][ch];
      float bm = s_bc[pb][i][n];
      float cv = s_bc[pb][i][16 + n];
      float xv = s_xv[pb][i][ch];
      hst = __expf(dv * A) * hst + (dv * xv) * bm;
      float p = hst * cv;
      p += __shfl_xor(p, 1, 64);
      p += __shfl_xor(p, 2, 64);
      p += __shfl_xor(p, 4, 64);
      p += __shfl_xor(p, 8, 64);
      int t = t0 + i;
      if (n == 0 && t < SL) {
        int torig = dir ? (SL - 1 - t) : t;
        float yv = p + xv * dpv;
        yout[ybase + (size_t)torig * DI] = yv * siluf(s_zv[pb][i][ch]);
      }
    }
  };

  LOADREG(0);
  STORE(0);
  LOADREG(1);
  __syncthreads();
  int pb = 0;
#pragma unroll 1
  for (int c = 0; c < NCHK; ++c) {
    COMP(pb, c);
    if (c + 1 < NCHK) {
      STORE(pb ^ 1);
      __syncthreads();
      if (c + 2 < NCHK) LOADREG(c + 2);
      pb ^= 1;
    }
  }
}

// ---- final: rmsnorm(h+res)*nfw, drop cls, token-major fT (e,b,196,192) ----
__global__ __launch_bounds__(DM) void k_final_norm(
    const float* __restrict__ h, const float* __restrict__ res,
    const float* __restrict__ nfw, float* __restrict__ fT) {
  int bx = blockIdx.x;
  int tk = bx % NT; int b = (bx / NT) % NB; int e = bx / (NT * NB);
  int c = threadIdx.x;
  __shared__ float wsum[3];
  size_t base = ((size_t)(e * NB + b) * SL + (tk + 1)) * DM;
  float r = h[base + c] + res[base + c];
  float tot = blk_sum3(r * r, wsum);
  float scale = rsqrtf(tot / (float)DM + 1e-5f);
  fT[((size_t)(e * NB + b) * NT + tk) * DM + c] = r * scale * nfw[e * DM + c];
}

// ---- depthwise 3x3 SAME over 14x14; in token-major, out channel-major ----
__global__ void k_dwconv(const float* __restrict__ qkvl, const float* __restrict__ qdw,
                         const float* __restrict__ kdw, const float* __restrict__ vdw,
                         float* __restrict__ qkvd) {
  int gid = blockIdx.x * blockDim.x + threadIdx.x;
  if (gid >= 3 * NB * DM * NT) return;
  int nn = gid % NT;
  int o = (gid / NT) % DM;
  int b = (gid / (NT * DM)) % NB;
  int zz = gid / (NT * DM * NB);
  const float* wsel = (zz == 0 ? qdw : (zz == 1 ? kdw : vdw)) + o * 9;
  int y = nn / HP, x = nn % HP;
  const float* in = qkvl + ((size_t)zz * NB + b) * NT * DM;
  float acc = 0.f;
#pragma unroll
  for (int ky = 0; ky < 3; ++ky) {
    int yy = y + ky - 1;
    if (yy < 0 || yy >= HP) continue;
#pragma unroll
    for (int kx = 0; kx < 3; ++kx) {
      int xx = x + kx - 1;
      if (xx < 0 || xx >= HP) continue;
      acc += in[(size_t)(yy * HP + xx) * DM + o] * wsel[ky * 3 + kx];
    }
  }
  qkvd[gid] = acc;
}

// ---- L2-normalize q,k rows over n=196 (in place) ----
__global__ __launch_bounds__(256) void k_l2norm(float* __restrict__ qkvd) {
  int bx = blockIdx.x;
  int C = bx % DM; int b = (bx / DM) % NB; int zz = bx / (DM * NB);
  int i = threadIdx.x;
  __shared__ float wsum[4];
  float* row = qkvd + ((size_t)zz * NB + b) * DM * NT + (size_t)C * NT;
  float v = (i < NT) ? row[i] : 0.f;
  float tot = blk_sum4(v * v, wsum);
  float sc = 1.f / fmaxf(sqrtf(tot), 1e-12f);
  if (i < NT) row[i] = v * sc;
}

// ---- S = temp*qn.kn^T, softmax over j (block=(b,h,i), 64 threads=j) ----
__global__ __launch_bounds__(64) void k_attn_sm(const float* __restrict__ qkvd,
                                                const float* __restrict__ temp,
                                                float* __restrict__ P) {
  int bx = blockIdx.x;
  int i = bx % 64; int hh = (bx / 64) % NH; int b = bx / (64 * NH);
  int j = threadIdx.x;
  __shared__ float qs[NT];
  const float* qrow = qkvd + ((size_t)0 * NB + b) * DM * NT + (size_t)(hh * 64 + i) * NT;
  for (int k = j; k < NT; k += 64) qs[k] = qrow[k];
  __syncthreads();
  const float* krow = qkvd + ((size_t)1 * NB + b) * DM * NT + (size_t)(hh * 64 + j) * NT;
  float acc = 0.f;
  for (int k = 0; k < NT; ++k) acc += qs[k] * krow[k];
  acc *= temp[hh];
  float m = acc;
  for (int off = 32; off; off >>= 1) m = fmaxf(m, __shfl_xor(m, off, 64));
  float ex = expf(acc - m);
  float s = ex;
  for (int off = 32; off; off >>= 1) s += __shfl_xor(s, off, 64);
  P[((size_t)(b * NH + hh) * 64 + i) * 64 + j] = ex / s;
}

// ---- out = P @ vh ----
__global__ __launch_bounds__(256) void k_av(const float* __restrict__ P,
                                            const float* __restrict__ qkvd,
                                            float* __restrict__ att) {
  int bx = blockIdx.x;
  int i = bx % 64; int hh = (bx / 64) % NH; int b = bx / (64 * NH);
  int nn = threadIdx.x;
  __shared__ float ps[64];
  if (nn < 64) ps[nn] = P[((size_t)(b * NH + hh) * 64 + i) * 64 + nn];
  __syncthreads();
  if (nn >= NT) return;
  const float* vbase = qkvd + ((size_t)2 * NB + b) * DM * NT + (size_t)(hh * 64) * NT + nn;
  float acc = 0.f;
  for (int j = 0; j < 64; ++j) acc += ps[j] * vbase[(size_t)j * NT];
  att[((size_t)b * DM + hh * 64 + i) * NT + nn] = acc;
}

// ---- final pointwise projection to d_out ----
__global__ __launch_bounds__(256) void k_out(const float* __restrict__ att,
                                             const float* __restrict__ pw,
                                             float* __restrict__ out) {
  int bx = blockIdx.x;
  int o = bx % DM; int b = bx / DM;
  int nn = threadIdx.x;
  if (nn >= NT) return;
  const float* abase = att + (size_t)b * DM * NT + nn;
  const float* w = pw + (size_t)o * DM;
  float acc = 0.f;
  for (int c = 0; c < DM; ++c) acc += abase[(size_t)c * NT] * w[c];
  out[((size_t)b * DM + o) * NT + nn] = acc;
}

extern "C" void kernel_launch(void* const* d_in, const int* in_sizes, int n_in,
                              void* d_out, int out_size, void* d_ws, size_t ws_size,
                              hipStream_t stream) {
  const float* x1      = (const float*)d_in[0];
  const float* x2      = (const float*)d_in[1];
  const float* patch_w = (const float*)d_in[2];
  const float* patch_b = (const float*)d_in[3];
  const float* cls_tok = (const float*)d_in[4];
  const float* pos_emb = (const float*)d_in[5];
  const float* norm_w  = (const float*)d_in[6];
  const float* in_w    = (const float*)d_in[7];
  const float* conv_w  = (const float*)d_in[8];
  const float* conv_b  = (const float*)d_in[9];
  const float* xp_w    = (const float*)d_in[10];
  const float* dt_w    = (const float*)d_in[11];
  const float* dt_b    = (const float*)d_in[12];
  const float* A_log   = (const float*)d_in[13];
  const float* Dp      = (const float*)d_in[14];
  const float* out_w   = (const float*)d_in[15];
  const float* normf_w = (const float*)d_in[16];
  const float* qw      = (const float*)d_in[17];
  const float* qdw     = (const float*)d_in[18];
  const float* kw      = (const float*)d_in[19];
  const float* kdw     = (const float*)d_in[20];
  const float* vw      = (const float*)d_in[21];
  const float* vdw     = (const float*)d_in[22];
  const float* pww     = (const float*)d_in[23];
  const float* temp    = (const float*)d_in[24];

  float* ws = (float*)d_ws;
  size_t o = 0;
  float* cosT = ws + o; o += (size_t)NT * DM;
  float* sinT = ws + o; o += (size_t)NT * DM;
  float* hB   = ws + o; o += 2ull * NB * SL * DM;
  float* resB = ws + o; o += 2ull * NB * SL * DM;
  float* hsB  = ws + o; o += 2ull * NB * SL * DM;
  float* xzB  = ws + o; o += 2ull * NB * SL * XZW;
  float* xsB  = ws + o; o += 4ull * NB * SL * DI;
  float* dblB = ws + o; o += 4ull * NB * SL * DBLW;
  float* delB = ws + o; o += 4ull * NB * SL * DI;   // aliased as im2col P before layers
  float* y0B  = ws + o; o += 2ull * NB * SL * DI;   // aliased as patch mm out before layers
  float* y1B  = ws + o; o += 2ull * NB * SL * DI;
  float* fTB  = ws + o; o += 2ull * NB * NT * DM;
  float* qkvL = ws + o; o += 3ull * NB * NT * DM;
  float* qkvD = ws + o; o += 3ull * NB * DM * NT;
  float* Pb   = ws + o; o += (size_t)NB * NH * 64 * 64;
  float* attB = ws + o; o += (size_t)NB * DM * NT;
  (void)ws_size; (void)in_sizes; (void)n_in; (void)out_size;

  const int M = NB * SL;  // 788 rows per encoder

  k_rope_init<<<(NT * DM + 255) / 256, 256, 0, stream>>>(cosT, sinT);

  // patch embed as im2col + GEMM + epilogue (delB/y0B reused as scratch here)
  float* Pm = delB;       // (2, 784, 768) = 1.2M floats <= delB's 2.42M
  float* Pout = y0B;      // (2, 784, 192) = 301k floats <= y0B's 1.21M
  k_im2col<<<(2 * 784 * 768 + 255) / 256, 256, 0, stream>>>(x1, x2, Pm);
  {
    MM4 p{};
    for (int e = 0; e < 2; ++e) {
      p.A0[e] = Pm + (size_t)e * 784 * 768;
      p.A1[e] = nullptr;
      p.B[e]  = patch_w + (size_t)e * DM * 768;
      p.C[e]  = Pout + (size_t)e * 784 * DM;
    }
    dim3 g((DM + 31) / 32, (784 + 31) / 32, 2);
    k_mm_nt<<<g, 256, 0, stream>>>(p, 784, DM, 768, 1.f);
  }
  k_patch_fin<<<(2 * NB * SL * DM + 255) / 256, 256, 0, stream>>>(
      Pout, patch_b, cls_tok, pos_emb, hB, resB);

  for (int l = 0; l < NL; ++l) {
    k_rope_res_norm<<<2 * NB * SL, DM, 0, stream>>>(hB, resB, hsB, norm_w, cosT, sinT, l);

    // xz = hs @ in_w^T  (per encoder)
    {
      MM4 p{};
      for (int e = 0; e < 2; ++e) {
        p.A0[e] = hsB + (size_t)e * M * DM;
        p.A1[e] = nullptr;
        p.B[e]  = in_w + (size_t)(e * NL + l) * XZW * DM;
        p.C[e]  = xzB + (size_t)e * M * XZW;
      }
      dim3 g((XZW + 31) / 32, (M + 31) / 32, 2);
      k_mm_nt<<<g, 256, 0, stream>>>(p, M, XZW, DM, 1.f);
    }

    k_conv_silu<<<(2 * 2 * NB * SL * DI + 255) / 256, 256, 0, stream>>>(xzB, conv_w, conv_b, xsB, l);

    // dbl = xs @ xp_w^T (per e,dir)
    {
      MM4 p{};
      for (int z = 0; z < 4; ++z) {
        int e = z / 2, dir = z % 2;
        p.A0[z] = xsB + (size_t)z * M * DI;
        p.A1[z] = nullptr;
        p.B[z]  = xp_w + ((size_t)(e * NL + l) * 2 + dir) * DBLW * DI;
        p.C[z]  = dblB + (size_t)z * M * DBLW;
      }
      dim3 g((DBLW + 31) / 32, (M + 31) / 32, 4);
      k_mm_nt<<<g, 256, 0, stream>>>(p, M, DBLW, DI, 1.f);
    }

    k_delta<<<(2 * 2 * NB * SL * DI + 255) / 256, 256, 0, stream>>>(dblB, dt_w, dt_b, delB, l);

    k_scan<<<2 * 2 * NB * (DI / 16), 256, 0, stream>>>(xsB, delB, dblB, xzB, A_log, Dp, y0B, y1B, l);

    // h = 0.5*(y0+y1) @ out_w^T (per encoder)
    {
      MM4 p{};
      for (int e = 0; e < 2; ++e) {
        p.A0[e] = y0B + (size_t)e * M * DI;
        p.A1[e] = y1B + (size_t)e * M * DI;
        p.B[e]  = out_w + (size_t)(e * NL + l) * DM * DI;
        p.C[e]  = hB + (size_t)e * M * DM;
      }
      dim3 g((DM + 31) / 32, (M + 31) / 32, 2);
      k_mm_nt<<<g, 256, 0, stream>>>(p, M, DM, DI, 0.5f);
    }
  }

  k_final_norm<<<2 * NB * NT, DM, 0, stream>>>(hB, resB, normf_w, fTB);

  // q/k/v linear: q from f1 (e=0), k,v from f2 (e=1)
  {
    MM4 p{};
    const int Mq = NB * NT;  // 784
    p.A0[0] = fTB;                                p.A1[0] = nullptr; p.B[0] = qw; p.C[0] = qkvL;
    p.A0[1] = fTB + (size_t)NB * NT * DM;         p.A1[1] = nullptr; p.B[1] = kw; p.C[1] = qkvL + (size_t)Mq * DM;
    p.A0[2] = fTB + (size_t)NB * NT * DM;         p.A1[2] = nullptr; p.B[2] = vw; p.C[2] = qkvL + 2ull * Mq * DM;
    dim3 g((DM + 31) / 32, (Mq + 31) / 32, 3);
    k_mm_nt<<<g, 256, 0, stream>>>(p, Mq, DM, DM, 1.f);
  }

  k_dwconv<<<(3 * NB * DM * NT + 255) / 256, 256, 0, stream>>>(qkvL, qdw, kdw, vdw, qkvD);
  k_l2norm<<<2 * NB * DM, 256, 0, stream>>>(qkvD);
  k_attn_sm<<<NB * NH * 64, 64, 0, stream>>>(qkvD, temp, Pb);
  k_av<<<NB * NH * 64, 256, 0, stream>>>(Pb, qkvD, attB);
  k_out<<<NB * DM, 256, 0, stream>>>(attB, pww, (float*)d_out);
}

// Round 5
// 3794.249 us; speedup vs baseline: 1.7804x; 1.3778x over previous
//
#include <hip/hip_runtime.h>

#define DM 192      // D_MODEL
#define DI 384      // D_INNER
#define DSt 16      // D_STATE
#define DTR 12      // DT_RANK
#define DC 4        // D_CONV
#define NL 24       // DEPTH
#define HP 14
#define NH 3
#define NB 4        // BATCH
#define SL 197      // seq len (tokens + cls)
#define NT 196      // spatial tokens
#define XZW 768     // 2*D_INNER
#define DBLW 44     // DT_RANK + 2*D_STATE
#define TC 32       // scan chunk (steps staged in LDS)
#define NCHK 7      // ceil(197/32)

static __device__ __forceinline__ float siluf(float x) { return x / (1.f + expf(-x)); }
static __device__ __forceinline__ float softplusf(float x) { return (x > 20.f) ? x : log1pf(expf(x)); }

// ---- block reduce helpers ----
static __device__ __forceinline__ float blk_sum3(float v, float* wsum) {
  for (int off = 32; off; off >>= 1) v += __shfl_xor(v, off, 64);
  int wid = threadIdx.x >> 6;
  if ((threadIdx.x & 63) == 0) wsum[wid] = v;
  __syncthreads();
  return wsum[0] + wsum[1] + wsum[2];
}
static __device__ __forceinline__ float blk_sum4(float v, float* wsum) {
  for (int off = 32; off; off >>= 1) v += __shfl_xor(v, off, 64);
  int wid = threadIdx.x >> 6;
  if ((threadIdx.x & 63) == 0) wsum[wid] = v;
  __syncthreads();
  return wsum[0] + wsum[1] + wsum[2] + wsum[3];
}

// ---- rope tables: cos/sin (196,192) ----
__global__ void k_rope_init(float* __restrict__ cosT, float* __restrict__ sinT) {
  int gid = blockIdx.x * blockDim.x + threadIdx.x;
  if (gid >= NT * DM) return;
  int c = gid % DM, tk = gid / DM;
  int py = tk / HP, px = tk % HP;
  int pos = (c < 96) ? py : px;
  int i = (c < 96) ? (c >> 1) : ((c - 96) >> 1);
  double fb = pow(10000.0, -((double)(2 * i)) / 96.0);
  double ang = (double)pos * fb;
  cosT[gid] = (float)cos(ang);
  sinT[gid] = (float)sin(ang);
}

// ---- im2col: P (2, 784, 768) patch matrix ----
__global__ void k_im2col(const float* __restrict__ x1, const float* __restrict__ x2,
                         float* __restrict__ P) {
  int gid = blockIdx.x * blockDim.x + threadIdx.x;
  if (gid >= 2 * 784 * 768) return;
  int col = gid % 768;
  int row = (gid / 768) % 784;
  int e = gid / (768 * 784);
  int b = row / NT, tk = row % NT;
  int c = col >> 8, r = (col >> 4) & 15, xx = col & 15;
  int py = tk / HP, px = tk % HP;
  const float* img = e ? x2 : x1;
  P[gid] = img[((size_t)(b * 3 + c) * 224 + (py * 16 + r)) * 224 + (px * 16 + xx)];
}

// ---- patch epilogue: h = mm_out + pb + pos (cls row special); res = 0 ----
__global__ void k_patch_fin(const float* __restrict__ pm, const float* __restrict__ pb,
                            const float* __restrict__ cls, const float* __restrict__ pos,
                            float* __restrict__ h, float* __restrict__ res) {
  int gid = blockIdx.x * blockDim.x + threadIdx.x;
  if (gid >= 2 * NB * SL * DM) return;
  int c = gid % DM;
  int t = (gid / DM) % SL;
  int b = (gid / (DM * SL)) % NB;
  int e = gid / (DM * SL * NB);
  float v;
  if (t == 0) v = cls[e * DM + c];
  else v = pm[((size_t)e * 784 + b * NT + (t - 1)) * DM + c] + pb[e * DM + c];
  h[gid] = v + pos[((size_t)e * SL + t) * DM + c];
  res[gid] = 0.f;
}

// ---- per layer: rope(h); res += ; hs = rmsnorm(res)*nw ----
__global__ __launch_bounds__(DM) void k_rope_res_norm(
    const float* __restrict__ h, float* __restrict__ res, float* __restrict__ hs,
    const float* __restrict__ nw, const float* __restrict__ cosT,
    const float* __restrict__ sinT, int l) {
  int bx = blockIdx.x;
  int t = bx % SL; int b = (bx / SL) % NB; int e = bx / (SL * NB);
  int c = threadIdx.x;
  __shared__ float sh[DM];
  __shared__ float wsum[3];
  size_t base = ((size_t)(e * NB + b) * SL + t) * DM;
  sh[c] = h[base + c];
  __syncthreads();
  float v = sh[c];
  if (t > 0) {
    int tk = t - 1;
    float co = cosT[tk * DM + c], si = sinT[tk * DM + c];
    float partner = sh[c ^ 1];
    float rot = (c & 1) ? partner : -partner;
    v = v * co + rot * si;
  }
  float r = res[base + c] + v;
  res[base + c] = r;
  float tot = blk_sum3(r * r, wsum);
  float scale = rsqrtf(tot / (float)DM + 1e-5f);
  hs[base + c] = r * scale * nw[(size_t)(e * NL + l) * DM + c];
}

// ---- register-blocked tiled GEMM: C = alpha*(A0[+A1]) @ B^T ----
// 64x64 tile, BK=16, 256 threads, 4x4 outputs/thread via float4 outer product.
// Transposed LDS tiles As/Bs[k][m] (pad 68 keeps float4 reads 2-way-max).
// Next k-tile global loads issued before compute: latency hides under FMAs.
struct MM4 {
  const float* A0[4];
  const float* A1[4];
  const float* B[4];
  float* C[4];
};
__global__ __launch_bounds__(256) void k_mm64(MM4 p, int M, int N, int K, float alpha) {
  const float* __restrict__ A0 = p.A0[blockIdx.z];
  const float* __restrict__ A1 = p.A1[blockIdx.z];
  const float* __restrict__ Bw = p.B[blockIdx.z];
  float* __restrict__ C = p.C[blockIdx.z];
  __shared__ __align__(16) float As[16][68];
  __shared__ __align__(16) float Bs[16][68];
  int tid = threadIdx.x;
  int m0 = blockIdx.y * 64, n0 = blockIdx.x * 64;
  int tm = tid >> 4, tn = tid & 15;       // compute roles
  int srow = tid >> 2, skq = tid & 3;     // staging roles
  int gmA = min(m0 + srow, M - 1);
  int gnB = min(n0 + srow, N - 1);
  bool hasA1 = (A1 != nullptr);
  float4 ra, rb, ra1;

  auto GLOAD = [&](int k0) {
    ra = *(const float4*)&A0[(size_t)gmA * K + k0 + skq * 4];
    if (hasA1) ra1 = *(const float4*)&A1[(size_t)gmA * K + k0 + skq * 4];
    rb = *(const float4*)&Bw[(size_t)gnB * K + k0 + skq * 4];
  };
  auto DSW = [&]() {
    float av0 = ra.x, av1 = ra.y, av2 = ra.z, av3 = ra.w;
    if (hasA1) { av0 += ra1.x; av1 += ra1.y; av2 += ra1.z; av3 += ra1.w; }
    int kb = skq * 4;
    As[kb + 0][srow] = av0;
    As[kb + 1][srow] = av1;
    As[kb + 2][srow] = av2;
    As[kb + 3][srow] = av3;
    Bs[kb + 0][srow] = rb.x;
    Bs[kb + 1][srow] = rb.y;
    Bs[kb + 2][srow] = rb.z;
    Bs[kb + 3][srow] = rb.w;
  };

  float acc[4][4] = {};
  int T = K >> 4;
  GLOAD(0);
  DSW();
  __syncthreads();
#pragma unroll 1
  for (int kt = 1; kt <= T; ++kt) {
    if (kt < T) GLOAD(kt * 16);
#pragma unroll
    for (int kk = 0; kk < 16; ++kk) {
      float4 a = *(const float4*)&As[kk][tm * 4];
      float4 b = *(const float4*)&Bs[kk][tn * 4];
      float av[4] = {a.x, a.y, a.z, a.w};
      float bv[4] = {b.x, b.y, b.z, b.w};
#pragma unroll
      for (int mi = 0; mi < 4; ++mi)
#pragma unroll
        for (int ni = 0; ni < 4; ++ni)
          acc[mi][ni] += av[mi] * bv[ni];
    }
    if (kt < T) {
      __syncthreads();
      DSW();
      __syncthreads();
    }
  }
#pragma unroll
  for (int mi = 0; mi < 4; ++mi) {
    int gm = m0 + tm * 4 + mi;
    if (gm >= M) continue;
    int gn = n0 + tn * 4;
    if (gn + 3 < N) {
      float4 o4 = make_float4(alpha * acc[mi][0], alpha * acc[mi][1],
                              alpha * acc[mi][2], alpha * acc[mi][3]);
      *(float4*)&C[(size_t)gm * N + gn] = o4;
    } else {
#pragma unroll
      for (int ni = 0; ni < 4; ++ni)
        if (gn + ni < N) C[(size_t)gm * N + gn + ni] = alpha * acc[mi][ni];
    }
  }
}

// ---- causal depthwise conv (k=4) + silu; handles direction reversal ----
__global__ void k_conv_silu(const float* __restrict__ xz, const float* __restrict__ cw,
                            const float* __restrict__ cb, float* __restrict__ xs, int l) {
  int gid = blockIdx.x * blockDim.x + threadIdx.x;
  if (gid >= 2 * 2 * NB * SL * DI) return;
  int d = gid % DI;
  int t = (gid / DI) % SL;
  int b = (gid / (DI * SL)) % NB;
  int dir = (gid / (DI * SL * NB)) % 2;
  int e = gid / (DI * SL * NB * 2);
  size_t pidx = (size_t)(e * NL + l) * 2 + dir;
  const float* cwp = cw + (pidx * DI + d) * DC;
  float acc = cb[pidx * DI + d];
#pragma unroll
  for (int k = 0; k < DC; ++k) {
    int ts = t - (DC - 1) + k;
    if (ts >= 0) {
      int torig = dir ? (SL - 1 - ts) : ts;
      acc += cwp[k] * xz[((size_t)(e * NB + b) * SL + torig) * XZW + d];
    }
  }
  xs[gid] = siluf(acc);
}

// ---- delta = softplus(dt @ dw^T + db) ----
__global__ void k_delta(const float* __restrict__ dbl, const float* __restrict__ dtw,
                        const float* __restrict__ dtb, float* __restrict__ delta, int l) {
  int gid = blockIdx.x * blockDim.x + threadIdx.x;
  if (gid >= 2 * 2 * NB * SL * DI) return;
  int d = gid % DI;
  int t = (gid / DI) % SL;
  int b = (gid / (DI * SL)) % NB;
  int dir = (gid / (DI * SL * NB)) % 2;
  int e = gid / (DI * SL * NB * 2);
  int z = e * 2 + dir;
  size_t pidx = (size_t)(e * NL + l) * 2 + dir;
  const float* row = dbl + ((size_t)(z * NB + b) * SL + t) * DBLW;
  const float* w = dtw + (pidx * DI + d) * DTR;
  float acc = dtb[pidx * DI + d];
#pragma unroll
  for (int r = 0; r < DTR; ++r) acc += row[r] * w[r];
  delta[gid] = softplusf(acc);
}

// ---- selective scan with explicit LDS double-buffered staging ----
__global__ __launch_bounds__(256) void k_scan(
    const float* __restrict__ xs, const float* __restrict__ delta,
    const float* __restrict__ dbl, const float* __restrict__ xz,
    const float* __restrict__ alog, const float* __restrict__ dpw,
    float* __restrict__ y0, float* __restrict__ y1, int l) {
  int bx = blockIdx.x;
  int dg = bx % (DI / 16);
  int b = (bx / (DI / 16)) % NB;
  int dir = (bx / (DI / 16 * NB)) % 2;
  int e = bx / (DI / 16 * NB * 2);
  int tid = threadIdx.x;
  int n = tid & 15;       // state index (compute role)
  int ch = tid >> 4;      // channel within group (compute role)
  int d = dg * 16 + ch;
  size_t pidx = (size_t)(e * NL + l) * 2 + dir;
  float A = -expf(alog[(pidx * DI + d) * DSt + n]);
  float dpv = dpw[pidx * DI + d];
  int z = e * 2 + dir;
  size_t dblbase = ((size_t)(z * NB + b) * SL) * DBLW;
  float* yout = dir ? y1 : y0;
  size_t ybase = ((size_t)(e * NB + b) * SL) * DI + d;

  // load-role bases
  int lch = tid & 15;       // channel for dv/xv/zv loads
  int ltt = tid >> 4;       // 0..15
  int lj = tid & 31;        // 0..31 (Bm|C)
  int ltt2 = tid >> 5;      // 0..7
  size_t gdbase = ((size_t)(z * NB + b) * SL) * DI + dg * 16 + lch;
  size_t gzbase = ((size_t)(e * NB + b) * SL) * XZW + DI + dg * 16 + lch;

  __shared__ float s_dv[2][TC][16];
  __shared__ float s_xv[2][TC][16];
  __shared__ float s_zv[2][TC][16];
  __shared__ float s_bc[2][TC][32];

  float r_dv[2], r_xv[2], r_zv[2], r_bc[4];

  auto LOADREG = [&](int c) {
    int t0 = c * TC;
#pragma unroll
    for (int k = 0; k < 2; ++k) {
      int t = t0 + ltt + 16 * k;
      int tm = t < SL ? t : SL - 1;
      r_dv[k] = delta[gdbase + (size_t)tm * DI];
      r_xv[k] = xs[gdbase + (size_t)tm * DI];
      int torig = dir ? (SL - 1 - tm) : tm;
      r_zv[k] = xz[gzbase + (size_t)torig * XZW];
    }
#pragma unroll
    for (int k = 0; k < 4; ++k) {
      int t = t0 + ltt2 + 8 * k;
      int tm = t < SL ? t : SL - 1;
      r_bc[k] = dbl[dblbase + (size_t)tm * DBLW + DTR + lj];
    }
  };
  auto STORE = [&](int pb) {
#pragma unroll
    for (int k = 0; k < 2; ++k) {
      s_dv[pb][ltt + 16 * k][lch] = r_dv[k];
      s_xv[pb][ltt + 16 * k][lch] = r_xv[k];
      s_zv[pb][ltt + 16 * k][lch] = r_zv[k];
    }
#pragma unroll
    for (int k = 0; k < 4; ++k) s_bc[pb][ltt2 + 8 * k][lj] = r_bc[k];
  };

  float hst = 0.f;
  auto COMP = [&](int pb, int c) {
    int t0 = c * TC;
#pragma unroll
    for (int i = 0; i < TC; ++i) {
      float dv = s_dv[pb][i][ch];
      float bm = s_bc[pb][i][n];
      float cv = s_bc[pb][i][16 + n];
      float xv = s_xv[pb][i][ch];
      hst = __expf(dv * A) * hst + (dv * xv) * bm;
      float p = hst * cv;
      p += __shfl_xor(p, 1, 64);
      p += __shfl_xor(p, 2, 64);
      p += __shfl_xor(p, 4, 64);
      p += __shfl_xor(p, 8, 64);
      int t = t0 + i;
      if (n == 0 && t < SL) {
        int torig = dir ? (SL - 1 - t) : t;
        float yv = p + xv * dpv;
        yout[ybase + (size_t)torig * DI] = yv * siluf(s_zv[pb][i][ch]);
      }
    }
  };

  LOADREG(0);
  STORE(0);
  LOADREG(1);
  __syncthreads();
  int pb = 0;
#pragma unroll 1
  for (int c = 0; c < NCHK; ++c) {
    COMP(pb, c);
    if (c + 1 < NCHK) {
      STORE(pb ^ 1);
      __syncthreads();
      if (c + 2 < NCHK) LOADREG(c + 2);
      pb ^= 1;
    }
  }
}

// ---- final: rmsnorm(h+res)*nfw, drop cls, token-major fT (e,b,196,192) ----
__global__ __launch_bounds__(DM) void k_final_norm(
    const float* __restrict__ h, const float* __restrict__ res,
    const float* __restrict__ nfw, float* __restrict__ fT) {
  int bx = blockIdx.x;
  int tk = bx % NT; int b = (bx / NT) % NB; int e = bx / (NT * NB);
  int c = threadIdx.x;
  __shared__ float wsum[3];
  size_t base = ((size_t)(e * NB + b) * SL + (tk + 1)) * DM;
  float r = h[base + c] + res[base + c];
  float tot = blk_sum3(r * r, wsum);
  float scale = rsqrtf(tot / (float)DM + 1e-5f);
  fT[((size_t)(e * NB + b) * NT + tk) * DM + c] = r * scale * nfw[e * DM + c];
}

// ---- depthwise 3x3 SAME over 14x14; in token-major, out channel-major ----
__global__ void k_dwconv(const float* __restrict__ qkvl, const float* __restrict__ qdw,
                         const float* __restrict__ kdw, const float* __restrict__ vdw,
                         float* __restrict__ qkvd) {
  int gid = blockIdx.x * blockDim.x + threadIdx.x;
  if (gid >= 3 * NB * DM * NT) return;
  int nn = gid % NT;
  int o = (gid / NT) % DM;
  int b = (gid / (NT * DM)) % NB;
  int zz = gid / (NT * DM * NB);
  const float* wsel = (zz == 0 ? qdw : (zz == 1 ? kdw : vdw)) + o * 9;
  int y = nn / HP, x = nn % HP;
  const float* in = qkvl + ((size_t)zz * NB + b) * NT * DM;
  float acc = 0.f;
#pragma unroll
  for (int ky = 0; ky < 3; ++ky) {
    int yy = y + ky - 1;
    if (yy < 0 || yy >= HP) continue;
#pragma unroll
    for (int kx = 0; kx < 3; ++kx) {
      int xx = x + kx - 1;
      if (xx < 0 || xx >= HP) continue;
      acc += in[(size_t)(yy * HP + xx) * DM + o] * wsel[ky * 3 + kx];
    }
  }
  qkvd[gid] = acc;
}

// ---- L2-normalize q,k rows over n=196 (in place) ----
__global__ __launch_bounds__(256) void k_l2norm(float* __restrict__ qkvd) {
  int bx = blockIdx.x;
  int C = bx % DM; int b = (bx / DM) % NB; int zz = bx / (DM * NB);
  int i = threadIdx.x;
  __shared__ float wsum[4];
  float* row = qkvd + ((size_t)zz * NB + b) * DM * NT + (size_t)C * NT;
  float v = (i < NT) ? row[i] : 0.f;
  float tot = blk_sum4(v * v, wsum);
  float sc = 1.f / fmaxf(sqrtf(tot), 1e-12f);
  if (i < NT) row[i] = v * sc;
}

// ---- S = temp*qn.kn^T, softmax over j (block=(b,h,i), 64 threads=j) ----
__global__ __launch_bounds__(64) void k_attn_sm(const float* __restrict__ qkvd,
                                                const float* __restrict__ temp,
                                                float* __restrict__ P) {
  int bx = blockIdx.x;
  int i = bx % 64; int hh = (bx / 64) % NH; int b = bx / (64 * NH);
  int j = threadIdx.x;
  __shared__ float qs[NT];
  const float* qrow = qkvd + ((size_t)0 * NB + b) * DM * NT + (size_t)(hh * 64 + i) * NT;
  for (int k = j; k < NT; k += 64) qs[k] = qrow[k];
  __syncthreads();
  const float* krow = qkvd + ((size_t)1 * NB + b) * DM * NT + (size_t)(hh * 64 + j) * NT;
  float acc = 0.f;
  for (int k = 0; k < NT; ++k) acc += qs[k] * krow[k];
  acc *= temp[hh];
  float m = acc;
  for (int off = 32; off; off >>= 1) m = fmaxf(m, __shfl_xor(m, off, 64));
  float ex = expf(acc - m);
  float s = ex;
  for (int off = 32; off; off >>= 1) s += __shfl_xor(s, off, 64);
  P[((size_t)(b * NH + hh) * 64 + i) * 64 + j] = ex / s;
}

// ---- out = P @ vh ----
__global__ __launch_bounds__(256) void k_av(const float* __restrict__ P,
                                            const float* __restrict__ qkvd,
                                            float* __restrict__ att) {
  int bx = blockIdx.x;
  int i = bx % 64; int hh = (bx / 64) % NH; int b = bx / (64 * NH);
  int nn = threadIdx.x;
  __shared__ float ps[64];
  if (nn < 64) ps[nn] = P[((size_t)(b * NH + hh) * 64 + i) * 64 + nn];
  __syncthreads();
  if (nn >= NT) return;
  const float* vbase = qkvd + ((size_t)2 * NB + b) * DM * NT + (size_t)(hh * 64) * NT + nn;
  float acc = 0.f;
  for (int j = 0; j < 64; ++j) acc += ps[j] * vbase[(size_t)j * NT];
  att[((size_t)b * DM + hh * 64 + i) * NT + nn] = acc;
}

// ---- final pointwise projection to d_out ----
__global__ __launch_bounds__(256) void k_out(const float* __restrict__ att,
                                             const float* __restrict__ pw,
                                             float* __restrict__ out) {
  int bx = blockIdx.x;
  int o = bx % DM; int b = bx / DM;
  int nn = threadIdx.x;
  if (nn >= NT) return;
  const float* abase = att + (size_t)b * DM * NT + nn;
  const float* w = pw + (size_t)o * DM;
  float acc = 0.f;
  for (int c = 0; c < DM; ++c) acc += abase[(size_t)c * NT] * w[c];
  out[((size_t)b * DM + o) * NT + nn] = acc;
}

extern "C" void kernel_launch(void* const* d_in, const int* in_sizes, int n_in,
                              void* d_out, int out_size, void* d_ws, size_t ws_size,
                              hipStream_t stream) {
  const float* x1      = (const float*)d_in[0];
  const float* x2      = (const float*)d_in[1];
  const float* patch_w = (const float*)d_in[2];
  const float* patch_b = (const float*)d_in[3];
  const float* cls_tok = (const float*)d_in[4];
  const float* pos_emb = (const float*)d_in[5];
  const float* norm_w  = (const float*)d_in[6];
  const float* in_w    = (const float*)d_in[7];
  const float* conv_w  = (const float*)d_in[8];
  const float* conv_b  = (const float*)d_in[9];
  const float* xp_w    = (const float*)d_in[10];
  const float* dt_w    = (const float*)d_in[11];
  const float* dt_b    = (const float*)d_in[12];
  const float* A_log   = (const float*)d_in[13];
  const float* Dp      = (const float*)d_in[14];
  const float* out_w   = (const float*)d_in[15];
  const float* normf_w = (const float*)d_in[16];
  const float* qw      = (const float*)d_in[17];
  const float* qdw     = (const float*)d_in[18];
  const float* kw      = (const float*)d_in[19];
  const float* kdw     = (const float*)d_in[20];
  const float* vw      = (const float*)d_in[21];
  const float* vdw     = (const float*)d_in[22];
  const float* pww     = (const float*)d_in[23];
  const float* temp    = (const float*)d_in[24];

  float* ws = (float*)d_ws;
  size_t o = 0;
  float* cosT = ws + o; o += (size_t)NT * DM;
  float* sinT = ws + o; o += (size_t)NT * DM;
  float* hB   = ws + o; o += 2ull * NB * SL * DM;
  float* resB = ws + o; o += 2ull * NB * SL * DM;
  float* hsB  = ws + o; o += 2ull * NB * SL * DM;
  float* xzB  = ws + o; o += 2ull * NB * SL * XZW;
  float* xsB  = ws + o; o += 4ull * NB * SL * DI;
  float* dblB = ws + o; o += 4ull * NB * SL * DBLW;
  float* delB = ws + o; o += 4ull * NB * SL * DI;   // aliased as im2col P before layers
  float* y0B  = ws + o; o += 2ull * NB * SL * DI;   // aliased as patch mm out before layers
  float* y1B  = ws + o; o += 2ull * NB * SL * DI;
  float* fTB  = ws + o; o += 2ull * NB * NT * DM;
  float* qkvL = ws + o; o += 3ull * NB * NT * DM;
  float* qkvD = ws + o; o += 3ull * NB * DM * NT;
  float* Pb   = ws + o; o += (size_t)NB * NH * 64 * 64;
  float* attB = ws + o; o += (size_t)NB * DM * NT;
  (void)ws_size; (void)in_sizes; (void)n_in; (void)out_size;

  const int M = NB * SL;  // 788 rows per encoder

  k_rope_init<<<(NT * DM + 255) / 256, 256, 0, stream>>>(cosT, sinT);

  // patch embed as im2col + GEMM + epilogue (delB/y0B reused as scratch here)
  float* Pm = delB;       // (2, 784, 768)
  float* Pout = y0B;      // (2, 784, 192)
  k_im2col<<<(2 * 784 * 768 + 255) / 256, 256, 0, stream>>>(x1, x2, Pm);
  {
    MM4 p{};
    for (int e = 0; e < 2; ++e) {
      p.A0[e] = Pm + (size_t)e * 784 * 768;
      p.A1[e] = nullptr;
      p.B[e]  = patch_w + (size_t)e * DM * 768;
      p.C[e]  = Pout + (size_t)e * 784 * DM;
    }
    dim3 g((DM + 63) / 64, (784 + 63) / 64, 2);
    k_mm64<<<g, 256, 0, stream>>>(p, 784, DM, 768, 1.f);
  }
  k_patch_fin<<<(2 * NB * SL * DM + 255) / 256, 256, 0, stream>>>(
      Pout, patch_b, cls_tok, pos_emb, hB, resB);

  for (int l = 0; l < NL; ++l) {
    k_rope_res_norm<<<2 * NB * SL, DM, 0, stream>>>(hB, resB, hsB, norm_w, cosT, sinT, l);

    // xz = hs @ in_w^T  (per encoder)
    {
      MM4 p{};
      for (int e = 0; e < 2; ++e) {
        p.A0[e] = hsB + (size_t)e * M * DM;
        p.A1[e] = nullptr;
        p.B[e]  = in_w + (size_t)(e * NL + l) * XZW * DM;
        p.C[e]  = xzB + (size_t)e * M * XZW;
      }
      dim3 g((XZW + 63) / 64, (M + 63) / 64, 2);
      k_mm64<<<g, 256, 0, stream>>>(p, M, XZW, DM, 1.f);
    }

    k_conv_silu<<<(2 * 2 * NB * SL * DI + 255) / 256, 256, 0, stream>>>(xzB, conv_w, conv_b, xsB, l);

    // dbl = xs @ xp_w^T (per e,dir)
    {
      MM4 p{};
      for (int z = 0; z < 4; ++z) {
        int e = z / 2, dir = z % 2;
        p.A0[z] = xsB + (size_t)z * M * DI;
        p.A1[z] = nullptr;
        p.B[z]  = xp_w + ((size_t)(e * NL + l) * 2 + dir) * DBLW * DI;
        p.C[z]  = dblB + (size_t)z * M * DBLW;
      }
      dim3 g((DBLW + 63) / 64, (M + 63) / 64, 4);
      k_mm64<<<g, 256, 0, stream>>>(p, M, DBLW, DI, 1.f);
    }

    k_delta<<<(2 * 2 * NB * SL * DI + 255) / 256, 256, 0, stream>>>(dblB, dt_w, dt_b, delB, l);

    k_scan<<<2 * 2 * NB * (DI / 16), 256, 0, stream>>>(xsB, delB, dblB, xzB, A_log, Dp, y0B, y1B, l);

    // h = 0.5*(y0+y1) @ out_w^T (per encoder)
    {
      MM4 p{};
      for (int e = 0; e < 2; ++e) {
        p.A0[e] = y0B + (size_t)e * M * DI;
        p.A1[e] = y1B + (size_t)e * M * DI;
        p.B[e]  = out_w + (size_t)(e * NL + l) * DM * DI;
        p.C[e]  = hB + (size_t)e * M * DM;
      }
      dim3 g((DM + 63) / 64, (M + 63) / 64, 2);
      k_mm64<<<g, 256, 0, stream>>>(p, M, DM, DI, 0.5f);
    }
  }

  k_final_norm<<<2 * NB * NT, DM, 0, stream>>>(hB, resB, normf_w, fTB);

  // q/k/v linear: q from f1 (e=0), k,v from f2 (e=1)
  {
    MM4 p{};
    const int Mq = NB * NT;  // 784
    p.A0[0] = fTB;                         p.A1[0] = nullptr; p.B[0] = qw; p.C[0] = qkvL;
    p.A0[1] = fTB + (size_t)NB * NT * DM;  p.A1[1] = nullptr; p.B[1] = kw; p.C[1] = qkvL + (size_t)Mq * DM;
    p.A0[2] = fTB + (size_t)NB * NT * DM;  p.A1[2] = nullptr; p.B[2] = vw; p.C[2] = qkvL + 2ull * Mq * DM;
    dim3 g((DM + 63) / 64, (Mq + 63) / 64, 3);
    k_mm64<<<g, 256, 0, stream>>>(p, Mq, DM, DM, 1.f);
  }

  k_dwconv<<<(3 * NB * DM * NT + 255) / 256, 256, 0, stream>>>(qkvL, qdw, kdw, vdw, qkvD);
  k_l2norm<<<2 * NB * DM, 256, 0, stream>>>(qkvD);
  k_attn_sm<<<NB * NH * 64, 64, 0, stream>>>(qkvD, temp, Pb);
  k_av<<<NB * NH * 64, 256, 0, stream>>>(Pb, qkvD, attB);
  k_out<<<NB * DM, 256, 0, stream>>>(attB, pww, (float*)d_out);
}

// Round 6
// 3651.663 us; speedup vs baseline: 1.8500x; 1.0390x over previous
//
#include <hip/hip_runtime.h>

#define DM 192      // D_MODEL
#define DI 384      // D_INNER
#define DSt 16      // D_STATE
#define DTR 12      // DT_RANK
#define DC 4        // D_CONV
#define NL 24       // DEPTH
#define HP 14
#define NH 3
#define NB 4        // BATCH
#define SL 197      // seq len (tokens + cls)
#define NT 196      // spatial tokens
#define XZW 768     // 2*D_INNER
#define DBLW 44     // DT_RANK + 2*D_STATE
#define TC 32       // scan chunk (steps staged in LDS)
#define NCHK 7      // ceil(197/32)

static __device__ __forceinline__ float siluf(float x) { return x / (1.f + expf(-x)); }
static __device__ __forceinline__ float softplusf(float x) { return (x > 20.f) ? x : log1pf(expf(x)); }

// ---- block reduce helpers ----
static __device__ __forceinline__ float blk_sum3(float v, float* wsum) {
  for (int off = 32; off; off >>= 1) v += __shfl_xor(v, off, 64);
  int wid = threadIdx.x >> 6;
  if ((threadIdx.x & 63) == 0) wsum[wid] = v;
  __syncthreads();
  return wsum[0] + wsum[1] + wsum[2];
}
static __device__ __forceinline__ float blk_sum4(float v, float* wsum) {
  for (int off = 32; off; off >>= 1) v += __shfl_xor(v, off, 64);
  int wid = threadIdx.x >> 6;
  if ((threadIdx.x & 63) == 0) wsum[wid] = v;
  __syncthreads();
  return wsum[0] + wsum[1] + wsum[2] + wsum[3];
}

// ---- rope tables: cos/sin (196,192) ----
__global__ void k_rope_init(float* __restrict__ cosT, float* __restrict__ sinT) {
  int gid = blockIdx.x * blockDim.x + threadIdx.x;
  if (gid >= NT * DM) return;
  int c = gid % DM, tk = gid / DM;
  int py = tk / HP, px = tk % HP;
  int pos = (c < 96) ? py : px;
  int i = (c < 96) ? (c >> 1) : ((c - 96) >> 1);
  double fb = pow(10000.0, -((double)(2 * i)) / 96.0);
  double ang = (double)pos * fb;
  cosT[gid] = (float)cos(ang);
  sinT[gid] = (float)sin(ang);
}

// ---- im2col: P (2, 784, 768) patch matrix ----
__global__ void k_im2col(const float* __restrict__ x1, const float* __restrict__ x2,
                         float* __restrict__ P) {
  int gid = blockIdx.x * blockDim.x + threadIdx.x;
  if (gid >= 2 * 784 * 768) return;
  int col = gid % 768;
  int row = (gid / 768) % 784;
  int e = gid / (768 * 784);
  int b = row / NT, tk = row % NT;
  int c = col >> 8, r = (col >> 4) & 15, xx = col & 15;
  int py = tk / HP, px = tk % HP;
  const float* img = e ? x2 : x1;
  P[gid] = img[((size_t)(b * 3 + c) * 224 + (py * 16 + r)) * 224 + (px * 16 + xx)];
}

// ---- patch epilogue: h = mm_out + pb + pos (cls row special); res = 0 ----
__global__ void k_patch_fin(const float* __restrict__ pm, const float* __restrict__ pb,
                            const float* __restrict__ cls, const float* __restrict__ pos,
                            float* __restrict__ h, float* __restrict__ res) {
  int gid = blockIdx.x * blockDim.x + threadIdx.x;
  if (gid >= 2 * NB * SL * DM) return;
  int c = gid % DM;
  int t = (gid / DM) % SL;
  int b = (gid / (DM * SL)) % NB;
  int e = gid / (DM * SL * NB);
  float v;
  if (t == 0) v = cls[e * DM + c];
  else v = pm[((size_t)e * 784 + b * NT + (t - 1)) * DM + c] + pb[e * DM + c];
  h[gid] = v + pos[((size_t)e * SL + t) * DM + c];
  res[gid] = 0.f;
}

// ---- per layer: rope(h); res += ; hs = rmsnorm(res)*nw ----
__global__ __launch_bounds__(DM) void k_rope_res_norm(
    const float* __restrict__ h, float* __restrict__ res, float* __restrict__ hs,
    const float* __restrict__ nw, const float* __restrict__ cosT,
    const float* __restrict__ sinT, int l) {
  int bx = blockIdx.x;
  int t = bx % SL; int b = (bx / SL) % NB; int e = bx / (SL * NB);
  int c = threadIdx.x;
  __shared__ float sh[DM];
  __shared__ float wsum[3];
  size_t base = ((size_t)(e * NB + b) * SL + t) * DM;
  sh[c] = h[base + c];
  __syncthreads();
  float v = sh[c];
  if (t > 0) {
    int tk = t - 1;
    float co = cosT[tk * DM + c], si = sinT[tk * DM + c];
    float partner = sh[c ^ 1];
    float rot = (c & 1) ? partner : -partner;
    v = v * co + rot * si;
  }
  float r = res[base + c] + v;
  res[base + c] = r;
  float tot = blk_sum3(r * r, wsum);
  float scale = rsqrtf(tot / (float)DM + 1e-5f);
  hs[base + c] = r * scale * nw[(size_t)(e * NL + l) * DM + c];
}

// ---- register-blocked tiled GEMM: C = alpha*(A0[+A1]) @ B^T ----
struct MM4 {
  const float* A0[4];
  const float* A1[4];
  const float* B[4];
  float* C[4];
};
__global__ __launch_bounds__(256) void k_mm64(MM4 p, int M, int N, int K, float alpha) {
  const float* __restrict__ A0 = p.A0[blockIdx.z];
  const float* __restrict__ A1 = p.A1[blockIdx.z];
  const float* __restrict__ Bw = p.B[blockIdx.z];
  float* __restrict__ C = p.C[blockIdx.z];
  __shared__ __align__(16) float As[16][68];
  __shared__ __align__(16) float Bs[16][68];
  int tid = threadIdx.x;
  int m0 = blockIdx.y * 64, n0 = blockIdx.x * 64;
  int tm = tid >> 4, tn = tid & 15;       // compute roles
  int srow = tid >> 2, skq = tid & 3;     // staging roles
  int gmA = min(m0 + srow, M - 1);
  int gnB = min(n0 + srow, N - 1);
  bool hasA1 = (A1 != nullptr);
  float4 ra, rb, ra1;

  auto GLOAD = [&](int k0) {
    ra = *(const float4*)&A0[(size_t)gmA * K + k0 + skq * 4];
    if (hasA1) ra1 = *(const float4*)&A1[(size_t)gmA * K + k0 + skq * 4];
    rb = *(const float4*)&Bw[(size_t)gnB * K + k0 + skq * 4];
  };
  auto DSW = [&]() {
    float av0 = ra.x, av1 = ra.y, av2 = ra.z, av3 = ra.w;
    if (hasA1) { av0 += ra1.x; av1 += ra1.y; av2 += ra1.z; av3 += ra1.w; }
    int kb = skq * 4;
    As[kb + 0][srow] = av0;
    As[kb + 1][srow] = av1;
    As[kb + 2][srow] = av2;
    As[kb + 3][srow] = av3;
    Bs[kb + 0][srow] = rb.x;
    Bs[kb + 1][srow] = rb.y;
    Bs[kb + 2][srow] = rb.z;
    Bs[kb + 3][srow] = rb.w;
  };

  float acc[4][4] = {};
  int T = K >> 4;
  GLOAD(0);
  DSW();
  __syncthreads();
#pragma unroll 1
  for (int kt = 1; kt <= T; ++kt) {
    if (kt < T) GLOAD(kt * 16);
#pragma unroll
    for (int kk = 0; kk < 16; ++kk) {
      float4 a = *(const float4*)&As[kk][tm * 4];
      float4 b = *(const float4*)&Bs[kk][tn * 4];
      float av[4] = {a.x, a.y, a.z, a.w};
      float bv[4] = {b.x, b.y, b.z, b.w};
#pragma unroll
      for (int mi = 0; mi < 4; ++mi)
#pragma unroll
        for (int ni = 0; ni < 4; ++ni)
          acc[mi][ni] += av[mi] * bv[ni];
    }
    if (kt < T) {
      __syncthreads();
      DSW();
      __syncthreads();
    }
  }
#pragma unroll
  for (int mi = 0; mi < 4; ++mi) {
    int gm = m0 + tm * 4 + mi;
    if (gm >= M) continue;
    int gn = n0 + tn * 4;
    if (gn + 3 < N) {
      float4 o4 = make_float4(alpha * acc[mi][0], alpha * acc[mi][1],
                              alpha * acc[mi][2], alpha * acc[mi][3]);
      *(float4*)&C[(size_t)gm * N + gn] = o4;
    } else {
#pragma unroll
      for (int ni = 0; ni < 4; ++ni)
        if (gn + ni < N) C[(size_t)gm * N + gn + ni] = alpha * acc[mi][ni];
    }
  }
}

// ---- causal depthwise conv (k=4) + silu; handles direction reversal ----
__global__ void k_conv_silu(const float* __restrict__ xz, const float* __restrict__ cw,
                            const float* __restrict__ cb, float* __restrict__ xs, int l) {
  int gid = blockIdx.x * blockDim.x + threadIdx.x;
  if (gid >= 2 * 2 * NB * SL * DI) return;
  int d = gid % DI;
  int t = (gid / DI) % SL;
  int b = (gid / (DI * SL)) % NB;
  int dir = (gid / (DI * SL * NB)) % 2;
  int e = gid / (DI * SL * NB * 2);
  size_t pidx = (size_t)(e * NL + l) * 2 + dir;
  const float* cwp = cw + (pidx * DI + d) * DC;
  float acc = cb[pidx * DI + d];
#pragma unroll
  for (int k = 0; k < DC; ++k) {
    int ts = t - (DC - 1) + k;
    if (ts >= 0) {
      int torig = dir ? (SL - 1 - ts) : ts;
      acc += cwp[k] * xz[((size_t)(e * NB + b) * SL + torig) * XZW + d];
    }
  }
  xs[gid] = siluf(acc);
}

// ---- delta = softplus(dt @ dw^T + db) ----
__global__ void k_delta(const float* __restrict__ dbl, const float* __restrict__ dtw,
                        const float* __restrict__ dtb, float* __restrict__ delta, int l) {
  int gid = blockIdx.x * blockDim.x + threadIdx.x;
  if (gid >= 2 * 2 * NB * SL * DI) return;
  int d = gid % DI;
  int t = (gid / DI) % SL;
  int b = (gid / (DI * SL)) % NB;
  int dir = (gid / (DI * SL * NB)) % 2;
  int e = gid / (DI * SL * NB * 2);
  int z = e * 2 + dir;
  size_t pidx = (size_t)(e * NL + l) * 2 + dir;
  const float* row = dbl + ((size_t)(z * NB + b) * SL + t) * DBLW;
  const float* w = dtw + (pidx * DI + d) * DTR;
  float acc = dtb[pidx * DI + d];
#pragma unroll
  for (int r = 0; r < DTR; ++r) acc += row[r] * w[r];
  delta[gid] = softplusf(acc);
}

// ---- selective scan, LDS double-buffered staging + batched reduction ----
// Per 32-step chunk: phase 1 runs only the h-recurrence (exp off-chain,
// pipelined), saving pc[i]=h*C into registers; phase 2 runs 32 independent
// 4-deep shfl-reduce chains (ILP hides crossbar latency); phase 3 stores.
__global__ __launch_bounds__(256) void k_scan(
    const float* __restrict__ xs, const float* __restrict__ delta,
    const float* __restrict__ dbl, const float* __restrict__ xz,
    const float* __restrict__ alog, const float* __restrict__ dpw,
    float* __restrict__ y0, float* __restrict__ y1, int l) {
  int bx = blockIdx.x;
  int dg = bx % (DI / 16);
  int b = (bx / (DI / 16)) % NB;
  int dir = (bx / (DI / 16 * NB)) % 2;
  int e = bx / (DI / 16 * NB * 2);
  int tid = threadIdx.x;
  int n = tid & 15;       // state index (compute role)
  int ch = tid >> 4;      // channel within group (compute role)
  int d = dg * 16 + ch;
  size_t pidx = (size_t)(e * NL + l) * 2 + dir;
  float A = -expf(alog[(pidx * DI + d) * DSt + n]);
  float dpv = dpw[pidx * DI + d];
  int z = e * 2 + dir;
  size_t dblbase = ((size_t)(z * NB + b) * SL) * DBLW;
  float* yout = dir ? y1 : y0;
  size_t ybase = ((size_t)(e * NB + b) * SL) * DI + d;

  // load-role bases
  int lch = tid & 15;       // channel for dv/xv/zv loads
  int ltt = tid >> 4;       // 0..15
  int lj = tid & 31;        // 0..31 (Bm|C)
  int ltt2 = tid >> 5;      // 0..7
  size_t gdbase = ((size_t)(z * NB + b) * SL) * DI + dg * 16 + lch;
  size_t gzbase = ((size_t)(e * NB + b) * SL) * XZW + DI + dg * 16 + lch;

  __shared__ float s_dv[2][TC][16];
  __shared__ float s_xv[2][TC][16];
  __shared__ float s_zv[2][TC][16];
  __shared__ float s_bc[2][TC][32];

  float r_dv[2], r_xv[2], r_zv[2], r_bc[4];

  auto LOADREG = [&](int c) {
    int t0 = c * TC;
#pragma unroll
    for (int k = 0; k < 2; ++k) {
      int t = t0 + ltt + 16 * k;
      int tm = t < SL ? t : SL - 1;
      r_dv[k] = delta[gdbase + (size_t)tm * DI];
      r_xv[k] = xs[gdbase + (size_t)tm * DI];
      int torig = dir ? (SL - 1 - tm) : tm;
      r_zv[k] = xz[gzbase + (size_t)torig * XZW];
    }
#pragma unroll
    for (int k = 0; k < 4; ++k) {
      int t = t0 + ltt2 + 8 * k;
      int tm = t < SL ? t : SL - 1;
      r_bc[k] = dbl[dblbase + (size_t)tm * DBLW + DTR + lj];
    }
  };
  auto STORE = [&](int pb) {
#pragma unroll
    for (int k = 0; k < 2; ++k) {
      s_dv[pb][ltt + 16 * k][lch] = r_dv[k];
      s_xv[pb][ltt + 16 * k][lch] = r_xv[k];
      s_zv[pb][ltt + 16 * k][lch] = r_zv[k];
    }
#pragma unroll
    for (int k = 0; k < 4; ++k) s_bc[pb][ltt2 + 8 * k][lj] = r_bc[k];
  };

  float hst = 0.f;
  float pc[TC];
  auto COMP = [&](int pb, int c) {
    int t0 = c * TC;
    // phase 1: h-recurrence only (exp off the serial chain)
#pragma unroll
    for (int i = 0; i < TC; ++i) {
      float dv = s_dv[pb][i][ch];
      float bm = s_bc[pb][i][n];
      float xv = s_xv[pb][i][ch];
      hst = __expf(dv * A) * hst + (dv * xv) * bm;
      pc[i] = hst * s_bc[pb][i][16 + n];
    }
    // phase 2: 32 independent 4-deep shfl reduction chains
#pragma unroll
    for (int i = 0; i < TC; ++i) {
      float p = pc[i];
      p += __shfl_xor(p, 1, 64);
      p += __shfl_xor(p, 2, 64);
      p += __shfl_xor(p, 4, 64);
      p += __shfl_xor(p, 8, 64);
      pc[i] = p;
    }
    // phase 3: batched stores (n==0 lanes)
    if (n == 0) {
#pragma unroll
      for (int i = 0; i < TC; ++i) {
        int t = t0 + i;
        if (t < SL) {
          int torig = dir ? (SL - 1 - t) : t;
          float yv = pc[i] + s_xv[pb][i][ch] * dpv;
          yout[ybase + (size_t)torig * DI] = yv * siluf(s_zv[pb][i][ch]);
        }
      }
    }
  };

  LOADREG(0);
  STORE(0);
  LOADREG(1);
  __syncthreads();
  int pb = 0;
#pragma unroll 1
  for (int c = 0; c < NCHK; ++c) {
    COMP(pb, c);
    if (c + 1 < NCHK) {
      STORE(pb ^ 1);
      __syncthreads();
      if (c + 2 < NCHK) LOADREG(c + 2);
      pb ^= 1;
    }
  }
}

// ---- final: rmsnorm(h+res)*nfw, drop cls, token-major fT (e,b,196,192) ----
__global__ __launch_bounds__(DM) void k_final_norm(
    const float* __restrict__ h, const float* __restrict__ res,
    const float* __restrict__ nfw, float* __restrict__ fT) {
  int bx = blockIdx.x;
  int tk = bx % NT; int b = (bx / NT) % NB; int e = bx / (NT * NB);
  int c = threadIdx.x;
  __shared__ float wsum[3];
  size_t base = ((size_t)(e * NB + b) * SL + (tk + 1)) * DM;
  float r = h[base + c] + res[base + c];
  float tot = blk_sum3(r * r, wsum);
  float scale = rsqrtf(tot / (float)DM + 1e-5f);
  fT[((size_t)(e * NB + b) * NT + tk) * DM + c] = r * scale * nfw[e * DM + c];
}

// ---- depthwise 3x3 SAME over 14x14; in token-major, out channel-major ----
__global__ void k_dwconv(const float* __restrict__ qkvl, const float* __restrict__ qdw,
                         const float* __restrict__ kdw, const float* __restrict__ vdw,
                         float* __restrict__ qkvd) {
  int gid = blockIdx.x * blockDim.x + threadIdx.x;
  if (gid >= 3 * NB * DM * NT) return;
  int nn = gid % NT;
  int o = (gid / NT) % DM;
  int b = (gid / (NT * DM)) % NB;
  int zz = gid / (NT * DM * NB);
  const float* wsel = (zz == 0 ? qdw : (zz == 1 ? kdw : vdw)) + o * 9;
  int y = nn / HP, x = nn % HP;
  const float* in = qkvl + ((size_t)zz * NB + b) * NT * DM;
  float acc = 0.f;
#pragma unroll
  for (int ky = 0; ky < 3; ++ky) {
    int yy = y + ky - 1;
    if (yy < 0 || yy >= HP) continue;
#pragma unroll
    for (int kx = 0; kx < 3; ++kx) {
      int xx = x + kx - 1;
      if (xx < 0 || xx >= HP) continue;
      acc += in[(size_t)(yy * HP + xx) * DM + o] * wsel[ky * 3 + kx];
    }
  }
  qkvd[gid] = acc;
}

// ---- L2-normalize q,k rows over n=196 (in place) ----
__global__ __launch_bounds__(256) void k_l2norm(float* __restrict__ qkvd) {
  int bx = blockIdx.x;
  int C = bx % DM; int b = (bx / DM) % NB; int zz = bx / (DM * NB);
  int i = threadIdx.x;
  __shared__ float wsum[4];
  float* row = qkvd + ((size_t)zz * NB + b) * DM * NT + (size_t)C * NT;
  float v = (i < NT) ? row[i] : 0.f;
  float tot = blk_sum4(v * v, wsum);
  float sc = 1.f / fmaxf(sqrtf(tot), 1e-12f);
  if (i < NT) row[i] = v * sc;
}

// ---- S = temp*qn.kn^T, softmax over j (block=(b,h,i), 64 threads=j) ----
__global__ __launch_bounds__(64) void k_attn_sm(const float* __restrict__ qkvd,
                                                const float* __restrict__ temp,
                                                float* __restrict__ P) {
  int bx = blockIdx.x;
  int i = bx % 64; int hh = (bx / 64) % NH; int b = bx / (64 * NH);
  int j = threadIdx.x;
  __shared__ float qs[NT];
  const float* qrow = qkvd + ((size_t)0 * NB + b) * DM * NT + (size_t)(hh * 64 + i) * NT;
  for (int k = j; k < NT; k += 64) qs[k] = qrow[k];
  __syncthreads();
  const float* krow = qkvd + ((size_t)1 * NB + b) * DM * NT + (size_t)(hh * 64 + j) * NT;
  float acc = 0.f;
  for (int k = 0; k < NT; ++k) acc += qs[k] * krow[k];
  acc *= temp[hh];
  float m = acc;
  for (int off = 32; off; off >>= 1) m = fmaxf(m, __shfl_xor(m, off, 64));
  float ex = expf(acc - m);
  float s = ex;
  for (int off = 32; off; off >>= 1) s += __shfl_xor(s, off, 64);
  P[((size_t)(b * NH + hh) * 64 + i) * 64 + j] = ex / s;
}

// ---- out = P @ vh ----
__global__ __launch_bounds__(256) void k_av(const float* __restrict__ P,
                                            const float* __restrict__ qkvd,
                                            float* __restrict__ att) {
  int bx = blockIdx.x;
  int i = bx % 64; int hh = (bx / 64) % NH; int b = bx / (64 * NH);
  int nn = threadIdx.x;
  __shared__ float ps[64];
  if (nn < 64) ps[nn] = P[((size_t)(b * NH + hh) * 64 + i) * 64 + nn];
  __syncthreads();
  if (nn >= NT) return;
  const float* vbase = qkvd + ((size_t)2 * NB + b) * DM * NT + (size_t)(hh * 64) * NT + nn;
  float acc = 0.f;
  for (int j = 0; j < 64; ++j) acc += ps[j] * vbase[(size_t)j * NT];
  att[((size_t)b * DM + hh * 64 + i) * NT + nn] = acc;
}

// ---- final pointwise projection to d_out ----
__global__ __launch_bounds__(256) void k_out(const float* __restrict__ att,
                                             const float* __restrict__ pw,
                                             float* __restrict__ out) {
  int bx = blockIdx.x;
  int o = bx % DM; int b = bx / DM;
  int nn = threadIdx.x;
  if (nn >= NT) return;
  const float* abase = att + (size_t)b * DM * NT + nn;
  const float* w = pw + (size_t)o * DM;
  float acc = 0.f;
  for (int c = 0; c < DM; ++c) acc += abase[(size_t)c * NT] * w[c];
  out[((size_t)b * DM + o) * NT + nn] = acc;
}

extern "C" void kernel_launch(void* const* d_in, const int* in_sizes, int n_in,
                              void* d_out, int out_size, void* d_ws, size_t ws_size,
                              hipStream_t stream) {
  const float* x1      = (const float*)d_in[0];
  const float* x2      = (const float*)d_in[1];
  const float* patch_w = (const float*)d_in[2];
  const float* patch_b = (const float*)d_in[3];
  const float* cls_tok = (const float*)d_in[4];
  const float* pos_emb = (const float*)d_in[5];
  const float* norm_w  = (const float*)d_in[6];
  const float* in_w    = (const float*)d_in[7];
  const float* conv_w  = (const float*)d_in[8];
  const float* conv_b  = (const float*)d_in[9];
  const float* xp_w    = (const float*)d_in[10];
  const float* dt_w    = (const float*)d_in[11];
  const float* dt_b    = (const float*)d_in[12];
  const float* A_log   = (const float*)d_in[13];
  const float* Dp      = (const float*)d_in[14];
  const float* out_w   = (const float*)d_in[15];
  const float* normf_w = (const float*)d_in[16];
  const float* qw      = (const float*)d_in[17];
  const float* qdw     = (const float*)d_in[18];
  const float* kw      = (const float*)d_in[19];
  const float* kdw     = (const float*)d_in[20];
  const float* vw      = (const float*)d_in[21];
  const float* vdw     = (const float*)d_in[22];
  const float* pww     = (const float*)d_in[23];
  const float* temp    = (const float*)d_in[24];

  float* ws = (float*)d_ws;
  size_t o = 0;
  float* cosT = ws + o; o += (size_t)NT * DM;
  float* sinT = ws + o; o += (size_t)NT * DM;
  float* hB   = ws + o; o += 2ull * NB * SL * DM;
  float* resB = ws + o; o += 2ull * NB * SL * DM;
  float* hsB  = ws + o; o += 2ull * NB * SL * DM;
  float* xzB  = ws + o; o += 2ull * NB * SL * XZW;
  float* xsB  = ws + o; o += 4ull * NB * SL * DI;
  float* dblB = ws + o; o += 4ull * NB * SL * DBLW;
  float* delB = ws + o; o += 4ull * NB * SL * DI;   // aliased as im2col P before layers
  float* y0B  = ws + o; o += 2ull * NB * SL * DI;   // aliased as patch mm out before layers
  float* y1B  = ws + o; o += 2ull * NB * SL * DI;
  float* fTB  = ws + o; o += 2ull * NB * NT * DM;
  float* qkvL = ws + o; o += 3ull * NB * NT * DM;
  float* qkvD = ws + o; o += 3ull * NB * DM * NT;
  float* Pb   = ws + o; o += (size_t)NB * NH * 64 * 64;
  float* attB = ws + o; o += (size_t)NB * DM * NT;
  (void)ws_size; (void)in_sizes; (void)n_in; (void)out_size;

  const int M = NB * SL;  // 788 rows per encoder

  k_rope_init<<<(NT * DM + 255) / 256, 256, 0, stream>>>(cosT, sinT);

  // patch embed as im2col + GEMM + epilogue (delB/y0B reused as scratch here)
  float* Pm = delB;       // (2, 784, 768)
  float* Pout = y0B;      // (2, 784, 192)
  k_im2col<<<(2 * 784 * 768 + 255) / 256, 256, 0, stream>>>(x1, x2, Pm);
  {
    MM4 p{};
    for (int e = 0; e < 2; ++e) {
      p.A0[e] = Pm + (size_t)e * 784 * 768;
      p.A1[e] = nullptr;
      p.B[e]  = patch_w + (size_t)e * DM * 768;
      p.C[e]  = Pout + (size_t)e * 784 * DM;
    }
    dim3 g((DM + 63) / 64, (784 + 63) / 64, 2);
    k_mm64<<<g, 256, 0, stream>>>(p, 784, DM, 768, 1.f);
  }
  k_patch_fin<<<(2 * NB * SL * DM + 255) / 256, 256, 0, stream>>>(
      Pout, patch_b, cls_tok, pos_emb, hB, resB);

  for (int l = 0; l < NL; ++l) {
    k_rope_res_norm<<<2 * NB * SL, DM, 0, stream>>>(hB, resB, hsB, norm_w, cosT, sinT, l);

    // xz = hs @ in_w^T  (per encoder)
    {
      MM4 p{};
      for (int e = 0; e < 2; ++e) {
        p.A0[e] = hsB + (size_t)e * M * DM;
        p.A1[e] = nullptr;
        p.B[e]  = in_w + (size_t)(e * NL + l) * XZW * DM;
        p.C[e]  = xzB + (size_t)e * M * XZW;
      }
      dim3 g((XZW + 63) / 64, (M + 63) / 64, 2);
      k_mm64<<<g, 256, 0, stream>>>(p, M, XZW, DM, 1.f);
    }

    k_conv_silu<<<(2 * 2 * NB * SL * DI + 255) / 256, 256, 0, stream>>>(xzB, conv_w, conv_b, xsB, l);

    // dbl = xs @ xp_w^T (per e,dir)
    {
      MM4 p{};
      for (int z = 0; z < 4; ++z) {
        int e = z / 2, dir = z % 2;
        p.A0[z] = xsB + (size_t)z * M * DI;
        p.A1[z] = nullptr;
        p.B[z]  = xp_w + ((size_t)(e * NL + l) * 2 + dir) * DBLW * DI;
        p.C[z]  = dblB + (size_t)z * M * DBLW;
      }
      dim3 g((DBLW + 63) / 64, (M + 63) / 64, 4);
      k_mm64<<<g, 256, 0, stream>>>(p, M, DBLW, DI, 1.f);
    }

    k_delta<<<(2 * 2 * NB * SL * DI + 255) / 256, 256, 0, stream>>>(dblB, dt_w, dt_b, delB, l);

    k_scan<<<2 * 2 * NB * (DI / 16), 256, 0, stream>>>(xsB, delB, dblB, xzB, A_log, Dp, y0B, y1B, l);

    // h = 0.5*(y0+y1) @ out_w^T (per encoder)
    {
      MM4 p{};
      for (int e = 0; e < 2; ++e) {
        p.A0[e] = y0B + (size_t)e * M * DI;
        p.A1[e] = y1B + (size_t)e * M * DI;
        p.B[e]  = out_w + (size_t)(e * NL + l) * DM * DI;
        p.C[e]  = hB + (size_t)e * M * DM;
      }
      dim3 g((DM + 63) / 64, (M + 63) / 64, 2);
      k_mm64<<<g, 256, 0, stream>>>(p, M, DM, DI, 0.5f);
    }
  }

  k_final_norm<<<2 * NB * NT, DM, 0, stream>>>(hB, resB, normf_w, fTB);

  // q/k/v linear: q from f1 (e=0), k,v from f2 (e=1)
  {
    MM4 p{};
    const int Mq = NB * NT;  // 784
    p.A0[0] = fTB;                         p.A1[0] = nullptr; p.B[0] = qw; p.C[0] = qkvL;
    p.A0[1] = fTB + (size_t)NB * NT * DM;  p.A1[1] = nullptr; p.B[1] = kw; p.C[1] = qkvL + (size_t)Mq * DM;
    p.A0[2] = fTB + (size_t)NB * NT * DM;  p.A1[2] = nullptr; p.B[2] = vw; p.C[2] = qkvL + 2ull * Mq * DM;
    dim3 g((DM + 63) / 64, (Mq + 63) / 64, 3);
    k_mm64<<<g, 256, 0, stream>>>(p, Mq, DM, DM, 1.f);
  }

  k_dwconv<<<(3 * NB * DM * NT + 255) / 256, 256, 0, stream>>>(qkvL, qdw, kdw, vdw, qkvD);
  k_l2norm<<<2 * NB * DM, 256, 0, stream>>>(qkvD);
  k_attn_sm<<<NB * NH * 64, 64, 0, stream>>>(qkvD, temp, Pb);
  k_av<<<NB * NH * 64, 256, 0, stream>>>(Pb, qkvD, attB);
  k_out<<<NB * DM, 256, 0, stream>>>(attB, pww, (float*)d_out);
}

// Round 7
// 3559.148 us; speedup vs baseline: 1.8981x; 1.0260x over previous
//
#include <hip/hip_runtime.h>

#define DM 192      // D_MODEL
#define DI 384      // D_INNER
#define DSt 16      // D_STATE
#define DTR 12      // DT_RANK
#define DC 4        // D_CONV
#define NL 24       // DEPTH
#define HP 14
#define NH 3
#define NB 4        // BATCH
#define SL 197      // seq len (tokens + cls)
#define NT 196      // spatial tokens
#define XZW 768     // 2*D_INNER
#define DBLW 44     // DT_RANK + 2*D_STATE
#define TC 32       // scan chunk (steps staged in LDS)
#define NCHK 7      // ceil(197/32)

static __device__ __forceinline__ float siluf(float x) { return x / (1.f + expf(-x)); }
static __device__ __forceinline__ float softplusf(float x) { return (x > 20.f) ? x : log1pf(expf(x)); }

// ---- block reduce helpers ----
static __device__ __forceinline__ float blk_sum3(float v, float* wsum) {
  for (int off = 32; off; off >>= 1) v += __shfl_xor(v, off, 64);
  int wid = threadIdx.x >> 6;
  if ((threadIdx.x & 63) == 0) wsum[wid] = v;
  __syncthreads();
  return wsum[0] + wsum[1] + wsum[2];
}
static __device__ __forceinline__ float blk_sum4(float v, float* wsum) {
  for (int off = 32; off; off >>= 1) v += __shfl_xor(v, off, 64);
  int wid = threadIdx.x >> 6;
  if ((threadIdx.x & 63) == 0) wsum[wid] = v;
  __syncthreads();
  return wsum[0] + wsum[1] + wsum[2] + wsum[3];
}

// ---- rope tables: cos/sin (196,192) ----
__global__ void k_rope_init(float* __restrict__ cosT, float* __restrict__ sinT) {
  int gid = blockIdx.x * blockDim.x + threadIdx.x;
  if (gid >= NT * DM) return;
  int c = gid % DM, tk = gid / DM;
  int py = tk / HP, px = tk % HP;
  int pos = (c < 96) ? py : px;
  int i = (c < 96) ? (c >> 1) : ((c - 96) >> 1);
  double fb = pow(10000.0, -((double)(2 * i)) / 96.0);
  double ang = (double)pos * fb;
  cosT[gid] = (float)cos(ang);
  sinT[gid] = (float)sin(ang);
}

// ---- im2col: P (2, 784, 768) patch matrix ----
__global__ void k_im2col(const float* __restrict__ x1, const float* __restrict__ x2,
                         float* __restrict__ P) {
  int gid = blockIdx.x * blockDim.x + threadIdx.x;
  if (gid >= 2 * 784 * 768) return;
  int col = gid % 768;
  int row = (gid / 768) % 784;
  int e = gid / (768 * 784);
  int b = row / NT, tk = row % NT;
  int c = col >> 8, r = (col >> 4) & 15, xx = col & 15;
  int py = tk / HP, px = tk % HP;
  const float* img = e ? x2 : x1;
  P[gid] = img[((size_t)(b * 3 + c) * 224 + (py * 16 + r)) * 224 + (px * 16 + xx)];
}

// ---- patch epilogue: h = mm_out + pb + pos (cls row special); res = 0 ----
__global__ void k_patch_fin(const float* __restrict__ pm, const float* __restrict__ pb,
                            const float* __restrict__ cls, const float* __restrict__ pos,
                            float* __restrict__ h, float* __restrict__ res) {
  int gid = blockIdx.x * blockDim.x + threadIdx.x;
  if (gid >= 2 * NB * SL * DM) return;
  int c = gid % DM;
  int t = (gid / DM) % SL;
  int b = (gid / (DM * SL)) % NB;
  int e = gid / (DM * SL * NB);
  float v;
  if (t == 0) v = cls[e * DM + c];
  else v = pm[((size_t)e * 784 + b * NT + (t - 1)) * DM + c] + pb[e * DM + c];
  h[gid] = v + pos[((size_t)e * SL + t) * DM + c];
  res[gid] = 0.f;
}

// ---- per layer: rope(h); res += ; hs = rmsnorm(res)*nw ----
__global__ __launch_bounds__(DM) void k_rope_res_norm(
    const float* __restrict__ h, float* __restrict__ res, float* __restrict__ hs,
    const float* __restrict__ nw, const float* __restrict__ cosT,
    const float* __restrict__ sinT, int l) {
  int bx = blockIdx.x;
  int t = bx % SL; int b = (bx / SL) % NB; int e = bx / (SL * NB);
  int c = threadIdx.x;
  __shared__ float sh[DM];
  __shared__ float wsum[3];
  size_t base = ((size_t)(e * NB + b) * SL + t) * DM;
  sh[c] = h[base + c];
  __syncthreads();
  float v = sh[c];
  if (t > 0) {
    int tk = t - 1;
    float co = cosT[tk * DM + c], si = sinT[tk * DM + c];
    float partner = sh[c ^ 1];
    float rot = (c & 1) ? partner : -partner;
    v = v * co + rot * si;
  }
  float r = res[base + c] + v;
  res[base + c] = r;
  float tot = blk_sum3(r * r, wsum);
  float scale = rsqrtf(tot / (float)DM + 1e-5f);
  hs[base + c] = r * scale * nw[(size_t)(e * NL + l) * DM + c];
}

// ---- register-blocked tiled GEMM: C = alpha*(A0[+A1]) @ B^T ----
struct MM4 {
  const float* A0[4];
  const float* A1[4];
  const float* B[4];
  float* C[4];
};
__global__ __launch_bounds__(256) void k_mm64(MM4 p, int M, int N, int K, float alpha) {
  const float* __restrict__ A0 = p.A0[blockIdx.z];
  const float* __restrict__ A1 = p.A1[blockIdx.z];
  const float* __restrict__ Bw = p.B[blockIdx.z];
  float* __restrict__ C = p.C[blockIdx.z];
  __shared__ __align__(16) float As[16][68];
  __shared__ __align__(16) float Bs[16][68];
  int tid = threadIdx.x;
  int m0 = blockIdx.y * 64, n0 = blockIdx.x * 64;
  int tm = tid >> 4, tn = tid & 15;       // compute roles
  int srow = tid >> 2, skq = tid & 3;     // staging roles
  int gmA = min(m0 + srow, M - 1);
  int gnB = min(n0 + srow, N - 1);
  bool hasA1 = (A1 != nullptr);
  float4 ra, rb, ra1;

  auto GLOAD = [&](int k0) {
    ra = *(const float4*)&A0[(size_t)gmA * K + k0 + skq * 4];
    if (hasA1) ra1 = *(const float4*)&A1[(size_t)gmA * K + k0 + skq * 4];
    rb = *(const float4*)&Bw[(size_t)gnB * K + k0 + skq * 4];
  };
  auto DSW = [&]() {
    float av0 = ra.x, av1 = ra.y, av2 = ra.z, av3 = ra.w;
    if (hasA1) { av0 += ra1.x; av1 += ra1.y; av2 += ra1.z; av3 += ra1.w; }
    int kb = skq * 4;
    As[kb + 0][srow] = av0;
    As[kb + 1][srow] = av1;
    As[kb + 2][srow] = av2;
    As[kb + 3][srow] = av3;
    Bs[kb + 0][srow] = rb.x;
    Bs[kb + 1][srow] = rb.y;
    Bs[kb + 2][srow] = rb.z;
    Bs[kb + 3][srow] = rb.w;
  };

  float acc[4][4] = {};
  int T = K >> 4;
  GLOAD(0);
  DSW();
  __syncthreads();
#pragma unroll 1
  for (int kt = 1; kt <= T; ++kt) {
    if (kt < T) GLOAD(kt * 16);
#pragma unroll
    for (int kk = 0; kk < 16; ++kk) {
      float4 a = *(const float4*)&As[kk][tm * 4];
      float4 b = *(const float4*)&Bs[kk][tn * 4];
      float av[4] = {a.x, a.y, a.z, a.w};
      float bv[4] = {b.x, b.y, b.z, b.w};
#pragma unroll
      for (int mi = 0; mi < 4; ++mi)
#pragma unroll
        for (int ni = 0; ni < 4; ++ni)
          acc[mi][ni] += av[mi] * bv[ni];
    }
    if (kt < T) {
      __syncthreads();
      DSW();
      __syncthreads();
    }
  }
#pragma unroll
  for (int mi = 0; mi < 4; ++mi) {
    int gm = m0 + tm * 4 + mi;
    if (gm >= M) continue;
    int gn = n0 + tn * 4;
    if (gn + 3 < N) {
      float4 o4 = make_float4(alpha * acc[mi][0], alpha * acc[mi][1],
                              alpha * acc[mi][2], alpha * acc[mi][3]);
      *(float4*)&C[(size_t)gm * N + gn] = o4;
    } else {
#pragma unroll
      for (int ni = 0; ni < 4; ++ni)
        if (gn + ni < N) C[(size_t)gm * N + gn + ni] = alpha * acc[mi][ni];
    }
  }
}

// ---- causal depthwise conv (k=4) + silu; handles direction reversal ----
__global__ void k_conv_silu(const float* __restrict__ xz, const float* __restrict__ cw,
                            const float* __restrict__ cb, float* __restrict__ xs, int l) {
  int gid = blockIdx.x * blockDim.x + threadIdx.x;
  if (gid >= 2 * 2 * NB * SL * DI) return;
  int d = gid % DI;
  int t = (gid / DI) % SL;
  int b = (gid / (DI * SL)) % NB;
  int dir = (gid / (DI * SL * NB)) % 2;
  int e = gid / (DI * SL * NB * 2);
  size_t pidx = (size_t)(e * NL + l) * 2 + dir;
  const float* cwp = cw + (pidx * DI + d) * DC;
  float acc = cb[pidx * DI + d];
#pragma unroll
  for (int k = 0; k < DC; ++k) {
    int ts = t - (DC - 1) + k;
    if (ts >= 0) {
      int torig = dir ? (SL - 1 - ts) : ts;
      acc += cwp[k] * xz[((size_t)(e * NB + b) * SL + torig) * XZW + d];
    }
  }
  xs[gid] = siluf(acc);
}

// ---- delta = softplus(dt @ dw^T + db) ----
__global__ void k_delta(const float* __restrict__ dbl, const float* __restrict__ dtw,
                        const float* __restrict__ dtb, float* __restrict__ delta, int l) {
  int gid = blockIdx.x * blockDim.x + threadIdx.x;
  if (gid >= 2 * 2 * NB * SL * DI) return;
  int d = gid % DI;
  int t = (gid / DI) % SL;
  int b = (gid / (DI * SL)) % NB;
  int dir = (gid / (DI * SL * NB)) % 2;
  int e = gid / (DI * SL * NB * 2);
  int z = e * 2 + dir;
  size_t pidx = (size_t)(e * NL + l) * 2 + dir;
  const float* row = dbl + ((size_t)(z * NB + b) * SL + t) * DBLW;
  const float* w = dtw + (pidx * DI + d) * DTR;
  float acc = dtb[pidx * DI + d];
#pragma unroll
  for (int r = 0; r < DTR; ++r) acc += row[r] * w[r];
  delta[gid] = softplusf(acc);
}

// ---- selective scan, LDS double-buffered staging + breadth-first compute ----
// Per 16-step sub-batch: (a) all ds_reads + 16 independent exps issued
// breadth-first into register arrays, (b) short serial h-chain (FMA only),
// (c) butterfly reduce as 4 explicit rounds of 16 INDEPENDENT shfls each
// (crossbar latency paid per round, not per chain), (d) batched stores.
__global__ __launch_bounds__(256) void k_scan(
    const float* __restrict__ xs, const float* __restrict__ delta,
    const float* __restrict__ dbl, const float* __restrict__ xz,
    const float* __restrict__ alog, const float* __restrict__ dpw,
    float* __restrict__ y0, float* __restrict__ y1, int l) {
  int bx = blockIdx.x;
  int dg = bx % (DI / 16);
  int b = (bx / (DI / 16)) % NB;
  int dir = (bx / (DI / 16 * NB)) % 2;
  int e = bx / (DI / 16 * NB * 2);
  int tid = threadIdx.x;
  int n = tid & 15;       // state index (compute role)
  int ch = tid >> 4;      // channel within group (compute role)
  int d = dg * 16 + ch;
  size_t pidx = (size_t)(e * NL + l) * 2 + dir;
  float A = -expf(alog[(pidx * DI + d) * DSt + n]);
  float dpv = dpw[pidx * DI + d];
  int z = e * 2 + dir;
  size_t dblbase = ((size_t)(z * NB + b) * SL) * DBLW;
  float* yout = dir ? y1 : y0;
  size_t ybase = ((size_t)(e * NB + b) * SL) * DI + d;

  // load-role bases
  int lch = tid & 15;       // channel for dv/xv/zv loads
  int ltt = tid >> 4;       // 0..15
  int lj = tid & 31;        // 0..31 (Bm|C)
  int ltt2 = tid >> 5;      // 0..7
  size_t gdbase = ((size_t)(z * NB + b) * SL) * DI + dg * 16 + lch;
  size_t gzbase = ((size_t)(e * NB + b) * SL) * XZW + DI + dg * 16 + lch;

  __shared__ float s_dv[2][TC][16];
  __shared__ float s_xv[2][TC][16];
  __shared__ float s_zv[2][TC][16];
  __shared__ float s_bc[2][TC][32];

  float r_dv[2], r_xv[2], r_zv[2], r_bc[4];

  auto LOADREG = [&](int c) {
    int t0 = c * TC;
#pragma unroll
    for (int k = 0; k < 2; ++k) {
      int t = t0 + ltt + 16 * k;
      int tm = t < SL ? t : SL - 1;
      r_dv[k] = delta[gdbase + (size_t)tm * DI];
      r_xv[k] = xs[gdbase + (size_t)tm * DI];
      int torig = dir ? (SL - 1 - tm) : tm;
      r_zv[k] = xz[gzbase + (size_t)torig * XZW];
    }
#pragma unroll
    for (int k = 0; k < 4; ++k) {
      int t = t0 + ltt2 + 8 * k;
      int tm = t < SL ? t : SL - 1;
      r_bc[k] = dbl[dblbase + (size_t)tm * DBLW + DTR + lj];
    }
  };
  auto STORE = [&](int pb) {
#pragma unroll
    for (int k = 0; k < 2; ++k) {
      s_dv[pb][ltt + 16 * k][lch] = r_dv[k];
      s_xv[pb][ltt + 16 * k][lch] = r_xv[k];
      s_zv[pb][ltt + 16 * k][lch] = r_zv[k];
    }
#pragma unroll
    for (int k = 0; k < 4; ++k) s_bc[pb][ltt2 + 8 * k][lj] = r_bc[k];
  };

  float hst = 0.f;
  auto COMP = [&](int pb, int c) {
    int t0 = c * TC;
#pragma unroll
    for (int half = 0; half < 2; ++half) {
      int i0 = half * 16;
      float ev[16], cc[16], cvv[16], xvv[16], pc[16], tmp[16];
      // (a) breadth-first LDS reads + independent exps
#pragma unroll
      for (int i = 0; i < 16; ++i) {
        float dv = s_dv[pb][i0 + i][ch];
        float bm = s_bc[pb][i0 + i][n];
        xvv[i] = s_xv[pb][i0 + i][ch];
        cvv[i] = s_bc[pb][i0 + i][16 + n];
        ev[i] = __expf(dv * A);
        cc[i] = (dv * xvv[i]) * bm;
      }
      // (b) short serial chain (one FMA + one mul per step)
#pragma unroll
      for (int i = 0; i < 16; ++i) {
        hst = ev[i] * hst + cc[i];
        pc[i] = hst * cvv[i];
      }
      // (c) butterfly: 4 rounds, 16 independent shfls per round
#pragma unroll
      for (int i = 0; i < 16; ++i) tmp[i] = __shfl_xor(pc[i], 1, 64);
#pragma unroll
      for (int i = 0; i < 16; ++i) pc[i] += tmp[i];
#pragma unroll
      for (int i = 0; i < 16; ++i) tmp[i] = __shfl_xor(pc[i], 2, 64);
#pragma unroll
      for (int i = 0; i < 16; ++i) pc[i] += tmp[i];
#pragma unroll
      for (int i = 0; i < 16; ++i) tmp[i] = __shfl_xor(pc[i], 4, 64);
#pragma unroll
      for (int i = 0; i < 16; ++i) pc[i] += tmp[i];
#pragma unroll
      for (int i = 0; i < 16; ++i) tmp[i] = __shfl_xor(pc[i], 8, 64);
#pragma unroll
      for (int i = 0; i < 16; ++i) pc[i] += tmp[i];
      // (d) batched stores (n==0 lanes)
      if (n == 0) {
#pragma unroll
        for (int i = 0; i < 16; ++i) {
          int t = t0 + i0 + i;
          if (t < SL) {
            int torig = dir ? (SL - 1 - t) : t;
            float yv = pc[i] + xvv[i] * dpv;
            yout[ybase + (size_t)torig * DI] = yv * siluf(s_zv[pb][i0 + i][ch]);
          }
        }
      }
    }
  };

  LOADREG(0);
  STORE(0);
  LOADREG(1);
  __syncthreads();
  int pb = 0;
#pragma unroll 1
  for (int c = 0; c < NCHK; ++c) {
    COMP(pb, c);
    if (c + 1 < NCHK) {
      STORE(pb ^ 1);
      __syncthreads();
      if (c + 2 < NCHK) LOADREG(c + 2);
      pb ^= 1;
    }
  }
}

// ---- final: rmsnorm(h+res)*nfw, drop cls, token-major fT (e,b,196,192) ----
__global__ __launch_bounds__(DM) void k_final_norm(
    const float* __restrict__ h, const float* __restrict__ res,
    const float* __restrict__ nfw, float* __restrict__ fT) {
  int bx = blockIdx.x;
  int tk = bx % NT; int b = (bx / NT) % NB; int e = bx / (NT * NB);
  int c = threadIdx.x;
  __shared__ float wsum[3];
  size_t base = ((size_t)(e * NB + b) * SL + (tk + 1)) * DM;
  float r = h[base + c] + res[base + c];
  float tot = blk_sum3(r * r, wsum);
  float scale = rsqrtf(tot / (float)DM + 1e-5f);
  fT[((size_t)(e * NB + b) * NT + tk) * DM + c] = r * scale * nfw[e * DM + c];
}

// ---- depthwise 3x3 SAME over 14x14; in token-major, out channel-major ----
__global__ void k_dwconv(const float* __restrict__ qkvl, const float* __restrict__ qdw,
                         const float* __restrict__ kdw, const float* __restrict__ vdw,
                         float* __restrict__ qkvd) {
  int gid = blockIdx.x * blockDim.x + threadIdx.x;
  if (gid >= 3 * NB * DM * NT) return;
  int nn = gid % NT;
  int o = (gid / NT) % DM;
  int b = (gid / (NT * DM)) % NB;
  int zz = gid / (NT * DM * NB);
  const float* wsel = (zz == 0 ? qdw : (zz == 1 ? kdw : vdw)) + o * 9;
  int y = nn / HP, x = nn % HP;
  const float* in = qkvl + ((size_t)zz * NB + b) * NT * DM;
  float acc = 0.f;
#pragma unroll
  for (int ky = 0; ky < 3; ++ky) {
    int yy = y + ky - 1;
    if (yy < 0 || yy >= HP) continue;
#pragma unroll
    for (int kx = 0; kx < 3; ++kx) {
      int xx = x + kx - 1;
      if (xx < 0 || xx >= HP) continue;
      acc += in[(size_t)(yy * HP + xx) * DM + o] * wsel[ky * 3 + kx];
    }
  }
  qkvd[gid] = acc;
}

// ---- L2-normalize q,k rows over n=196 (in place) ----
__global__ __launch_bounds__(256) void k_l2norm(float* __restrict__ qkvd) {
  int bx = blockIdx.x;
  int C = bx % DM; int b = (bx / DM) % NB; int zz = bx / (DM * NB);
  int i = threadIdx.x;
  __shared__ float wsum[4];
  float* row = qkvd + ((size_t)zz * NB + b) * DM * NT + (size_t)C * NT;
  float v = (i < NT) ? row[i] : 0.f;
  float tot = blk_sum4(v * v, wsum);
  float sc = 1.f / fmaxf(sqrtf(tot), 1e-12f);
  if (i < NT) row[i] = v * sc;
}

// ---- S = temp*qn.kn^T, softmax over j (block=(b,h,i), 64 threads=j) ----
__global__ __launch_bounds__(64) void k_attn_sm(const float* __restrict__ qkvd,
                                                const float* __restrict__ temp,
                                                float* __restrict__ P) {
  int bx = blockIdx.x;
  int i = bx % 64; int hh = (bx / 64) % NH; int b = bx / (64 * NH);
  int j = threadIdx.x;
  __shared__ float qs[NT];
  const float* qrow = qkvd + ((size_t)0 * NB + b) * DM * NT + (size_t)(hh * 64 + i) * NT;
  for (int k = j; k < NT; k += 64) qs[k] = qrow[k];
  __syncthreads();
  const float* krow = qkvd + ((size_t)1 * NB + b) * DM * NT + (size_t)(hh * 64 + j) * NT;
  float acc = 0.f;
  for (int k = 0; k < NT; ++k) acc += qs[k] * krow[k];
  acc *= temp[hh];
  float m = acc;
  for (int off = 32; off; off >>= 1) m = fmaxf(m, __shfl_xor(m, off, 64));
  float ex = expf(acc - m);
  float s = ex;
  for (int off = 32; off; off >>= 1) s += __shfl_xor(s, off, 64);
  P[((size_t)(b * NH + hh) * 64 + i) * 64 + j] = ex / s;
}

// ---- out = P @ vh ----
__global__ __launch_bounds__(256) void k_av(const float* __restrict__ P,
                                            const float* __restrict__ qkvd,
                                            float* __restrict__ att) {
  int bx = blockIdx.x;
  int i = bx % 64; int hh = (bx / 64) % NH; int b = bx / (64 * NH);
  int nn = threadIdx.x;
  __shared__ float ps[64];
  if (nn < 64) ps[nn] = P[((size_t)(b * NH + hh) * 64 + i) * 64 + nn];
  __syncthreads();
  if (nn >= NT) return;
  const float* vbase = qkvd + ((size_t)2 * NB + b) * DM * NT + (size_t)(hh * 64) * NT + nn;
  float acc = 0.f;
  for (int j = 0; j < 64; ++j) acc += ps[j] * vbase[(size_t)j * NT];
  att[((size_t)b * DM + hh * 64 + i) * NT + nn] = acc;
}

// ---- final pointwise projection to d_out ----
__global__ __launch_bounds__(256) void k_out(const float* __restrict__ att,
                                             const float* __restrict__ pw,
                                             float* __restrict__ out) {
  int bx = blockIdx.x;
  int o = bx % DM; int b = bx / DM;
  int nn = threadIdx.x;
  if (nn >= NT) return;
  const float* abase = att + (size_t)b * DM * NT + nn;
  const float* w = pw + (size_t)o * DM;
  float acc = 0.f;
  for (int c = 0; c < DM; ++c) acc += abase[(size_t)c * NT] * w[c];
  out[((size_t)b * DM + o) * NT + nn] = acc;
}

extern "C" void kernel_launch(void* const* d_in, const int* in_sizes, int n_in,
                              void* d_out, int out_size, void* d_ws, size_t ws_size,
                              hipStream_t stream) {
  const float* x1      = (const float*)d_in[0];
  const float* x2      = (const float*)d_in[1];
  const float* patch_w = (const float*)d_in[2];
  const float* patch_b = (const float*)d_in[3];
  const float* cls_tok = (const float*)d_in[4];
  const float* pos_emb = (const float*)d_in[5];
  const float* norm_w  = (const float*)d_in[6];
  const float* in_w    = (const float*)d_in[7];
  const float* conv_w  = (const float*)d_in[8];
  const float* conv_b  = (const float*)d_in[9];
  const float* xp_w    = (const float*)d_in[10];
  const float* dt_w    = (const float*)d_in[11];
  const float* dt_b    = (const float*)d_in[12];
  const float* A_log   = (const float*)d_in[13];
  const float* Dp      = (const float*)d_in[14];
  const float* out_w   = (const float*)d_in[15];
  const float* normf_w = (const float*)d_in[16];
  const float* qw      = (const float*)d_in[17];
  const float* qdw     = (const float*)d_in[18];
  const float* kw      = (const float*)d_in[19];
  const float* kdw     = (const float*)d_in[20];
  const float* vw      = (const float*)d_in[21];
  const float* vdw     = (const float*)d_in[22];
  const float* pww     = (const float*)d_in[23];
  const float* temp    = (const float*)d_in[24];

  float* ws = (float*)d_ws;
  size_t o = 0;
  float* cosT = ws + o; o += (size_t)NT * DM;
  float* sinT = ws + o; o += (size_t)NT * DM;
  float* hB   = ws + o; o += 2ull * NB * SL * DM;
  float* resB = ws + o; o += 2ull * NB * SL * DM;
  float* hsB  = ws + o; o += 2ull * NB * SL * DM;
  float* xzB  = ws + o; o += 2ull * NB * SL * XZW;
  float* xsB  = ws + o; o += 4ull * NB * SL * DI;
  float* dblB = ws + o; o += 4ull * NB * SL * DBLW;
  float* delB = ws + o; o += 4ull * NB * SL * DI;   // aliased as im2col P before layers
  float* y0B  = ws + o; o += 2ull * NB * SL * DI;   // aliased as patch mm out before layers
  float* y1B  = ws + o; o += 2ull * NB * SL * DI;
  float* fTB  = ws + o; o += 2ull * NB * NT * DM;
  float* qkvL = ws + o; o += 3ull * NB * NT * DM;
  float* qkvD = ws + o; o += 3ull * NB * DM * NT;
  float* Pb   = ws + o; o += (size_t)NB * NH * 64 * 64;
  float* attB = ws + o; o += (size_t)NB * DM * NT;
  (void)ws_size; (void)in_sizes; (void)n_in; (void)out_size;

  const int M = NB * SL;  // 788 rows per encoder

  k_rope_init<<<(NT * DM + 255) / 256, 256, 0, stream>>>(cosT, sinT);

  // patch embed as im2col + GEMM + epilogue (delB/y0B reused as scratch here)
  float* Pm = delB;       // (2, 784, 768)
  float* Pout = y0B;      // (2, 784, 192)
  k_im2col<<<(2 * 784 * 768 + 255) / 256, 256, 0, stream>>>(x1, x2, Pm);
  {
    MM4 p{};
    for (int e = 0; e < 2; ++e) {
      p.A0[e] = Pm + (size_t)e * 784 * 768;
      p.A1[e] = nullptr;
      p.B[e]  = patch_w + (size_t)e * DM * 768;
      p.C[e]  = Pout + (size_t)e * 784 * DM;
    }
    dim3 g((DM + 63) / 64, (784 + 63) / 64, 2);
    k_mm64<<<g, 256, 0, stream>>>(p, 784, DM, 768, 1.f);
  }
  k_patch_fin<<<(2 * NB * SL * DM + 255) / 256, 256, 0, stream>>>(
      Pout, patch_b, cls_tok, pos_emb, hB, resB);

  for (int l = 0; l < NL; ++l) {
    k_rope_res_norm<<<2 * NB * SL, DM, 0, stream>>>(hB, resB, hsB, norm_w, cosT, sinT, l);

    // xz = hs @ in_w^T  (per encoder)
    {
      MM4 p{};
      for (int e = 0; e < 2; ++e) {
        p.A0[e] = hsB + (size_t)e * M * DM;
        p.A1[e] = nullptr;
        p.B[e]  = in_w + (size_t)(e * NL + l) * XZW * DM;
        p.C[e]  = xzB + (size_t)e * M * XZW;
      }
      dim3 g((XZW + 63) / 64, (M + 63) / 64, 2);
      k_mm64<<<g, 256, 0, stream>>>(p, M, XZW, DM, 1.f);
    }

    k_conv_silu<<<(2 * 2 * NB * SL * DI + 255) / 256, 256, 0, stream>>>(xzB, conv_w, conv_b, xsB, l);

    // dbl = xs @ xp_w^T (per e,dir)
    {
      MM4 p{};
      for (int z = 0; z < 4; ++z) {
        int e = z / 2, dir = z % 2;
        p.A0[z] = xsB + (size_t)z * M * DI;
        p.A1[z] = nullptr;
        p.B[z]  = xp_w + ((size_t)(e * NL + l) * 2 + dir) * DBLW * DI;
        p.C[z]  = dblB + (size_t)z * M * DBLW;
      }
      dim3 g((DBLW + 63) / 64, (M + 63) / 64, 4);
      k_mm64<<<g, 256, 0, stream>>>(p, M, DBLW, DI, 1.f);
    }

    k_delta<<<(2 * 2 * NB * SL * DI + 255) / 256, 256, 0, stream>>>(dblB, dt_w, dt_b, delB, l);

    k_scan<<<2 * 2 * NB * (DI / 16), 256, 0, stream>>>(xsB, delB, dblB, xzB, A_log, Dp, y0B, y1B, l);

    // h = 0.5*(y0+y1) @ out_w^T (per encoder)
    {
      MM4 p{};
      for (int e = 0; e < 2; ++e) {
        p.A0[e] = y0B + (size_t)e * M * DI;
        p.A1[e] = y1B + (size_t)e * M * DI;
        p.B[e]  = out_w + (size_t)(e * NL + l) * DM * DI;
        p.C[e]  = hB + (size_t)e * M * DM;
      }
      dim3 g((DM + 63) / 64, (M + 63) / 64, 2);
      k_mm64<<<g, 256, 0, stream>>>(p, M, DM, DI, 0.5f);
    }
  }

  k_final_norm<<<2 * NB * NT, DM, 0, stream>>>(hB, resB, normf_w, fTB);

  // q/k/v linear: q from f1 (e=0), k,v from f2 (e=1)
  {
    MM4 p{};
    const int Mq = NB * NT;  // 784
    p.A0[0] = fTB;                         p.A1[0] = nullptr; p.B[0] = qw; p.C[0] = qkvL;
    p.A0[1] = fTB + (size_t)NB * NT * DM;  p.A1[1] = nullptr; p.B[1] = kw; p.C[1] = qkvL + (size_t)Mq * DM;
    p.A0[2] = fTB + (size_t)NB * NT * DM;  p.A1[2] = nullptr; p.B[2] = vw; p.C[2] = qkvL + 2ull * Mq * DM;
    dim3 g((DM + 63) / 64, (Mq + 63) / 64, 3);
    k_mm64<<<g, 256, 0, stream>>>(p, Mq, DM, DM, 1.f);
  }

  k_dwconv<<<(3 * NB * DM * NT + 255) / 256, 256, 0, stream>>>(qkvL, qdw, kdw, vdw, qkvD);
  k_l2norm<<<2 * NB * DM, 256, 0, stream>>>(qkvD);
  k_attn_sm<<<NB * NH * 64, 64, 0, stream>>>(qkvD, temp, Pb);
  k_av<<<NB * NH * 64, 256, 0, stream>>>(Pb, qkvD, attB);
  k_out<<<NB * DM, 256, 0, stream>>>(attB, pww, (float*)d_out);
}

// Round 9
// 3296.924 us; speedup vs baseline: 2.0490x; 1.0795x over previous
//
#include <hip/hip_runtime.h>

#define DM 192      // D_MODEL
#define DI 384      // D_INNER
#define DSt 16      // D_STATE
#define DTR 12      // DT_RANK
#define DC 4        // D_CONV
#define NL 24       // DEPTH
#define HP 14
#define NH 3
#define NB 4        // BATCH
#define SL 197      // seq len (tokens + cls)
#define NT 196      // spatial tokens
#define XZW 768     // 2*D_INNER
#define DBLW 44     // DT_RANK + 2*D_STATE
#define TC 32       // scan chunk (steps staged in LDS)
#define NCHK 7      // ceil(197/32)

static __device__ __forceinline__ float siluf(float x) { return x / (1.f + expf(-x)); }
static __device__ __forceinline__ float softplusf(float x) { return (x > 20.f) ? x : log1pf(expf(x)); }

// DPP-based add of a shifted copy (VALU pipe, no LDS crossbar).
template <int CTRL>
static __device__ __forceinline__ float dpp_addf(float x) {
  int y = __builtin_amdgcn_update_dpp(0, __float_as_int(x), CTRL, 0xF, 0xF, true);
  return x + __int_as_float(y);
}

// ---- block reduce helpers ----
static __device__ __forceinline__ float blk_sum3(float v, float* wsum) {
  for (int off = 32; off; off >>= 1) v += __shfl_xor(v, off, 64);
  int wid = threadIdx.x >> 6;
  if ((threadIdx.x & 63) == 0) wsum[wid] = v;
  __syncthreads();
  return wsum[0] + wsum[1] + wsum[2];
}
static __device__ __forceinline__ float blk_sum4(float v, float* wsum) {
  for (int off = 32; off; off >>= 1) v += __shfl_xor(v, off, 64);
  int wid = threadIdx.x >> 6;
  if ((threadIdx.x & 63) == 0) wsum[wid] = v;
  __syncthreads();
  return wsum[0] + wsum[1] + wsum[2] + wsum[3];
}

// ---- rope tables: cos/sin (196,192) ----
__global__ void k_rope_init(float* __restrict__ cosT, float* __restrict__ sinT) {
  int gid = blockIdx.x * blockDim.x + threadIdx.x;
  if (gid >= NT * DM) return;
  int c = gid % DM, tk = gid / DM;
  int py = tk / HP, px = tk % HP;
  int pos = (c < 96) ? py : px;
  int i = (c < 96) ? (c >> 1) : ((c - 96) >> 1);
  double fb = pow(10000.0, -((double)(2 * i)) / 96.0);
  double ang = (double)pos * fb;
  cosT[gid] = (float)cos(ang);
  sinT[gid] = (float)sin(ang);
}

// ---- im2col: P (2, 784, 768) patch matrix ----
__global__ void k_im2col(const float* __restrict__ x1, const float* __restrict__ x2,
                         float* __restrict__ P) {
  int gid = blockIdx.x * blockDim.x + threadIdx.x;
  if (gid >= 2 * 784 * 768) return;
  int col = gid % 768;
  int row = (gid / 768) % 784;
  int e = gid / (768 * 784);
  int b = row / NT, tk = row % NT;
  int c = col >> 8, r = (col >> 4) & 15, xx = col & 15;
  int py = tk / HP, px = tk % HP;
  const float* img = e ? x2 : x1;
  P[gid] = img[((size_t)(b * 3 + c) * 224 + (py * 16 + r)) * 224 + (px * 16 + xx)];
}

// ---- patch epilogue: h = mm_out + pb + pos (cls row special); res = 0 ----
__global__ void k_patch_fin(const float* __restrict__ pm, const float* __restrict__ pb,
                            const float* __restrict__ cls, const float* __restrict__ pos,
                            float* __restrict__ h, float* __restrict__ res) {
  int gid = blockIdx.x * blockDim.x + threadIdx.x;
  if (gid >= 2 * NB * SL * DM) return;
  int c = gid % DM;
  int t = (gid / DM) % SL;
  int b = (gid / (DM * SL)) % NB;
  int e = gid / (DM * SL * NB);
  float v;
  if (t == 0) v = cls[e * DM + c];
  else v = pm[((size_t)e * 784 + b * NT + (t - 1)) * DM + c] + pb[e * DM + c];
  h[gid] = v + pos[((size_t)e * SL + t) * DM + c];
  res[gid] = 0.f;
}

// ---- per layer: rope(h); res += ; hs = rmsnorm(res)*nw ----
__global__ __launch_bounds__(DM) void k_rope_res_norm(
    const float* __restrict__ h, float* __restrict__ res, float* __restrict__ hs,
    const float* __restrict__ nw, const float* __restrict__ cosT,
    const float* __restrict__ sinT, int l) {
  int bx = blockIdx.x;
  int t = bx % SL; int b = (bx / SL) % NB; int e = bx / (SL * NB);
  int c = threadIdx.x;
  __shared__ float sh[DM];
  __shared__ float wsum[3];
  size_t base = ((size_t)(e * NB + b) * SL + t) * DM;
  sh[c] = h[base + c];
  __syncthreads();
  float v = sh[c];
  if (t > 0) {
    int tk = t - 1;
    float co = cosT[tk * DM + c], si = sinT[tk * DM + c];
    float partner = sh[c ^ 1];
    float rot = (c & 1) ? partner : -partner;
    v = v * co + rot * si;
  }
  float r = res[base + c] + v;
  res[base + c] = r;
  float tot = blk_sum3(r * r, wsum);
  float scale = rsqrtf(tot / (float)DM + 1e-5f);
  hs[base + c] = r * scale * nw[(size_t)(e * NL + l) * DM + c];
}

// ---- register-blocked tiled GEMM: C = alpha*(A0[+A1]) @ B^T ----
struct MM4 {
  const float* A0[4];
  const float* A1[4];
  const float* B[4];
  float* C[4];
};
__global__ __launch_bounds__(256) void k_mm64(MM4 p, int M, int N, int K, float alpha) {
  const float* __restrict__ A0 = p.A0[blockIdx.z];
  const float* __restrict__ A1 = p.A1[blockIdx.z];
  const float* __restrict__ Bw = p.B[blockIdx.z];
  float* __restrict__ C = p.C[blockIdx.z];
  __shared__ __align__(16) float As[16][68];
  __shared__ __align__(16) float Bs[16][68];
  int tid = threadIdx.x;
  int m0 = blockIdx.y * 64, n0 = blockIdx.x * 64;
  int tm = tid >> 4, tn = tid & 15;       // compute roles
  int srow = tid >> 2, skq = tid & 3;     // staging roles
  int gmA = min(m0 + srow, M - 1);
  int gnB = min(n0 + srow, N - 1);
  bool hasA1 = (A1 != nullptr);
  float4 ra, rb, ra1;

  auto GLOAD = [&](int k0) {
    ra = *(const float4*)&A0[(size_t)gmA * K + k0 + skq * 4];
    if (hasA1) ra1 = *(const float4*)&A1[(size_t)gmA * K + k0 + skq * 4];
    rb = *(const float4*)&Bw[(size_t)gnB * K + k0 + skq * 4];
  };
  auto DSW = [&]() {
    float av0 = ra.x, av1 = ra.y, av2 = ra.z, av3 = ra.w;
    if (hasA1) { av0 += ra1.x; av1 += ra1.y; av2 += ra1.z; av3 += ra1.w; }
    int kb = skq * 4;
    As[kb + 0][srow] = av0;
    As[kb + 1][srow] = av1;
    As[kb + 2][srow] = av2;
    As[kb + 3][srow] = av3;
    Bs[kb + 0][srow] = rb.x;
    Bs[kb + 1][srow] = rb.y;
    Bs[kb + 2][srow] = rb.z;
    Bs[kb + 3][srow] = rb.w;
  };

  float acc[4][4] = {};
  int T = K >> 4;
  GLOAD(0);
  DSW();
  __syncthreads();
#pragma unroll 1
  for (int kt = 1; kt <= T; ++kt) {
    if (kt < T) GLOAD(kt * 16);
#pragma unroll
    for (int kk = 0; kk < 16; ++kk) {
      float4 a = *(const float4*)&As[kk][tm * 4];
      float4 b = *(const float4*)&Bs[kk][tn * 4];
      float av[4] = {a.x, a.y, a.z, a.w};
      float bv[4] = {b.x, b.y, b.z, b.w};
#pragma unroll
      for (int mi = 0; mi < 4; ++mi)
#pragma unroll
        for (int ni = 0; ni < 4; ++ni)
          acc[mi][ni] += av[mi] * bv[ni];
    }
    if (kt < T) {
      __syncthreads();
      DSW();
      __syncthreads();
    }
  }
#pragma unroll
  for (int mi = 0; mi < 4; ++mi) {
    int gm = m0 + tm * 4 + mi;
    if (gm >= M) continue;
    int gn = n0 + tn * 4;
    if (gn + 3 < N) {
      float4 o4 = make_float4(alpha * acc[mi][0], alpha * acc[mi][1],
                              alpha * acc[mi][2], alpha * acc[mi][3]);
      *(float4*)&C[(size_t)gm * N + gn] = o4;
    } else {
#pragma unroll
      for (int ni = 0; ni < 4; ++ni)
        if (gn + ni < N) C[(size_t)gm * N + gn + ni] = alpha * acc[mi][ni];
    }
  }
}

// ---- causal depthwise conv (k=4) + silu; handles direction reversal ----
__global__ void k_conv_silu(const float* __restrict__ xz, const float* __restrict__ cw,
                            const float* __restrict__ cb, float* __restrict__ xs, int l) {
  int gid = blockIdx.x * blockDim.x + threadIdx.x;
  if (gid >= 2 * 2 * NB * SL * DI) return;
  int d = gid % DI;
  int t = (gid / DI) % SL;
  int b = (gid / (DI * SL)) % NB;
  int dir = (gid / (DI * SL * NB)) % 2;
  int e = gid / (DI * SL * NB * 2);
  size_t pidx = (size_t)(e * NL + l) * 2 + dir;
  const float* cwp = cw + (pidx * DI + d) * DC;
  float acc = cb[pidx * DI + d];
#pragma unroll
  for (int k = 0; k < DC; ++k) {
    int ts = t - (DC - 1) + k;
    if (ts >= 0) {
      int torig = dir ? (SL - 1 - ts) : ts;
      acc += cwp[k] * xz[((size_t)(e * NB + b) * SL + torig) * XZW + d];
    }
  }
  xs[gid] = siluf(acc);
}

// ---- delta = softplus(dt @ dw^T + db) ----
__global__ void k_delta(const float* __restrict__ dbl, const float* __restrict__ dtw,
                        const float* __restrict__ dtb, float* __restrict__ delta, int l) {
  int gid = blockIdx.x * blockDim.x + threadIdx.x;
  if (gid >= 2 * 2 * NB * SL * DI) return;
  int d = gid % DI;
  int t = (gid / DI) % SL;
  int b = (gid / (DI * SL)) % NB;
  int dir = (gid / (DI * SL * NB)) % 2;
  int e = gid / (DI * SL * NB * 2);
  int z = e * 2 + dir;
  size_t pidx = (size_t)(e * NL + l) * 2 + dir;
  const float* row = dbl + ((size_t)(z * NB + b) * SL + t) * DBLW;
  const float* w = dtw + (pidx * DI + d) * DTR;
  float acc = dtb[pidx * DI + d];
#pragma unroll
  for (int r = 0; r < DTR; ++r) acc += row[r] * w[r];
  delta[gid] = softplusf(acc);
}

// ---- selective scan, LDS double-buffered staging; DPP reduce over n ----
// Per 16-step sub-batch: (a) LDS reads (dv,xv packed b64) + independent exps,
// (b) short serial h-chain (FMA only), (c) n-reduction entirely on the VALU
// pipe via DPP (quad_perm xor1/xor2 + row_shr:4/8; total lands in lanes
// n>=12), (d) stores from lane n==15.
__global__ __launch_bounds__(256) void k_scan(
    const float* __restrict__ xs, const float* __restrict__ delta,
    const float* __restrict__ dbl, const float* __restrict__ xz,
    const float* __restrict__ alog, const float* __restrict__ dpw,
    float* __restrict__ y0, float* __restrict__ y1, int l) {
  int bx = blockIdx.x;
  int dg = bx % (DI / 16);
  int b = (bx / (DI / 16)) % NB;
  int dir = (bx / (DI / 16 * NB)) % 2;
  int e = bx / (DI / 16 * NB * 2);
  int tid = threadIdx.x;
  int n = tid & 15;       // state index (compute role)
  int ch = tid >> 4;      // channel within group (compute role)
  int d = dg * 16 + ch;
  size_t pidx = (size_t)(e * NL + l) * 2 + dir;
  float A = -expf(alog[(pidx * DI + d) * DSt + n]);
  float dpv = dpw[pidx * DI + d];
  int z = e * 2 + dir;
  size_t dblbase = ((size_t)(z * NB + b) * SL) * DBLW;
  float* yout = dir ? y1 : y0;
  size_t ybase = ((size_t)(e * NB + b) * SL) * DI + d;

  // load-role bases
  int lch = tid & 15;       // channel for dv/xv/zv loads
  int ltt = tid >> 4;       // 0..15
  int lj = tid & 31;        // 0..31 (Bm|C)
  int ltt2 = tid >> 5;      // 0..7
  size_t gdbase = ((size_t)(z * NB + b) * SL) * DI + dg * 16 + lch;
  size_t gzbase = ((size_t)(e * NB + b) * SL) * XZW + DI + dg * 16 + lch;

  __shared__ float2 s_dx[2][TC][16];
  __shared__ float s_zv[2][TC][16];
  __shared__ float s_bc[2][TC][32];

  float r_dv[2], r_xv[2], r_zv[2], r_bc[4];

  auto LOADREG = [&](int c) {
    int t0 = c * TC;
#pragma unroll
    for (int k = 0; k < 2; ++k) {
      int t = t0 + ltt + 16 * k;
      int tm = t < SL ? t : SL - 1;
      r_dv[k] = delta[gdbase + (size_t)tm * DI];
      r_xv[k] = xs[gdbase + (size_t)tm * DI];
      int torig = dir ? (SL - 1 - tm) : tm;
      r_zv[k] = xz[gzbase + (size_t)torig * XZW];
    }
#pragma unroll
    for (int k = 0; k < 4; ++k) {
      int t = t0 + ltt2 + 8 * k;
      int tm = t < SL ? t : SL - 1;
      r_bc[k] = dbl[dblbase + (size_t)tm * DBLW + DTR + lj];
    }
  };
  auto STORE = [&](int pb) {
#pragma unroll
    for (int k = 0; k < 2; ++k) {
      s_dx[pb][ltt + 16 * k][lch] = make_float2(r_dv[k], r_xv[k]);
      s_zv[pb][ltt + 16 * k][lch] = r_zv[k];
    }
#pragma unroll
    for (int k = 0; k < 4; ++k) s_bc[pb][ltt2 + 8 * k][lj] = r_bc[k];
  };

  float hst = 0.f;
  auto COMP = [&](int pb, int c) {
    int t0 = c * TC;
#pragma unroll
    for (int half = 0; half < 2; ++half) {
      int i0 = half * 16;
      float ev[16], cc[16], cvv[16], xvv[16], pc[16];
      // (a) LDS reads (b64 packed) + independent exps
#pragma unroll
      for (int i = 0; i < 16; ++i) {
        float2 dx = s_dx[pb][i0 + i][ch];
        float bm = s_bc[pb][i0 + i][n];
        xvv[i] = dx.y;
        cvv[i] = s_bc[pb][i0 + i][16 + n];
        ev[i] = __expf(dx.x * A);
        cc[i] = (dx.x * xvv[i]) * bm;
      }
      // (b) short serial chain (one FMA + one mul per step)
#pragma unroll
      for (int i = 0; i < 16; ++i) {
        hst = ev[i] * hst + cc[i];
        pc[i] = hst * cvv[i];
      }
      // (c) n-reduce on the VALU pipe: DPP xor1, xor2, shr4, shr8
#pragma unroll
      for (int i = 0; i < 16; ++i) pc[i] = dpp_addf<0xB1>(pc[i]);   // quad xor1
#pragma unroll
      for (int i = 0; i < 16; ++i) pc[i] = dpp_addf<0x4E>(pc[i]);   // quad xor2
#pragma unroll
      for (int i = 0; i < 16; ++i) pc[i] = dpp_addf<0x114>(pc[i]);  // row_shr:4
#pragma unroll
      for (int i = 0; i < 16; ++i) pc[i] = dpp_addf<0x118>(pc[i]);  // row_shr:8
      // (d) batched stores (lane n==15 holds the full n-sum)
      if (n == 15) {
#pragma unroll
        for (int i = 0; i < 16; ++i) {
          int t = t0 + i0 + i;
          if (t < SL) {
            int torig = dir ? (SL - 1 - t) : t;
            float yv = pc[i] + xvv[i] * dpv;
            yout[ybase + (size_t)torig * DI] = yv * siluf(s_zv[pb][i0 + i][ch]);
          }
        }
      }
    }
  };

  LOADREG(0);
  STORE(0);
  LOADREG(1);
  __syncthreads();
  int pb = 0;
#pragma unroll 1
  for (int c = 0; c < NCHK; ++c) {
    COMP(pb, c);
    if (c + 1 < NCHK) {
      STORE(pb ^ 1);
      __syncthreads();
      if (c + 2 < NCHK) LOADREG(c + 2);
      pb ^= 1;
    }
  }
}

// ---- final: rmsnorm(h+res)*nfw, drop cls, token-major fT (e,b,196,192) ----
__global__ __launch_bounds__(DM) void k_final_norm(
    const float* __restrict__ h, const float* __restrict__ res,
    const float* __restrict__ nfw, float* __restrict__ fT) {
  int bx = blockIdx.x;
  int tk = bx % NT; int b = (bx / NT) % NB; int e = bx / (NT * NB);
  int c = threadIdx.x;
  __shared__ float wsum[3];
  size_t base = ((size_t)(e * NB + b) * SL + (tk + 1)) * DM;
  float r = h[base + c] + res[base + c];
  float tot = blk_sum3(r * r, wsum);
  float scale = rsqrtf(tot / (float)DM + 1e-5f);
  fT[((size_t)(e * NB + b) * NT + tk) * DM + c] = r * scale * nfw[e * DM + c];
}

// ---- depthwise 3x3 SAME over 14x14; in token-major, out channel-major ----
__global__ void k_dwconv(const float* __restrict__ qkvl, const float* __restrict__ qdw,
                         const float* __restrict__ kdw, const float* __restrict__ vdw,
                         float* __restrict__ qkvd) {
  int gid = blockIdx.x * blockDim.x + threadIdx.x;
  if (gid >= 3 * NB * DM * NT) return;
  int nn = gid % NT;
  int o = (gid / NT) % DM;
  int b = (gid / (NT * DM)) % NB;
  int zz = gid / (NT * DM * NB);
  const float* wsel = (zz == 0 ? qdw : (zz == 1 ? kdw : vdw)) + o * 9;
  int y = nn / HP, x = nn % HP;
  const float* in = qkvl + ((size_t)zz * NB + b) * NT * DM;
  float acc = 0.f;
#pragma unroll
  for (int ky = 0; ky < 3; ++ky) {
    int yy = y + ky - 1;
    if (yy < 0 || yy >= HP) continue;
#pragma unroll
    for (int kx = 0; kx < 3; ++kx) {
      int xx = x + kx - 1;
      if (xx < 0 || xx >= HP) continue;
      acc += in[(size_t)(yy * HP + xx) * DM + o] * wsel[ky * 3 + kx];
    }
  }
  qkvd[gid] = acc;
}

// ---- L2-normalize q,k rows over n=196 (in place) ----
__global__ __launch_bounds__(256) void k_l2norm(float* __restrict__ qkvd) {
  int bx = blockIdx.x;
  int C = bx % DM; int b = (bx / DM) % NB; int zz = bx / (DM * NB);
  int i = threadIdx.x;
  __shared__ float wsum[4];
  float* row = qkvd + ((size_t)zz * NB + b) * DM * NT + (size_t)C * NT;
  float v = (i < NT) ? row[i] : 0.f;
  float tot = blk_sum4(v * v, wsum);
  float sc = 1.f / fmaxf(sqrtf(tot), 1e-12f);
  if (i < NT) row[i] = v * sc;
}

// ---- S = temp*qn.kn^T, softmax over j (block=(b,h,i), 64 threads=j) ----
__global__ __launch_bounds__(64) void k_attn_sm(const float* __restrict__ qkvd,
                                                const float* __restrict__ temp,
                                                float* __restrict__ P) {
  int bx = blockIdx.x;
  int i = bx % 64; int hh = (bx / 64) % NH; int b = bx / (64 * NH);
  int j = threadIdx.x;
  __shared__ float qs[NT];
  const float* qrow = qkvd + ((size_t)0 * NB + b) * DM * NT + (size_t)(hh * 64 + i) * NT;
  for (int k = j; k < NT; k += 64) qs[k] = qrow[k];
  __syncthreads();
  const float* krow = qkvd + ((size_t)1 * NB + b) * DM * NT + (size_t)(hh * 64 + j) * NT;
  float acc = 0.f;
  for (int k = 0; k < NT; ++k) acc += qs[k] * krow[k];
  acc *= temp[hh];
  float m = acc;
  for (int off = 32; off; off >>= 1) m = fmaxf(m, __shfl_xor(m, off, 64));
  float ex = expf(acc - m);
  float s = ex;
  for (int off = 32; off; off >>= 1) s += __shfl_xor(s, off, 64);
  P[((size_t)(b * NH + hh) * 64 + i) * 64 + j] = ex / s;
}

// ---- out = P @ vh ----
__global__ __launch_bounds__(256) void k_av(const float* __restrict__ P,
                                            const float* __restrict__ qkvd,
                                            float* __restrict__ att) {
  int bx = blockIdx.x;
  int i = bx % 64; int hh = (bx / 64) % NH; int b = bx / (64 * NH);
  int nn = threadIdx.x;
  __shared__ float ps[64];
  if (nn < 64) ps[nn] = P[((size_t)(b * NH + hh) * 64 + i) * 64 + nn];
  __syncthreads();
  if (nn >= NT) return;
  const float* vbase = qkvd + ((size_t)2 * NB + b) * DM * NT + (size_t)(hh * 64) * NT + nn;
  float acc = 0.f;
  for (int j = 0; j < 64; ++j) acc += ps[j] * vbase[(size_t)j * NT];
  att[((size_t)b * DM + hh * 64 + i) * NT + nn] = acc;
}

// ---- final pointwise projection to d_out ----
__global__ __launch_bounds__(256) void k_out(const float* __restrict__ att,
                                             const float* __restrict__ pw,
                                             float* __restrict__ out) {
  int bx = blockIdx.x;
  int o = bx % DM; int b = bx / DM;
  int nn = threadIdx.x;
  if (nn >= NT) return;
  const float* abase = att + (size_t)b * DM * NT + nn;
  const float* w = pw + (size_t)o * DM;
  float acc = 0.f;
  for (int c = 0; c < DM; ++c) acc += abase[(size_t)c * NT] * w[c];
  out[((size_t)b * DM + o) * NT + nn] = acc;
}

extern "C" void kernel_launch(void* const* d_in, const int* in_sizes, int n_in,
                              void* d_out, int out_size, void* d_ws, size_t ws_size,
                              hipStream_t stream) {
  const float* x1      = (const float*)d_in[0];
  const float* x2      = (const float*)d_in[1];
  const float* patch_w = (const float*)d_in[2];
  const float* patch_b = (const float*)d_in[3];
  const float* cls_tok = (const float*)d_in[4];
  const float* pos_emb = (const float*)d_in[5];
  const float* norm_w  = (const float*)d_in[6];
  const float* in_w    = (const float*)d_in[7];
  const float* conv_w  = (const float*)d_in[8];
  const float* conv_b  = (const float*)d_in[9];
  const float* xp_w    = (const float*)d_in[10];
  const float* dt_w    = (const float*)d_in[11];
  const float* dt_b    = (const float*)d_in[12];
  const float* A_log   = (const float*)d_in[13];
  const float* Dp      = (const float*)d_in[14];
  const float* out_w   = (const float*)d_in[15];
  const float* normf_w = (const float*)d_in[16];
  const float* qw      = (const float*)d_in[17];
  const float* qdw     = (const float*)d_in[18];
  const float* kw      = (const float*)d_in[19];
  const float* kdw     = (const float*)d_in[20];
  const float* vw      = (const float*)d_in[21];
  const float* vdw     = (const float*)d_in[22];
  const float* pww     = (const float*)d_in[23];
  const float* temp    = (const float*)d_in[24];

  float* ws = (float*)d_ws;
  size_t o = 0;
  float* cosT = ws + o; o += (size_t)NT * DM;
  float* sinT = ws + o; o += (size_t)NT * DM;
  float* hB   = ws + o; o += 2ull * NB * SL * DM;
  float* resB = ws + o; o += 2ull * NB * SL * DM;
  float* hsB  = ws + o; o += 2ull * NB * SL * DM;
  float* xzB  = ws + o; o += 2ull * NB * SL * XZW;
  float* xsB  = ws + o; o += 4ull * NB * SL * DI;
  float* dblB = ws + o; o += 4ull * NB * SL * DBLW;
  float* delB = ws + o; o += 4ull * NB * SL * DI;   // aliased as im2col P before layers
  float* y0B  = ws + o; o += 2ull * NB * SL * DI;   // aliased as patch mm out before layers
  float* y1B  = ws + o; o += 2ull * NB * SL * DI;
  float* fTB  = ws + o; o += 2ull * NB * NT * DM;
  float* qkvL = ws + o; o += 3ull * NB * NT * DM;
  float* qkvD = ws + o; o += 3ull * NB * DM * NT;
  float* Pb   = ws + o; o += (size_t)NB * NH * 64 * 64;
  float* attB = ws + o; o += (size_t)NB * DM * NT;
  (void)ws_size; (void)in_sizes; (void)n_in; (void)out_size;

  const int M = NB * SL;  // 788 rows per encoder

  k_rope_init<<<(NT * DM + 255) / 256, 256, 0, stream>>>(cosT, sinT);

  // patch embed as im2col + GEMM + epilogue (delB/y0B reused as scratch here)
  float* Pm = delB;       // (2, 784, 768)
  float* Pout = y0B;      // (2, 784, 192)
  k_im2col<<<(2 * 784 * 768 + 255) / 256, 256, 0, stream>>>(x1, x2, Pm);
  {
    MM4 p{};
    for (int e = 0; e < 2; ++e) {
      p.A0[e] = Pm + (size_t)e * 784 * 768;
      p.A1[e] = nullptr;
      p.B[e]  = patch_w + (size_t)e * DM * 768;
      p.C[e]  = Pout + (size_t)e * 784 * DM;
    }
    dim3 g((DM + 63) / 64, (784 + 63) / 64, 2);
    k_mm64<<<g, 256, 0, stream>>>(p, 784, DM, 768, 1.f);
  }
  k_patch_fin<<<(2 * NB * SL * DM + 255) / 256, 256, 0, stream>>>(
      Pout, patch_b, cls_tok, pos_emb, hB, resB);

  for (int l = 0; l < NL; ++l) {
    k_rope_res_norm<<<2 * NB * SL, DM, 0, stream>>>(hB, resB, hsB, norm_w, cosT, sinT, l);

    // xz = hs @ in_w^T  (per encoder)
    {
      MM4 p{};
      for (int e = 0; e < 2; ++e) {
        p.A0[e] = hsB + (size_t)e * M * DM;
        p.A1[e] = nullptr;
        p.B[e]  = in_w + (size_t)(e * NL + l) * XZW * DM;
        p.C[e]  = xzB + (size_t)e * M * XZW;
      }
      dim3 g((XZW + 63) / 64, (M + 63) / 64, 2);
      k_mm64<<<g, 256, 0, stream>>>(p, M, XZW, DM, 1.f);
    }

    k_conv_silu<<<(2 * 2 * NB * SL * DI + 255) / 256, 256, 0, stream>>>(xzB, conv_w, conv_b, xsB, l);

    // dbl = xs @ xp_w^T (per e,dir)
    {
      MM4 p{};
      for (int z = 0; z < 4; ++z) {
        int e = z / 2, dir = z % 2;
        p.A0[z] = xsB + (size_t)z * M * DI;
        p.A1[z] = nullptr;
        p.B[z]  = xp_w + ((size_t)(e * NL + l) * 2 + dir) * DBLW * DI;
        p.C[z]  = dblB + (size_t)z * M * DBLW;
      }
      dim3 g((DBLW + 63) / 64, (M + 63) / 64, 4);
      k_mm64<<<g, 256, 0, stream>>>(p, M, DBLW, DI, 1.f);
    }

    k_delta<<<(2 * 2 * NB * SL * DI + 255) / 256, 256, 0, stream>>>(dblB, dt_w, dt_b, delB, l);

    k_scan<<<2 * 2 * NB * (DI / 16), 256, 0, stream>>>(xsB, delB, dblB, xzB, A_log, Dp, y0B, y1B, l);

    // h = 0.5*(y0+y1) @ out_w^T (per encoder)
    {
      MM4 p{};
      for (int e = 0; e < 2; ++e) {
        p.A0[e] = y0B + (size_t)e * M * DI;
        p.A1[e] = y1B + (size_t)e * M * DI;
        p.B[e]  = out_w + (size_t)(e * NL + l) * DM * DI;
        p.C[e]  = hB + (size_t)e * M * DM;
      }
      dim3 g((DM + 63) / 64, (M + 63) / 64, 2);
      k_mm64<<<g, 256, 0, stream>>>(p, M, DM, DI, 0.5f);
    }
  }

  k_final_norm<<<2 * NB * NT, DM, 0, stream>>>(hB, resB, normf_w, fTB);

  // q/k/v linear: q from f1 (e=0), k,v from f2 (e=1)
  {
    MM4 p{};
    const int Mq = NB * NT;  // 784
    p.A0[0] = fTB;                         p.A1[0] = nullptr; p.B[0] = qw; p.C[0] = qkvL;
    p.A0[1] = fTB + (size_t)NB * NT * DM;  p.A1[1] = nullptr; p.B[1] = kw; p.C[1] = qkvL + (size_t)Mq * DM;
    p.A0[2] = fTB + (size_t)NB * NT * DM;  p.A1[2] = nullptr; p.B[2] = vw; p.C[2] = qkvL + 2ull * Mq * DM;
    dim3 g((DM + 63) / 64, (Mq + 63) / 64, 3);
    k_mm64<<<g, 256, 0, stream>>>(p, Mq, DM, DM, 1.f);
  }

  k_dwconv<<<(3 * NB * DM * NT + 255) / 256, 256, 0, stream>>>(qkvL, qdw, kdw, vdw, qkvD);
  k_l2norm<<<2 * NB * DM, 256, 0, stream>>>(qkvD);
  k_attn_sm<<<NB * NH * 64, 64, 0, stream>>>(qkvD, temp, Pb);
  k_av<<<NB * NH * 64, 256, 0, stream>>>(Pb, qkvD, attB);
  k_out<<<NB * DM, 256, 0, stream>>>(attB, pww, (float*)d_out);
}

// Round 11
// 3070.334 us; speedup vs baseline: 2.2002x; 1.0738x over previous
//
#include <hip/hip_runtime.h>

#define DM 192      // D_MODEL
#define DI 384      // D_INNER
#define DSt 16      // D_STATE
#define DTR 12      // DT_RANK
#define DC 4        // D_CONV
#define NL 24       // DEPTH
#define HP 14
#define NH 3
#define NB 4        // BATCH
#define SL 197      // seq len (tokens + cls)
#define NT 196      // spatial tokens
#define XZW 768     // 2*D_INNER
#define DBLW 44     // DT_RANK + 2*D_STATE
#define TC 32       // scan chunk (steps staged in LDS)
#define NCHK 7      // ceil(197/32)

static __device__ __forceinline__ float siluf(float x) { return x / (1.f + expf(-x)); }
static __device__ __forceinline__ float softplusf(float x) { return (x > 20.f) ? x : log1pf(expf(x)); }

// DPP-based add of a shifted copy (VALU pipe, no LDS crossbar).
template <int CTRL>
static __device__ __forceinline__ float dpp_addf(float x) {
  int y = __builtin_amdgcn_update_dpp(0, __float_as_int(x), CTRL, 0xF, 0xF, true);
  return x + __int_as_float(y);
}

// ---- block reduce helpers ----
static __device__ __forceinline__ float blk_sum3(float v, float* wsum) {
  for (int off = 32; off; off >>= 1) v += __shfl_xor(v, off, 64);
  int wid = threadIdx.x >> 6;
  if ((threadIdx.x & 63) == 0) wsum[wid] = v;
  __syncthreads();
  return wsum[0] + wsum[1] + wsum[2];
}
static __device__ __forceinline__ float blk_sum4(float v, float* wsum) {
  for (int off = 32; off; off >>= 1) v += __shfl_xor(v, off, 64);
  int wid = threadIdx.x >> 6;
  if ((threadIdx.x & 63) == 0) wsum[wid] = v;
  __syncthreads();
  return wsum[0] + wsum[1] + wsum[2] + wsum[3];
}

// ---- rope tables: cos/sin (196,192) ----
__global__ void k_rope_init(float* __restrict__ cosT, float* __restrict__ sinT) {
  int gid = blockIdx.x * blockDim.x + threadIdx.x;
  if (gid >= NT * DM) return;
  int c = gid % DM, tk = gid / DM;
  int py = tk / HP, px = tk % HP;
  int pos = (c < 96) ? py : px;
  int i = (c < 96) ? (c >> 1) : ((c - 96) >> 1);
  double fb = pow(10000.0, -((double)(2 * i)) / 96.0);
  double ang = (double)pos * fb;
  cosT[gid] = (float)cos(ang);
  sinT[gid] = (float)sin(ang);
}

// ---- im2col: P (2, 784, 768) patch matrix ----
__global__ void k_im2col(const float* __restrict__ x1, const float* __restrict__ x2,
                         float* __restrict__ P) {
  int gid = blockIdx.x * blockDim.x + threadIdx.x;
  if (gid >= 2 * 784 * 768) return;
  int col = gid % 768;
  int row = (gid / 768) % 784;
  int e = gid / (768 * 784);
  int b = row / NT, tk = row % NT;
  int c = col >> 8, r = (col >> 4) & 15, xx = col & 15;
  int py = tk / HP, px = tk % HP;
  const float* img = e ? x2 : x1;
  P[gid] = img[((size_t)(b * 3 + c) * 224 + (py * 16 + r)) * 224 + (px * 16 + xx)];
}

// ---- patch epilogue: h = mm_out + pb + pos (cls row special); res = 0 ----
__global__ void k_patch_fin(const float* __restrict__ pm, const float* __restrict__ pb,
                            const float* __restrict__ cls, const float* __restrict__ pos,
                            float* __restrict__ h, float* __restrict__ res) {
  int gid = blockIdx.x * blockDim.x + threadIdx.x;
  if (gid >= 2 * NB * SL * DM) return;
  int c = gid % DM;
  int t = (gid / DM) % SL;
  int b = (gid / (DM * SL)) % NB;
  int e = gid / (DM * SL * NB);
  float v;
  if (t == 0) v = cls[e * DM + c];
  else v = pm[((size_t)e * 784 + b * NT + (t - 1)) * DM + c] + pb[e * DM + c];
  h[gid] = v + pos[((size_t)e * SL + t) * DM + c];
  res[gid] = 0.f;
}

// ---- per layer: rope(h); res += ; hs = rmsnorm(res)*nw ----
__global__ __launch_bounds__(DM) void k_rope_res_norm(
    const float* __restrict__ h, float* __restrict__ res, float* __restrict__ hs,
    const float* __restrict__ nw, const float* __restrict__ cosT,
    const float* __restrict__ sinT, int l) {
  int bx = blockIdx.x;
  int t = bx % SL; int b = (bx / SL) % NB; int e = bx / (SL * NB);
  int c = threadIdx.x;
  __shared__ float sh[DM];
  __shared__ float wsum[3];
  size_t base = ((size_t)(e * NB + b) * SL + t) * DM;
  sh[c] = h[base + c];
  __syncthreads();
  float v = sh[c];
  if (t > 0) {
    int tk = t - 1;
    float co = cosT[tk * DM + c], si = sinT[tk * DM + c];
    float partner = sh[c ^ 1];
    float rot = (c & 1) ? partner : -partner;
    v = v * co + rot * si;
  }
  float r = res[base + c] + v;
  res[base + c] = r;
  float tot = blk_sum3(r * r, wsum);
  float scale = rsqrtf(tot / (float)DM + 1e-5f);
  hs[base + c] = r * scale * nw[(size_t)(e * NL + l) * DM + c];
}

// ---- register-blocked tiled GEMM: C = alpha*(A0[+A1]) @ B^T ----
// 32x64 tile, BK=16, 256 threads, 2x4 outputs/thread (float2 x float4).
// Small BM doubles block count for skinny-M matrices (occupancy was the
// limiter at BM=64: out-proj had only 78 blocks on 256 CUs).
struct MM4 {
  const float* A0[4];
  const float* A1[4];
  const float* B[4];
  float* C[4];
};
__global__ __launch_bounds__(256) void k_mm32(MM4 p, int M, int N, int K, float alpha) {
  const float* __restrict__ A0 = p.A0[blockIdx.z];
  const float* __restrict__ A1 = p.A1[blockIdx.z];
  const float* __restrict__ Bw = p.B[blockIdx.z];
  float* __restrict__ C = p.C[blockIdx.z];
  __shared__ __align__(16) float As[16][34];
  __shared__ __align__(16) float Bs[16][68];
  int tid = threadIdx.x;
  int m0 = blockIdx.y * 32, n0 = blockIdx.x * 64;
  int tm = tid >> 4, tn = tid & 15;        // compute roles: rows tm*2..+1, cols tn*4..+3
  int srow = tid >> 2, skq = tid & 3;      // B staging: 64 rows x 4 quads
  int srowA = (tid & 127) >> 2;            // A staging (tid<128): 32 rows x 4 quads
  bool doA = tid < 128;
  int gmA = min(m0 + srowA, M - 1);
  int gnB = min(n0 + srow, N - 1);
  bool hasA1 = (A1 != nullptr);
  float4 ra, rb, ra1;

  auto GLOAD = [&](int k0) {
    if (doA) {
      ra = *(const float4*)&A0[(size_t)gmA * K + k0 + skq * 4];
      if (hasA1) ra1 = *(const float4*)&A1[(size_t)gmA * K + k0 + skq * 4];
    }
    rb = *(const float4*)&Bw[(size_t)gnB * K + k0 + skq * 4];
  };
  auto DSW = [&]() {
    int kb = skq * 4;
    if (doA) {
      float av0 = ra.x, av1 = ra.y, av2 = ra.z, av3 = ra.w;
      if (hasA1) { av0 += ra1.x; av1 += ra1.y; av2 += ra1.z; av3 += ra1.w; }
      As[kb + 0][srowA] = av0;
      As[kb + 1][srowA] = av1;
      As[kb + 2][srowA] = av2;
      As[kb + 3][srowA] = av3;
    }
    Bs[kb + 0][srow] = rb.x;
    Bs[kb + 1][srow] = rb.y;
    Bs[kb + 2][srow] = rb.z;
    Bs[kb + 3][srow] = rb.w;
  };

  float acc[2][4] = {};
  int T = K >> 4;
  GLOAD(0);
  DSW();
  __syncthreads();
#pragma unroll 1
  for (int kt = 1; kt <= T; ++kt) {
    if (kt < T) GLOAD(kt * 16);
#pragma unroll
    for (int kk = 0; kk < 16; ++kk) {
      float2 a = *(const float2*)&As[kk][tm * 2];
      float4 b = *(const float4*)&Bs[kk][tn * 4];
      acc[0][0] += a.x * b.x; acc[0][1] += a.x * b.y;
      acc[0][2] += a.x * b.z; acc[0][3] += a.x * b.w;
      acc[1][0] += a.y * b.x; acc[1][1] += a.y * b.y;
      acc[1][2] += a.y * b.z; acc[1][3] += a.y * b.w;
    }
    if (kt < T) {
      __syncthreads();
      DSW();
      __syncthreads();
    }
  }
#pragma unroll
  for (int mi = 0; mi < 2; ++mi) {
    int gm = m0 + tm * 2 + mi;
    if (gm >= M) continue;
    int gn = n0 + tn * 4;
    if (gn + 3 < N) {
      float4 o4 = make_float4(alpha * acc[mi][0], alpha * acc[mi][1],
                              alpha * acc[mi][2], alpha * acc[mi][3]);
      *(float4*)&C[(size_t)gm * N + gn] = o4;
    } else {
#pragma unroll
      for (int ni = 0; ni < 4; ++ni)
        if (gn + ni < N) C[(size_t)gm * N + gn + ni] = alpha * acc[mi][ni];
    }
  }
}

// ---- causal depthwise conv (k=4) + silu; handles direction reversal ----
__global__ void k_conv_silu(const float* __restrict__ xz, const float* __restrict__ cw,
                            const float* __restrict__ cb, float* __restrict__ xs, int l) {
  int gid = blockIdx.x * blockDim.x + threadIdx.x;
  if (gid >= 2 * 2 * NB * SL * DI) return;
  int d = gid % DI;
  int t = (gid / DI) % SL;
  int b = (gid / (DI * SL)) % NB;
  int dir = (gid / (DI * SL * NB)) % 2;
  int e = gid / (DI * SL * NB * 2);
  size_t pidx = (size_t)(e * NL + l) * 2 + dir;
  const float* cwp = cw + (pidx * DI + d) * DC;
  float acc = cb[pidx * DI + d];
#pragma unroll
  for (int k = 0; k < DC; ++k) {
    int ts = t - (DC - 1) + k;
    if (ts >= 0) {
      int torig = dir ? (SL - 1 - ts) : ts;
      acc += cwp[k] * xz[((size_t)(e * NB + b) * SL + torig) * XZW + d];
    }
  }
  xs[gid] = siluf(acc);
}

// ---- delta = softplus(dt @ dw^T + db) ----
__global__ void k_delta(const float* __restrict__ dbl, const float* __restrict__ dtw,
                        const float* __restrict__ dtb, float* __restrict__ delta, int l) {
  int gid = blockIdx.x * blockDim.x + threadIdx.x;
  if (gid >= 2 * 2 * NB * SL * DI) return;
  int d = gid % DI;
  int t = (gid / DI) % SL;
  int b = (gid / (DI * SL)) % NB;
  int dir = (gid / (DI * SL * NB)) % 2;
  int e = gid / (DI * SL * NB * 2);
  int z = e * 2 + dir;
  size_t pidx = (size_t)(e * NL + l) * 2 + dir;
  const float* row = dbl + ((size_t)(z * NB + b) * SL + t) * DBLW;
  const float* w = dtw + (pidx * DI + d) * DTR;
  float acc = dtb[pidx * DI + d];
#pragma unroll
  for (int r = 0; r < DTR; ++r) acc += row[r] * w[r];
  delta[gid] = softplusf(acc);
}

// ---- selective scan, LDS double-buffered staging; DPP reduce over n ----
__global__ __launch_bounds__(256) void k_scan(
    const float* __restrict__ xs, const float* __restrict__ delta,
    const float* __restrict__ dbl, const float* __restrict__ xz,
    const float* __restrict__ alog, const float* __restrict__ dpw,
    float* __restrict__ y0, float* __restrict__ y1, int l) {
  int bx = blockIdx.x;
  int dg = bx % (DI / 16);
  int b = (bx / (DI / 16)) % NB;
  int dir = (bx / (DI / 16 * NB)) % 2;
  int e = bx / (DI / 16 * NB * 2);
  int tid = threadIdx.x;
  int n = tid & 15;       // state index (compute role)
  int ch = tid >> 4;      // channel within group (compute role)
  int d = dg * 16 + ch;
  size_t pidx = (size_t)(e * NL + l) * 2 + dir;
  float A = -expf(alog[(pidx * DI + d) * DSt + n]);
  float dpv = dpw[pidx * DI + d];
  int z = e * 2 + dir;
  size_t dblbase = ((size_t)(z * NB + b) * SL) * DBLW;
  float* yout = dir ? y1 : y0;
  size_t ybase = ((size_t)(e * NB + b) * SL) * DI + d;

  // load-role bases
  int lch = tid & 15;       // channel for dv/xv/zv loads
  int ltt = tid >> 4;       // 0..15
  int lj = tid & 31;        // 0..31 (Bm|C)
  int ltt2 = tid >> 5;      // 0..7
  size_t gdbase = ((size_t)(z * NB + b) * SL) * DI + dg * 16 + lch;
  size_t gzbase = ((size_t)(e * NB + b) * SL) * XZW + DI + dg * 16 + lch;

  __shared__ float2 s_dx[2][TC][16];
  __shared__ float s_zv[2][TC][16];
  __shared__ float s_bc[2][TC][32];

  float r_dv[2], r_xv[2], r_zv[2], r_bc[4];

  auto LOADREG = [&](int c) {
    int t0 = c * TC;
#pragma unroll
    for (int k = 0; k < 2; ++k) {
      int t = t0 + ltt + 16 * k;
      int tm = t < SL ? t : SL - 1;
      r_dv[k] = delta[gdbase + (size_t)tm * DI];
      r_xv[k] = xs[gdbase + (size_t)tm * DI];
      int torig = dir ? (SL - 1 - tm) : tm;
      r_zv[k] = xz[gzbase + (size_t)torig * XZW];
    }
#pragma unroll
    for (int k = 0; k < 4; ++k) {
      int t = t0 + ltt2 + 8 * k;
      int tm = t < SL ? t : SL - 1;
      r_bc[k] = dbl[dblbase + (size_t)tm * DBLW + DTR + lj];
    }
  };
  auto STORE = [&](int pb) {
#pragma unroll
    for (int k = 0; k < 2; ++k) {
      s_dx[pb][ltt + 16 * k][lch] = make_float2(r_dv[k], r_xv[k]);
      s_zv[pb][ltt + 16 * k][lch] = r_zv[k];
    }
#pragma unroll
    for (int k = 0; k < 4; ++k) s_bc[pb][ltt2 + 8 * k][lj] = r_bc[k];
  };

  float hst = 0.f;
  auto COMP = [&](int pb, int c) {
    int t0 = c * TC;
#pragma unroll
    for (int half = 0; half < 2; ++half) {
      int i0 = half * 16;
      float ev[16], cc[16], cvv[16], xvv[16], pc[16];
      // (a) LDS reads (b64 packed) + independent exps
#pragma unroll
      for (int i = 0; i < 16; ++i) {
        float2 dx = s_dx[pb][i0 + i][ch];
        float bm = s_bc[pb][i0 + i][n];
        xvv[i] = dx.y;
        cvv[i] = s_bc[pb][i0 + i][16 + n];
        ev[i] = __expf(dx.x * A);
        cc[i] = (dx.x * xvv[i]) * bm;
      }
      // (b) short serial chain (one FMA + one mul per step)
#pragma unroll
      for (int i = 0; i < 16; ++i) {
        hst = ev[i] * hst + cc[i];
        pc[i] = hst * cvv[i];
      }
      // (c) n-reduce on the VALU pipe: DPP xor1, xor2, shr4, shr8
#pragma unroll
      for (int i = 0; i < 16; ++i) pc[i] = dpp_addf<0xB1>(pc[i]);   // quad xor1
#pragma unroll
      for (int i = 0; i < 16; ++i) pc[i] = dpp_addf<0x4E>(pc[i]);   // quad xor2
#pragma unroll
      for (int i = 0; i < 16; ++i) pc[i] = dpp_addf<0x114>(pc[i]);  // row_shr:4
#pragma unroll
      for (int i = 0; i < 16; ++i) pc[i] = dpp_addf<0x118>(pc[i]);  // row_shr:8
      // (d) batched stores (lane n==15 holds the full n-sum)
      if (n == 15) {
#pragma unroll
        for (int i = 0; i < 16; ++i) {
          int t = t0 + i0 + i;
          if (t < SL) {
            int torig = dir ? (SL - 1 - t) : t;
            float yv = pc[i] + xvv[i] * dpv;
            yout[ybase + (size_t)torig * DI] = yv * siluf(s_zv[pb][i0 + i][ch]);
          }
        }
      }
    }
  };

  LOADREG(0);
  STORE(0);
  LOADREG(1);
  __syncthreads();
  int pb = 0;
#pragma unroll 1
  for (int c = 0; c < NCHK; ++c) {
    COMP(pb, c);
    if (c + 1 < NCHK) {
      STORE(pb ^ 1);
      __syncthreads();
      if (c + 2 < NCHK) LOADREG(c + 2);
      pb ^= 1;
    }
  }
}

// ---- final: rmsnorm(h+res)*nfw, drop cls, token-major fT (e,b,196,192) ----
__global__ __launch_bounds__(DM) void k_final_norm(
    const float* __restrict__ h, const float* __restrict__ res,
    const float* __restrict__ nfw, float* __restrict__ fT) {
  int bx = blockIdx.x;
  int tk = bx % NT; int b = (bx / NT) % NB; int e = bx / (NT * NB);
  int c = threadIdx.x;
  __shared__ float wsum[3];
  size_t base = ((size_t)(e * NB + b) * SL + (tk + 1)) * DM;
  float r = h[base + c] + res[base + c];
  float tot = blk_sum3(r * r, wsum);
  float scale = rsqrtf(tot / (float)DM + 1e-5f);
  fT[((size_t)(e * NB + b) * NT + tk) * DM + c] = r * scale * nfw[e * DM + c];
}

// ---- depthwise 3x3 SAME over 14x14; in token-major, out channel-major ----
__global__ void k_dwconv(const float* __restrict__ qkvl, const float* __restrict__ qdw,
                         const float* __restrict__ kdw, const float* __restrict__ vdw,
                         float* __restrict__ qkvd) {
  int gid = blockIdx.x * blockDim.x + threadIdx.x;
  if (gid >= 3 * NB * DM * NT) return;
  int nn = gid % NT;
  int o = (gid / NT) % DM;
  int b = (gid / (NT * DM)) % NB;
  int zz = gid / (NT * DM * NB);
  const float* wsel = (zz == 0 ? qdw : (zz == 1 ? kdw : vdw)) + o * 9;
  int y = nn / HP, x = nn % HP;
  const float* in = qkvl + ((size_t)zz * NB + b) * NT * DM;
  float acc = 0.f;
#pragma unroll
  for (int ky = 0; ky < 3; ++ky) {
    int yy = y + ky - 1;
    if (yy < 0 || yy >= HP) continue;
#pragma unroll
    for (int kx = 0; kx < 3; ++kx) {
      int xx = x + kx - 1;
      if (xx < 0 || xx >= HP) continue;
      acc += in[(size_t)(yy * HP + xx) * DM + o] * wsel[ky * 3 + kx];
    }
  }
  qkvd[gid] = acc;
}

// ---- L2-normalize q,k rows over n=196 (in place) ----
__global__ __launch_bounds__(256) void k_l2norm(float* __restrict__ qkvd) {
  int bx = blockIdx.x;
  int C = bx % DM; int b = (bx / DM) % NB; int zz = bx / (DM * NB);
  int i = threadIdx.x;
  __shared__ float wsum[4];
  float* row = qkvd + ((size_t)zz * NB + b) * DM * NT + (size_t)C * NT;
  float v = (i < NT) ? row[i] : 0.f;
  float tot = blk_sum4(v * v, wsum);
  float sc = 1.f / fmaxf(sqrtf(tot), 1e-12f);
  if (i < NT) row[i] = v * sc;
}

// ---- S = temp*qn.kn^T, softmax over j (block=(b,h,i), 64 threads=j) ----
__global__ __launch_bounds__(64) void k_attn_sm(const float* __restrict__ qkvd,
                                                const float* __restrict__ temp,
                                                float* __restrict__ P) {
  int bx = blockIdx.x;
  int i = bx % 64; int hh = (bx / 64) % NH; int b = bx / (64 * NH);
  int j = threadIdx.x;
  __shared__ float qs[NT];
  const float* qrow = qkvd + ((size_t)0 * NB + b) * DM * NT + (size_t)(hh * 64 + i) * NT;
  for (int k = j; k < NT; k += 64) qs[k] = qrow[k];
  __syncthreads();
  const float* krow = qkvd + ((size_t)1 * NB + b) * DM * NT + (size_t)(hh * 64 + j) * NT;
  float acc = 0.f;
  for (int k = 0; k < NT; ++k) acc += qs[k] * krow[k];
  acc *= temp[hh];
  float m = acc;
  for (int off = 32; off; off >>= 1) m = fmaxf(m, __shfl_xor(m, off, 64));
  float ex = expf(acc - m);
  float s = ex;
  for (int off = 32; off; off >>= 1) s += __shfl_xor(s, off, 64);
  P[((size_t)(b * NH + hh) * 64 + i) * 64 + j] = ex / s;
}

// ---- out = P @ vh ----
__global__ __launch_bounds__(256) void k_av(const float* __restrict__ P,
                                            const float* __restrict__ qkvd,
                                            float* __restrict__ att) {
  int bx = blockIdx.x;
  int i = bx % 64; int hh = (bx / 64) % NH; int b = bx / (64 * NH);
  int nn = threadIdx.x;
  __shared__ float ps[64];
  if (nn < 64) ps[nn] = P[((size_t)(b * NH + hh) * 64 + i) * 64 + nn];
  __syncthreads();
  if (nn >= NT) return;
  const float* vbase = qkvd + ((size_t)2 * NB + b) * DM * NT + (size_t)(hh * 64) * NT + nn;
  float acc = 0.f;
  for (int j = 0; j < 64; ++j) acc += ps[j] * vbase[(size_t)j * NT];
  att[((size_t)b * DM + hh * 64 + i) * NT + nn] = acc;
}

// ---- final pointwise projection to d_out ----
__global__ __launch_bounds__(256) void k_out(const float* __restrict__ att,
                                             const float* __restrict__ pw,
                                             float* __restrict__ out) {
  int bx = blockIdx.x;
  int o = bx % DM; int b = bx / DM;
  int nn = threadIdx.x;
  if (nn >= NT) return;
  const float* abase = att + (size_t)b * DM * NT + nn;
  const float* w = pw + (size_t)o * DM;
  float acc = 0.f;
  for (int c = 0; c < DM; ++c) acc += abase[(size_t)c * NT] * w[c];
  out[((size_t)b * DM + o) * NT + nn] = acc;
}

extern "C" void kernel_launch(void* const* d_in, const int* in_sizes, int n_in,
                              void* d_out, int out_size, void* d_ws, size_t ws_size,
                              hipStream_t stream) {
  const float* x1      = (const float*)d_in[0];
  const float* x2      = (const float*)d_in[1];
  const float* patch_w = (const float*)d_in[2];
  const float* patch_b = (const float*)d_in[3];
  const float* cls_tok = (const float*)d_in[4];
  const float* pos_emb = (const float*)d_in[5];
  const float* norm_w  = (const float*)d_in[6];
  const float* in_w    = (const float*)d_in[7];
  const float* conv_w  = (const float*)d_in[8];
  const float* conv_b  = (const float*)d_in[9];
  const float* xp_w    = (const float*)d_in[10];
  const float* dt_w    = (const float*)d_in[11];
  const float* dt_b    = (const float*)d_in[12];
  const float* A_log   = (const float*)d_in[13];
  const float* Dp      = (const float*)d_in[14];
  const float* out_w   = (const float*)d_in[15];
  const float* normf_w = (const float*)d_in[16];
  const float* qw      = (const float*)d_in[17];
  const float* qdw     = (const float*)d_in[18];
  const float* kw      = (const float*)d_in[19];
  const float* kdw     = (const float*)d_in[20];
  const float* vw      = (const float*)d_in[21];
  const float* vdw     = (const float*)d_in[22];
  const float* pww     = (const float*)d_in[23];
  const float* temp    = (const float*)d_in[24];

  float* ws = (float*)d_ws;
  size_t o = 0;
  float* cosT = ws + o; o += (size_t)NT * DM;
  float* sinT = ws + o; o += (size_t)NT * DM;
  float* hB   = ws + o; o += 2ull * NB * SL * DM;
  float* resB = ws + o; o += 2ull * NB * SL * DM;
  float* hsB  = ws + o; o += 2ull * NB * SL * DM;
  float* xzB  = ws + o; o += 2ull * NB * SL * XZW;
  float* xsB  = ws + o; o += 4ull * NB * SL * DI;
  float* dblB = ws + o; o += 4ull * NB * SL * DBLW;
  float* delB = ws + o; o += 4ull * NB * SL * DI;   // aliased as im2col P before layers
  float* y0B  = ws + o; o += 2ull * NB * SL * DI;   // aliased as patch mm out before layers
  float* y1B  = ws + o; o += 2ull * NB * SL * DI;
  float* fTB  = ws + o; o += 2ull * NB * NT * DM;
  float* qkvL = ws + o; o += 3ull * NB * NT * DM;
  float* qkvD = ws + o; o += 3ull * NB * DM * NT;
  float* Pb   = ws + o; o += (size_t)NB * NH * 64 * 64;
  float* attB = ws + o; o += (size_t)NB * DM * NT;
  (void)ws_size; (void)in_sizes; (void)n_in; (void)out_size;

  const int M = NB * SL;  // 788 rows per encoder

  k_rope_init<<<(NT * DM + 255) / 256, 256, 0, stream>>>(cosT, sinT);

  // patch embed as im2col + GEMM + epilogue (delB/y0B reused as scratch here)
  float* Pm = delB;       // (2, 784, 768)
  float* Pout = y0B;      // (2, 784, 192)
  k_im2col<<<(2 * 784 * 768 + 255) / 256, 256, 0, stream>>>(x1, x2, Pm);
  {
    MM4 p{};
    for (int e = 0; e < 2; ++e) {
      p.A0[e] = Pm + (size_t)e * 784 * 768;
      p.A1[e] = nullptr;
      p.B[e]  = patch_w + (size_t)e * DM * 768;
      p.C[e]  = Pout + (size_t)e * 784 * DM;
    }
    dim3 g((DM + 63) / 64, (784 + 31) / 32, 2);
    k_mm32<<<g, 256, 0, stream>>>(p, 784, DM, 768, 1.f);
  }
  k_patch_fin<<<(2 * NB * SL * DM + 255) / 256, 256, 0, stream>>>(
      Pout, patch_b, cls_tok, pos_emb, hB, resB);

  for (int l = 0; l < NL; ++l) {
    k_rope_res_norm<<<2 * NB * SL, DM, 0, stream>>>(hB, resB, hsB, norm_w, cosT, sinT, l);

    // xz = hs @ in_w^T  (per encoder)
    {
      MM4 p{};
      for (int e = 0; e < 2; ++e) {
        p.A0[e] = hsB + (size_t)e * M * DM;
        p.A1[e] = nullptr;
        p.B[e]  = in_w + (size_t)(e * NL + l) * XZW * DM;
        p.C[e]  = xzB + (size_t)e * M * XZW;
      }
      dim3 g((XZW + 63) / 64, (M + 31) / 32, 2);
      k_mm32<<<g, 256, 0, stream>>>(p, M, XZW, DM, 1.f);
    }

    k_conv_silu<<<(2 * 2 * NB * SL * DI + 255) / 256, 256, 0, stream>>>(xzB, conv_w, conv_b, xsB, l);

    // dbl = xs @ xp_w^T (per e,dir)
    {
      MM4 p{};
      for (int z = 0; z < 4; ++z) {
        int e = z / 2, dir = z % 2;
        p.A0[z] = xsB + (size_t)z * M * DI;
        p.A1[z] = nullptr;
        p.B[z]  = xp_w + ((size_t)(e * NL + l) * 2 + dir) * DBLW * DI;
        p.C[z]  = dblB + (size_t)z * M * DBLW;
      }
      dim3 g((DBLW + 63) / 64, (M + 31) / 32, 4);
      k_mm32<<<g, 256, 0, stream>>>(p, M, DBLW, DI, 1.f);
    }

    k_delta<<<(2 * 2 * NB * SL * DI + 255) / 256, 256, 0, stream>>>(dblB, dt_w, dt_b, delB, l);

    k_scan<<<2 * 2 * NB * (DI / 16), 256, 0, stream>>>(xsB, delB, dblB, xzB, A_log, Dp, y0B, y1B, l);

    // h = 0.5*(y0+y1) @ out_w^T (per encoder)
    {
      MM4 p{};
      for (int e = 0; e < 2; ++e) {
        p.A0[e] = y0B + (size_t)e * M * DI;
        p.A1[e] = y1B + (size_t)e * M * DI;
        p.B[e]  = out_w + (size_t)(e * NL + l) * DM * DI;
        p.C[e]  = hB + (size_t)e * M * DM;
      }
      dim3 g((DM + 63) / 64, (M + 31) / 32, 2);
      k_mm32<<<g, 256, 0, stream>>>(p, M, DM, DI, 0.5f);
    }
  }

  k_final_norm<<<2 * NB * NT, DM, 0, stream>>>(hB, resB, normf_w, fTB);

  // q/k/v linear: q from f1 (e=0), k,v from f2 (e=1)
  {
    MM4 p{};
    const int Mq = NB * NT;  // 784
    p.A0[0] = fTB;                         p.A1[0] = nullptr; p.B[0] = qw; p.C[0] = qkvL;
    p.A0[1] = fTB + (size_t)NB * NT * DM;  p.A1[1] = nullptr; p.B[1] = kw; p.C[1] = qkvL + (size_t)Mq * DM;
    p.A0[2] = fTB + (size_t)NB * NT * DM;  p.A1[2] = nullptr; p.B[2] = vw; p.C[2] = qkvL + 2ull * Mq * DM;
    dim3 g((DM + 63) / 64, (Mq + 31) / 32, 3);
    k_mm32<<<g, 256, 0, stream>>>(p, Mq, DM, DM, 1.f);
  }

  k_dwconv<<<(3 * NB * DM * NT + 255) / 256, 256, 0, stream>>>(qkvL, qdw, kdw, vdw, qkvD);
  k_l2norm<<<2 * NB * DM, 256, 0, stream>>>(qkvD);
  k_attn_sm<<<NB * NH * 64, 64, 0, stream>>>(qkvD, temp, Pb);
  k_av<<<NB * NH * 64, 256, 0, stream>>>(Pb, qkvD, attB);
  k_out<<<NB * DM, 256, 0, stream>>>(attB, pww, (float*)d_out);
}